// Round 8
// baseline (301.537 us; speedup 1.0000x reference)
//
#include <hip/hip_runtime.h>
#include <math.h>

#define B_ 2
#define C_ 256
#define N_ 4096
#define TXT_ 512
#define CH_ 128
#define TN 32
#define KSPLIT 4
#define PXR 4224          // 64 * 66 padded-pixel rows per batch
#define PXPAD 96          // halo pad rows each side
#define PXTOT (PXR + 2 * PXPAD)

typedef unsigned short u16;
typedef unsigned char u8;
typedef __attribute__((ext_vector_type(8))) short short8;
typedef __attribute__((ext_vector_type(4))) float f32x4;

__device__ __forceinline__ float bf2f(u16 v){
  union { unsigned u; float f; } w; w.u = ((unsigned)v) << 16; return w.f;
}
__device__ __forceinline__ u16 f2bf(float f){
  union { float f; unsigned u; } w; w.f = f;
  unsigned r = w.u + 0x7fffu + ((w.u >> 16) & 1u);
  return (u16)(r >> 16);
}
// f >= 0, f <= ~3: round-to-nearest-even into OCP e4m3fn
__device__ __forceinline__ unsigned f2e4(float f){
  unsigned x = __float_as_uint(f);
  unsigned r = x + 0x7FFFFu + ((x >> 20) & 1u);
  int E = (int)((r >> 23) & 255) - 120;
  if (E <= 0){
    int s = __float2int_rn(f * 512.f);   // subnormal step 2^-9; s in [0,8]
    return (unsigned)s;                   // s==8 encodes as (1<<3)|0 = 2^-6, correct
  }
  return ((unsigned)E << 3) | ((r >> 20) & 7u);
}
// e4m3fn (non-negative) -> f32, branchless
__device__ __forceinline__ float e42f(unsigned v){
  unsigned e = (v >> 3) & 15u, m = v & 7u;
  float nrm = __uint_as_float(((e + 120u) << 23) | (m << 20));
  float sub = (float)m * 0.001953125f;
  return e ? nrm : sub;
}

#define MFMA_BF16(a,b,c) __builtin_amdgcn_mfma_f32_16x16x32_bf16(a,b,c,0,0,0)

// Stage a 128-row x 64-col bf16 tile (256 threads). Pre-swizzled source, linear LDS dest.
__device__ __forceinline__ void stage_tile(const u16* __restrict__ g, int stride, u16* lds, int t)
{
  #pragma unroll
  for (int q = 0; q < 4; q++){
    int e = q * 256 + t;          // 16B unit index
    int row = e >> 3;
    int slot = e & 7;
    const u16* gp = g + (size_t)row * stride + ((slot ^ (row & 7)) << 3);
    u16* lp = lds + (size_t)e * 8;
    __builtin_amdgcn_global_load_lds((const __attribute__((address_space(1))) void*)gp,
                                     (__attribute__((address_space(3))) void*)lp, 16, 0, 0);
  }
}

// 512-thread variant: 256 rows.
__device__ __forceinline__ void stage_tile512_256(const u16* __restrict__ g, int stride, u16* lds, int t)
{
  #pragma unroll
  for (int q = 0; q < 4; q++){
    int e = q * 512 + t;          // 2048 units
    int row = e >> 3;
    int slot = e & 7;
    const u16* gp = g + (size_t)row * stride + ((slot ^ (row & 7)) << 3);
    u16* lp = lds + (size_t)e * 8;
    __builtin_amdgcn_global_load_lds((const __attribute__((address_space(1))) void*)gp,
                                     (__attribute__((address_space(3))) void*)lp, 16, 0, 0);
  }
}

__device__ __forceinline__ short8 frag_ld(const u16* lds, int row, int slot)
{
  return *(const short8*)(lds + row * 64 + ((slot ^ (row & 7)) << 3));
}

// ---------- text pipeline: txt_emb, attn constant (v@wo^T+bo), txt_n ----------
__global__ __launch_bounds__(256) void k_text(
    const float* __restrict__ txt, const float* __restrict__ tpw,
    const float* __restrict__ tpb, const float* __restrict__ wv,
    const float* __restrict__ bv, const float* __restrict__ wo,
    const float* __restrict__ bo,
    float* __restrict__ txt_emb, float* __restrict__ attn_c, float* __restrict__ txt_n)
{
  int b = blockIdx.x, t = threadIdx.x;
  __shared__ float te[C_], vs[C_], red[C_];
  const float* tb = txt + b * TXT_;
  const float* wr = tpw + (size_t)t * TXT_;
  float s = 0.f;
  for (int j = 0; j < TXT_; j++) s += tb[j] * wr[j];
  s += tpb[t];
  te[t] = s;
  txt_emb[b * C_ + t] = s;
  __syncthreads();
  float sv = 0.f;
  const float* wvr = wv + (size_t)t * C_;
  for (int j = 0; j < C_; j++) sv += te[j] * wvr[j];
  sv += bv[t];
  vs[t] = sv;
  __syncthreads();
  float sa = 0.f;
  const float* wor = wo + (size_t)t * C_;
  for (int j = 0; j < C_; j++) sa += vs[j] * wor[j];
  sa += bo[t];
  attn_c[b * C_ + t] = sa;
  red[t] = te[t] * te[t];
  __syncthreads();
  for (int o = 128; o > 0; o >>= 1){ if (t < o) red[t] += red[t + o]; __syncthreads(); }
  float nrm = sqrtf(red[0]);
  float inv = 1.f / fmaxf(nrm, 1e-12f);
  txt_n[b * C_ + t] = te[t] * inv;
}

// ---------- source (residual+LN) -> srcT bf16 [C][N], snb bf16 [N][C], cos ----------
__global__ __launch_bounds__(256) void k_source(
    const float* __restrict__ img, const float* __restrict__ attn_c,
    const float* __restrict__ ln_g, const float* __restrict__ ln_b,
    const float* __restrict__ txt_n,
    u16* __restrict__ srcT, u16* __restrict__ snb, float* __restrict__ cosv)
{
  int b = blockIdx.y;
  int n0 = blockIdx.x * TN;
  int t = threadIdx.x;
  __shared__ float x[C_][TN + 1];
  __shared__ float ps[8][TN];
  __shared__ float ps2[8][TN];
  __shared__ float ac_s[C_], g_s[C_], bb_s[C_], tn_s[C_];
  __shared__ float mean_s[TN], rstd_s[TN], rn_s[TN];
  ac_s[t] = attn_c[b * C_ + t];
  g_s[t]  = ln_g[t];
  bb_s[t] = ln_b[t];
  tn_s[t] = txt_n[b * C_ + t];
  const float* ib = img + (size_t)b * C_ * N_ + n0;
  for (int k = 0; k < TN; k++){
    int e = t + k * 256;
    int c = e >> 5, nn = e & 31;
    x[c][nn] = ib[(size_t)c * N_ + nn];
  }
  __syncthreads();
  for (int k = 0; k < TN; k++){
    int e = t + k * 256;
    int c = e >> 5, nn = e & 31;
    x[c][nn] += ac_s[c];
  }
  __syncthreads();
  {
    int p = t >> 5, nn = t & 31;
    float s1 = 0.f, s2 = 0.f;
    for (int j = 0; j < 32; j++){
      float v = x[p + 8 * j][nn];
      s1 += v; s2 += v * v;
    }
    ps[p][nn] = s1; ps2[p][nn] = s2;
  }
  __syncthreads();
  if (t < TN){
    float S1 = 0.f, S2 = 0.f;
    for (int pp = 0; pp < 8; pp++){ S1 += ps[pp][t]; S2 += ps2[pp][t]; }
    float mean = S1 * (1.f / C_);
    float var = S2 * (1.f / C_) - mean * mean;
    mean_s[t] = mean;
    rstd_s[t] = rsqrtf(var + 1e-5f);
  }
  __syncthreads();
  for (int k = 0; k < TN; k++){
    float sval = (x[t][k] - mean_s[k]) * rstd_s[k] * g_s[t] + bb_s[t];
    x[t][k] = sval;
  }
  for (int kq = 0; kq < TN; kq += 4){
    ushort4 pkv;
    pkv.x = f2bf(x[t][kq + 0]);
    pkv.y = f2bf(x[t][kq + 1]);
    pkv.z = f2bf(x[t][kq + 2]);
    pkv.w = f2bf(x[t][kq + 3]);
    *reinterpret_cast<ushort4*>(&srcT[(size_t)(b * C_ + t) * N_ + n0 + kq]) = pkv;
  }
  __syncthreads();
  {
    int p = t >> 5, nn = t & 31;
    float s2 = 0.f, sd = 0.f;
    for (int j = 0; j < 32; j++){
      int c = p + 8 * j;
      float v = x[c][nn];
      s2 += v * v; sd += v * tn_s[c];
    }
    ps[p][nn] = s2; ps2[p][nn] = sd;
  }
  __syncthreads();
  if (t < TN){
    float S2 = 0.f, SD = 0.f;
    for (int pp = 0; pp < 8; pp++){ S2 += ps[pp][t]; SD += ps2[pp][t]; }
    float nrm = sqrtf(S2);
    float rn = 1.f / fmaxf(nrm, 1e-12f);
    rn_s[t] = rn;
    cosv[(b << 12) + n0 + t] = SD * rn;
  }
  __syncthreads();
  for (int k = 0; k < TN; k++){
    snb[(size_t)((b << 12) + n0 + k) * C_ + t] = f2bf(x[t][k] * rn_s[k]);
  }
}

// ---------- marginals ----------
__global__ __launch_bounds__(256) void k_qmarg(const float* __restrict__ dens, float* __restrict__ q){
  int b = blockIdx.x, t = threadIdx.x;
  __shared__ float red[256];
  const float* d = dens + (size_t)b * N_;
  float s = 0.f;
  for (int n = t; n < N_; n += 256) s += fmaxf(d[n], 0.f) + 1e-6f;
  red[t] = s; __syncthreads();
  for (int o = 128; o > 0; o >>= 1){ if (t < o) red[t] += red[t + o]; __syncthreads(); }
  float inv = 1.f / red[0];
  for (int n = t; n < N_; n += 256) q[b * N_ + n] = (fmaxf(d[n], 0.f) + 1e-6f) * inv;
}

__global__ __launch_bounds__(256) void k_pmarg(const float* __restrict__ cosv,
    const float* __restrict__ temp_p, float* __restrict__ p){
  int b = blockIdx.x, t = threadIdx.x;
  __shared__ float red[256];
  float temp = fmaxf(temp_p[0], 0.01f);
  float inv_t = 1.f / temp;
  const float* cb = cosv + (size_t)b * N_;
  float m = -1e30f;
  for (int n = t; n < N_; n += 256) m = fmaxf(m, cb[n] * inv_t);
  red[t] = m; __syncthreads();
  for (int o = 128; o > 0; o >>= 1){ if (t < o) red[t] = fmaxf(red[t], red[t + o]); __syncthreads(); }
  m = red[0]; __syncthreads();
  float s = 0.f;
  for (int n = t; n < N_; n += 256) s += expf(cb[n] * inv_t - m);
  red[t] = s; __syncthreads();
  for (int o = 128; o > 0; o >>= 1){ if (t < o) red[t] += red[t + o]; __syncthreads(); }
  float invs = 1.f / red[0];
  for (int n = t; n < N_; n += 256) p[b * N_ + n] = expf(cb[n] * inv_t - m) * invs;
}

__global__ __launch_bounds__(256) void k_zero(float* __restrict__ p, int n){
  int i = blockIdx.x * 256 + threadIdx.x;
  if (i < n) p[i] = 0.f;
}

// ---------- K = exp(20*(sn sn^T - 1)) -> FP8 e4m3 via MFMA + column sums ----------
// Full grid, single-pass epilogue. Output tile staged through byte-swizzled LDS
// (Cf8 aliases staging buffer) for coalesced 16B stores; colsum sums fp8-decoded values.
__global__ __launch_bounds__(256) void k_kgen(
    const u16* __restrict__ snb, u8* __restrict__ Kp, float* __restrict__ colsum)
{
  int b = blockIdx.z;
  int m0 = blockIdx.x << 7, n0 = blockIdx.y << 7;
  int t = threadIdx.x;
  int lane = t & 63, w = t >> 6;
  int wr = w >> 1, wc = w & 1;
  __shared__ __align__(16) u16 shbuf[128 * 128];   // 32 KB: Al|Bl, low 16KB reused as Cf8
  u16* Al = shbuf;
  u16* Bl = shbuf + 128 * 64;
  __shared__ float cs[128];
  if (t < 128) cs[t] = 0.f;
  f32x4 zero = {0.f, 0.f, 0.f, 0.f};
  f32x4 acc[4][4];
  #pragma unroll
  for (int i = 0; i < 4; i++){
    #pragma unroll
    for (int j = 0; j < 4; j++) acc[i][j] = zero;
  }
  const u16* sb = snb + (size_t)b * N_ * C_;
  const u16* ga = sb + (size_t)m0 * C_;
  const u16* gb = sb + (size_t)n0 * C_;
  for (int kt = 0; kt < C_; kt += 64){
    stage_tile(ga + kt, C_, Al, t);
    stage_tile(gb + kt, C_, Bl, t);
    __syncthreads();
    #pragma unroll
    for (int kh = 0; kh < 2; kh++){
      short8 af[4], bfv[4];
      #pragma unroll
      for (int i = 0; i < 4; i++){
        af[i]  = frag_ld(Al, wr * 64 + i * 16 + (lane & 15), kh * 4 + (lane >> 4));
        bfv[i] = frag_ld(Bl, wc * 64 + i * 16 + (lane & 15), kh * 4 + (lane >> 4));
      }
      #pragma unroll
      for (int i = 0; i < 4; i++){
        #pragma unroll
        for (int j = 0; j < 4; j++)
          acc[i][j] = MFMA_BF16(af[i], bfv[j], acc[i][j]);
      }
    }
    __syncthreads();
  }
  // epilogue: exp -> fp8 into byte-swizzled Cf8 (aliases staging LDS; all reads done)
  u8* Cf8 = (u8*)shbuf;   // [128][128] bytes, col swizzled by ((row>>2)&7)<<4
  #pragma unroll
  for (int j = 0; j < 4; j++){
    int col = wc * 64 + j * 16 + (lane & 15);
    float csum = 0.f;
    #pragma unroll
    for (int i = 0; i < 4; i++){
      int rb = wr * 64 + i * 16 + (lane >> 4) * 4;
      #pragma unroll
      for (int r = 0; r < 4; r++){
        int row = rb + r;
        float e = expf(20.f * (acc[i][j][r] - 1.f));
        unsigned pk = f2e4(e);
        csum += e42f(pk);
        Cf8[row * 128 + (col ^ (((row >> 2) & 7) << 4))] = (u8)pk;
      }
    }
    atomicAdd(&cs[col], csum);
  }
  __syncthreads();
  u8* Kb = Kp + (size_t)b * N_ * N_;
  // coalesced stores: 128 rows x 8 units of 16B (un-swizzle on unit index)
  for (int e = t; e < 1024; e += 256){
    int row = e >> 3, un = e & 7;
    uint4 v = *(const uint4*)(Cf8 + row * 128 + ((un ^ ((row >> 2) & 7)) << 4));
    *reinterpret_cast<uint4*>(&Kb[(size_t)(m0 + row) * N_ + n0 + (un << 4)]) = v;
  }
  if (t < 128) atomicAdd(&colsum[b * N_ + n0 + t], cs[t]);
}

__global__ __launch_bounds__(256) void k_div(
    const float* __restrict__ marg, const float* __restrict__ denom, float* __restrict__ outp){
  int i = blockIdx.x * 256 + threadIdx.x;
  if (i < B_ * N_) outp[i] = marg[i] / (denom[i] + 1e-8f);
}

// ---------- out[r] = marg[r] / (K_row_r . x + 1e-8)  (K symmetric, fp8), 8 rows/block ----------
__global__ __launch_bounds__(256) void k_mv(
    const u8* __restrict__ Kp, const float* __restrict__ x,
    const float* __restrict__ marg, float* __restrict__ outp)
{
  int r0 = blockIdx.x * 8;
  int b = r0 >> 12;
  int t = threadIdx.x, w = t >> 6, lane = t & 63;
  __shared__ __align__(16) float xs[N_];
  const float* xb = x + b * N_;
  for (int i = t; i < N_ / 4; i += 256)
    reinterpret_cast<float4*>(xs)[i] = reinterpret_cast<const float4*>(xb)[i];
  __syncthreads();
  int r = r0 + w * 2;
  const u8* Kr0 = Kp + (size_t)b * N_ * N_ + (size_t)(r & (N_ - 1)) * N_;
  const u8* Kr1 = Kr0 + N_;
  float acc0 = 0.f, acc1 = 0.f;
  #pragma unroll
  for (int p = 0; p < 8; p++){
    int idx = p * 512 + lane * 8;
    uint2 a = *reinterpret_cast<const uint2*>(Kr0 + idx);
    uint2 c = *reinterpret_cast<const uint2*>(Kr1 + idx);
    float4 x0 = *reinterpret_cast<const float4*>(xs + idx);
    float4 x1 = *reinterpret_cast<const float4*>(xs + idx + 4);
    acc0 += e42f(a.x & 255u) * x0.x + e42f((a.x >> 8) & 255u) * x0.y
          + e42f((a.x >> 16) & 255u) * x0.z + e42f(a.x >> 24) * x0.w
          + e42f(a.y & 255u) * x1.x + e42f((a.y >> 8) & 255u) * x1.y
          + e42f((a.y >> 16) & 255u) * x1.z + e42f(a.y >> 24) * x1.w;
    acc1 += e42f(c.x & 255u) * x0.x + e42f((c.x >> 8) & 255u) * x0.y
          + e42f((c.x >> 16) & 255u) * x0.z + e42f(c.x >> 24) * x0.w
          + e42f(c.y & 255u) * x1.x + e42f((c.y >> 8) & 255u) * x1.y
          + e42f((c.y >> 16) & 255u) * x1.z + e42f(c.y >> 24) * x1.w;
  }
  for (int o = 32; o > 0; o >>= 1){
    acc0 += __shfl_down(acc0, o);
    acc1 += __shfl_down(acc1, o);
  }
  if (lane == 0){
    outp[r] = marg[r] / (acc0 + 1e-8f);
    outp[r + 1] = marg[r + 1] / (acc1 + 1e-8f);
  }
}

// ---------- usrcT[c][n] = srcT[c][n] * u[n] ----------
__global__ __launch_bounds__(256) void k_uscale(
    const u16* __restrict__ srcT, const float* __restrict__ uu, u16* __restrict__ usrcT)
{
  int i = blockIdx.x * 256 + threadIdx.x;
  int n8 = i & (N_ / 8 - 1);
  int row = i >> 9;
  int b = row >> 8;
  const u16* s = srcT + (size_t)row * N_ + n8 * 8;
  short8 v = *reinterpret_cast<const short8*>(s);
  const float* ub = uu + b * N_ + n8 * 8;
  short8 o;
  #pragma unroll
  for (int q = 0; q < 8; q++) o[q] = (short)f2bf(bf2f((u16)v[q]) * ub[q]);
  *reinterpret_cast<short8*>(usrcT + (size_t)row * N_ + n8 * 8) = o;
}

// ---------- part[ks][m][c] = vv[m] * sum_{n in ks chunk} K[m][n]*usrc[n][c] ----------
// 512 threads, tile 64m x 256c, fp8 K A-operand decoded to bf16 in registers.
__global__ __launch_bounds__(512) void k_full(
    const u8* __restrict__ Kp, const u16* __restrict__ usrcT,
    const float* __restrict__ vvv,
    u16* __restrict__ p0, u16* __restrict__ p1,
    u16* __restrict__ p2, u16* __restrict__ p3)
{
  int m0 = blockIdx.x << 6;
  int b = blockIdx.z >> 2, ks = blockIdx.z & 3;
  int t = threadIdx.x, lane = t & 63, w = t >> 6;   // w: 0..7 -> c-stripe of 32
  __shared__ __align__(16) u16 shbuf[64 * 64 + 256 * 64];  // Al 8KB | Bl 32KB
  __shared__ float vsm[64];
  u16* Al = shbuf;
  u16* Bl = shbuf + 64 * 64;
  if (t < 64) vsm[t] = vvv[b * N_ + m0 + t];
  f32x4 zero = {0.f, 0.f, 0.f, 0.f};
  f32x4 acc[4][2];
  #pragma unroll
  for (int i = 0; i < 4; i++){
    #pragma unroll
    for (int j = 0; j < 2; j++) acc[i][j] = zero;
  }
  const u8* ka = Kp + (size_t)b * N_ * N_ + (size_t)m0 * N_ + ks * (N_ / KSPLIT);
  const u16* ub = usrcT + (size_t)b * C_ * N_ + ks * (N_ / KSPLIT);
  for (int kt = 0; kt < N_ / KSPLIT; kt += 64){
    // A: 64x64 fp8 -> decode to bf16, reg-stage into swizzled-content linear LDS
    {
      int row = t >> 3, slot = t & 7;
      const u8* gp = ka + (size_t)row * N_ + kt + ((slot ^ (row & 7)) << 3);
      uint2 v8 = *reinterpret_cast<const uint2*>(gp);
      short8 o;
      o[0] = (short)f2bf(e42f(v8.x & 255u));
      o[1] = (short)f2bf(e42f((v8.x >> 8) & 255u));
      o[2] = (short)f2bf(e42f((v8.x >> 16) & 255u));
      o[3] = (short)f2bf(e42f(v8.x >> 24));
      o[4] = (short)f2bf(e42f(v8.y & 255u));
      o[5] = (short)f2bf(e42f((v8.y >> 8) & 255u));
      o[6] = (short)f2bf(e42f((v8.y >> 16) & 255u));
      o[7] = (short)f2bf(e42f(v8.y >> 24));
      *reinterpret_cast<short8*>(Al + (size_t)t * 8) = o;
    }
    stage_tile512_256(ub + kt, N_, Bl, t);
    __syncthreads();
    #pragma unroll
    for (int kh = 0; kh < 2; kh++){
      short8 af[4], bfv[2];
      #pragma unroll
      for (int i = 0; i < 4; i++)
        af[i] = frag_ld(Al, i * 16 + (lane & 15), kh * 4 + (lane >> 4));
      #pragma unroll
      for (int j = 0; j < 2; j++)
        bfv[j] = frag_ld(Bl, w * 32 + j * 16 + (lane & 15), kh * 4 + (lane >> 4));
      #pragma unroll
      for (int i = 0; i < 4; i++){
        #pragma unroll
        for (int j = 0; j < 2; j++)
          acc[i][j] = MFMA_BF16(af[i], bfv[j], acc[i][j]);
      }
    }
    __syncthreads();
  }
  // restage [64m][256c] bf16 (vv-scaled) into swizzled Ct, then fully-linear stores
  u16* Ct = shbuf;
  #pragma unroll
  for (int j = 0; j < 2; j++){
    int col = w * 32 + j * 16 + (lane & 15);
    #pragma unroll
    for (int i = 0; i < 4; i++){
      int rb = i * 16 + (lane >> 4) * 4;
      #pragma unroll
      for (int r = 0; r < 4; r++){
        int row = rb + r;
        Ct[row * 256 + ((((col >> 3) ^ (row & 7)) << 3) | (col & 7))] =
            f2bf(acc[i][j][r] * vsm[row]);
      }
    }
  }
  __syncthreads();
  u16* P = (ks == 0) ? p0 : (ks == 1) ? p1 : (ks == 2) ? p2 : p3;
  for (int e = t; e < 2048; e += 512){
    int row = e >> 5, un = e & 31;
    short8 v8 = *(const short8*)(Ct + row * 256 + ((un ^ (row & 7)) << 3));
    *reinterpret_cast<short8*>(&P[(size_t)((b << 12) + m0 + row) * C_ + (un << 3)]) = v8;
  }
}

// ---------- cast opw (f32 256x256) to bf16 ----------
__global__ __launch_bounds__(256) void k_wcast(const float* __restrict__ w, u16* __restrict__ o){
  int i = blockIdx.x * 256 + threadIdx.x;
  o[i] = f2bf(w[i]);
}

// ---------- out_feat = img + 1x1conv(p0+p1+p2+p3) via MFMA; tile 64n x 128co ----------
__global__ __launch_bounds__(256) void k_opconv(
    const u16* __restrict__ opwB, const float* __restrict__ opb,
    const u16* __restrict__ p0, const u16* __restrict__ p1,
    const u16* __restrict__ p2, const u16* __restrict__ p3,
    const float* __restrict__ img, float* __restrict__ outf)
{
  int b = blockIdx.z;
  int n0 = blockIdx.x << 6;
  int co0 = blockIdx.y << 7;
  int t = threadIdx.x, lane = t & 63, w = t >> 6;
  int wr = w >> 1, wc = w & 1;              // wr: co half (64), wc: n half (32)
  __shared__ __align__(16) u16 Al[128 * 64];   // opw rows=co
  __shared__ __align__(16) u16 Bl[64 * 64];    // fused rows=n
  f32x4 zero = {0.f, 0.f, 0.f, 0.f};
  f32x4 acc[4][2];
  #pragma unroll
  for (int i = 0; i < 4; i++){
    #pragma unroll
    for (int j = 0; j < 2; j++) acc[i][j] = zero;
  }
  for (int ct = 0; ct < C_; ct += 64){
    stage_tile(opwB + (size_t)co0 * C_ + ct, C_, Al, t);
    // reg-stage B: sum 4 bf16 partials into swizzled layout (512 units, 2 iters)
    #pragma unroll
    for (int q = 0; q < 2; q++){
      int e = q * 256 + t;
      int row = e >> 3, slot = e & 7;
      int col = ct + ((slot ^ (row & 7)) << 3);
      size_t idx = (size_t)((b << 12) + n0 + row) * C_ + col;
      short8 a0 = *reinterpret_cast<const short8*>(p0 + idx);
      short8 a1 = *reinterpret_cast<const short8*>(p1 + idx);
      short8 a2 = *reinterpret_cast<const short8*>(p2 + idx);
      short8 a3 = *reinterpret_cast<const short8*>(p3 + idx);
      short8 o;
      #pragma unroll
      for (int k = 0; k < 8; k++)
        o[k] = (short)f2bf(bf2f((u16)a0[k]) + bf2f((u16)a1[k]) + bf2f((u16)a2[k]) + bf2f((u16)a3[k]));
      *reinterpret_cast<short8*>(Bl + (size_t)e * 8) = o;
    }
    __syncthreads();
    #pragma unroll
    for (int kh = 0; kh < 2; kh++){
      short8 af[4], bfv[2];
      #pragma unroll
      for (int i = 0; i < 4; i++)
        af[i] = frag_ld(Al, wr * 64 + i * 16 + (lane & 15), kh * 4 + (lane >> 4));
      #pragma unroll
      for (int j = 0; j < 2; j++)
        bfv[j] = frag_ld(Bl, wc * 32 + j * 16 + (lane & 15), kh * 4 + (lane >> 4));
      #pragma unroll
      for (int i = 0; i < 4; i++){
        #pragma unroll
        for (int j = 0; j < 2; j++)
          acc[i][j] = MFMA_BF16(af[i], bfv[j], acc[i][j]);
      }
    }
    __syncthreads();
  }
  #pragma unroll
  for (int i = 0; i < 4; i++){
    int cb = co0 + wr * 64 + i * 16 + (lane >> 4) * 4;
    #pragma unroll
    for (int j = 0; j < 2; j++){
      int nc = n0 + wc * 32 + j * 16 + (lane & 15);
      #pragma unroll
      for (int r = 0; r < 4; r++){
        int co = cb + r;
        size_t oi = (size_t)(b * C_ + co) * N_ + nc;
        outf[oi] = acc[i][j][r] + img[oi] + opb[co];
      }
    }
  }
}

// ---------- transpose out_feat -> padded bf16 [b][px'][ci] ----------
__global__ __launch_bounds__(256) void k_tr(const float* __restrict__ outf, u16* __restrict__ inTp)
{
  int b = blockIdx.z;
  int c0 = blockIdx.y << 6;
  int px0 = blockIdx.x << 6;
  int t = threadIdx.x;
  __shared__ float tile[64][65];
  int tx = t & 63, ty4 = t >> 6;
  for (int cc = ty4; cc < 64; cc += 4)
    tile[cc][tx] = outf[((size_t)(b * C_) + c0 + cc) * N_ + px0 + tx];
  __syncthreads();
  int p = t >> 2, cg = (t & 3) << 4;
  int px = px0 + p;
  int y = px >> 6, x = px & 63;
  int pxp = y * 66 + x + 1;
  u16* dst = inTp + ((size_t)b * PXTOT + PXPAD + pxp) * C_ + c0 + cg;
  #pragma unroll
  for (int q = 0; q < 16; q += 4){
    ushort4 pk;
    pk.x = f2bf(tile[cg + q + 0][p]);
    pk.y = f2bf(tile[cg + q + 1][p]);
    pk.z = f2bf(tile[cg + q + 2][p]);
    pk.w = f2bf(tile[cg + q + 3][p]);
    *reinterpret_cast<ushort4*>(dst + q) = pk;
  }
}

// ---------- weights -> Wt[tap][co(256 fused)][ci] bf16, fused bias ----------
__global__ __launch_bounds__(256) void k_wtr(
    const float* __restrict__ hm1_w, const float* __restrict__ hv1_w,
    const float* __restrict__ hm1_b, const float* __restrict__ hv1_b,
    u16* __restrict__ Wt, float* __restrict__ biasF)
{
  int i = blockIdx.x * 256 + threadIdx.x;   // < 9*256*256
  int ci = i & 255, co = (i >> 8) & 255, tap = i >> 16;
  float v = (co < CH_) ? hm1_w[((size_t)co * C_ + ci) * 9 + tap]
                       : hv1_w[((size_t)(co - CH_) * C_ + ci) * 9 + tap];
  Wt[i] = f2bf(v);
  if (i < CH_) biasF[i] = hm1_b[i];
  else if (i < 2 * CH_) biasF[i] = hv1_b[i - CH_];
}

// ---------- fused 3x3 conv (both heads) as implicit GEMM: C[co][px'] (bf16 out) ----------
__global__ __launch_bounds__(256) void k_conv3m(
    const u16* __restrict__ inTp, const u16* __restrict__ Wt,
    const float* __restrict__ biasF,
    u16* __restrict__ q0, u16* __restrict__ q1,
    u16* __restrict__ q2, u16* __restrict__ q3)
{
  int px0 = blockIdx.x << 7;           // 0..32 (33 tiles of 128 px')
  int cot = blockIdx.y;                // 0..1 (co halves of 256 fused)
  int b = blockIdx.z >> 2, ks = blockIdx.z & 3;
  int t = threadIdx.x, lane = t & 63, w = t >> 6;
  int wr = w >> 1, wc = w & 1;
  __shared__ __align__(16) u16 Al[128 * 64];   // weights: 128 co rows x 64 ci
  __shared__ __align__(16) u16 Bl[128 * 64];   // input:   128 px rows x 64 ci
  f32x4 zero = {0.f, 0.f, 0.f, 0.f};
  f32x4 acc[4][4];
  #pragma unroll
  for (int i = 0; i < 4; i++){
    #pragma unroll
    for (int j = 0; j < 4; j++) acc[i][j] = zero;
  }
  const u16* inb = inTp + ((size_t)b * PXTOT + PXPAD + px0) * C_;
  for (int s = ks * 9; s < ks * 9 + 9; s++){
    int tap = s >> 2, cic = (s & 3) << 6;
    int ky = tap / 3, kx = tap - ky * 3;
    int off = (ky - 1) * 66 + (kx - 1);
    stage_tile(Wt + ((size_t)tap * 256 + cot * 128) * C_ + cic, C_, Al, t);
    stage_tile(inb + (ptrdiff_t)off * C_ + cic, C_, Bl, t);
    __syncthreads();
    #pragma unroll
    for (int kh = 0; kh < 2; kh++){
      short8 af[4], bfv[4];
      #pragma unroll
      for (int i = 0; i < 4; i++){
        af[i]  = frag_ld(Al, wr * 64 + i * 16 + (lane & 15), kh * 4 + (lane >> 4));
        bfv[i] = frag_ld(Bl, wc * 64 + i * 16 + (lane & 15), kh * 4 + (lane >> 4));
      }
      #pragma unroll
      for (int i = 0; i < 4; i++){
        #pragma unroll
        for (int j = 0; j < 4; j++)
          acc[i][j] = MFMA_BF16(af[i], bfv[j], acc[i][j]);
      }
    }
    __syncthreads();
  }
  u16* P = (ks == 0) ? q0 : (ks == 1) ? q1 : (ks == 2) ? q2 : q3;
  #pragma unroll
  for (int i = 0; i < 4; i++){
    #pragma unroll
    for (int j = 0; j < 4; j++){
      int pxp = px0 + wc * 64 + j * 16 + (lane & 15);
      int y = pxp / 66;
      int xm = pxp - y * 66;
      bool valid = (xm >= 1 && xm <= 64);
      int outn = y * 64 + xm - 1;
      #pragma unroll
      for (int r = 0; r < 4; r++){
        int co = cot * 128 + wr * 64 + i * 16 + (lane >> 4) * 4 + r;
        if (valid){
          float bco = (ks == 0) ? biasF[co] : 0.f;
          P[((size_t)(b * 256 + co)) * N_ + outn] = f2bf(acc[i][j][r] + bco);
        }
      }
    }
  }
}

// ---------- batchnorm stats over (B,H,W) per fused channel (sums 4 K-parts) ----------
__global__ __launch_bounds__(256) void k_bnstats2(
    const u16* __restrict__ p0, const u16* __restrict__ p1,
    const u16* __restrict__ p2, const u16* __restrict__ p3,
    float* __restrict__ stats)
{
  int ch = blockIdx.x, t = threadIdx.x;   // ch in [0,256)
  __shared__ float r1[256], r2[256];
  float s1 = 0.f, s2 = 0.f;
  for (int i = t; i < B_ * N_; i += 256){
    int b = i >> 12, n = i & (N_ - 1);
    size_t idx = ((size_t)(b * 256 + ch)) * N_ + n;
    float v = bf2f(p0[idx]) + bf2f(p1[idx]) + bf2f(p2[idx]) + bf2f(p3[idx]);
    s1 += v; s2 += v * v;
  }
  r1[t] = s1; r2[t] = s2; __syncthreads();
  for (int o = 128; o > 0; o >>= 1){
    if (t < o){ r1[t] += r1[t + o]; r2[t] += r2[t + o]; }
    __syncthreads();
  }
  if (t == 0){
    float mean = r1[0] / (float)(B_ * N_);
    float var = r2[0] / (float)(B_ * N_) - mean * mean;
    stats[ch * 2] = mean;
    stats[ch * 2 + 1] = rsqrtf(var + 1e-5f);
  }
}

// ---------- fused dual-head: relu(bn(mid)) -> 1x1 conv to 2 ch per head ----------
__global__ __launch_bounds__(256) void k_headF(
    const u16* __restrict__ p0, const u16* __restrict__ p1,
    const u16* __restrict__ p2, const u16* __restrict__ p3,
    const float* __restrict__ stats,
    const float* __restrict__ hm_g, const float* __restrict__ hm_b,
    const float* __restrict__ hm2_w, const float* __restrict__ hm2_b,
    const float* __restrict__ hv_g, const float* __restrict__ hv_b,
    const float* __restrict__ hv2_w, const float* __restrict__ hv2_b,
    float* __restrict__ outhm, float* __restrict__ outhv)
{
  int t = threadIdx.x;
  int nl = t & 31, g = t >> 5;
  int idx0 = blockIdx.x * 32;
  int idx = idx0 + nl;
  int b = idx >> 12, n = idx & (N_ - 1);
  int head = g >> 2;
  int ch0 = (g & 3) * 32;
  const float* gg = head ? hv_g : hm_g;
  const float* gb = head ? hv_b : hm_b;
  const float* w2 = head ? hv2_w : hm2_w;
  float a0 = 0.f, a1 = 0.f;
  #pragma unroll 8
  for (int cc = 0; cc < 32; cc++){
    int ch = ch0 + cc;
    int fc = head * CH_ + ch;
    size_t id = ((size_t)(b * 256 + fc)) * N_ + n;
    float v = bf2f(p0[id]) + bf2f(p1[id]) + bf2f(p2[id]) + bf2f(p3[id]);
    float rr = fmaxf((v - stats[fc * 2]) * stats[fc * 2 + 1] * gg[ch] + gb[ch], 0.f);
    a0 += w2[ch] * rr;
    a1 += w2[CH_ + ch] * rr;
  }
  __shared__ float r0[8][32], r1[8][32];
  r0[g][nl] = a0; r1[g][nl] = a1;
  __syncthreads();
  if (t < 64){
    int hh = t >> 5, n2 = t & 31;
    int base = hh * 4;
    float s0 = r0[base][n2] + r0[base + 1][n2] + r0[base + 2][n2] + r0[base + 3][n2];
    float s1 = r1[base][n2] + r1[base + 1][n2] + r1[base + 2][n2] + r1[base + 3][n2];
    int idx2 = idx0 + n2;
    int b2 = idx2 >> 12, nn = idx2 & (N_ - 1);
    float* op = hh ? outhv : outhm;
    const float* bp = hh ? hv2_b : hm2_b;
    op[(size_t)(b2 * 2) * N_ + nn] = s0 + bp[0];
    op[(size_t)(b2 * 2 + 1) * N_ + nn] = s1 + bp[1];
  }
}

extern "C" void kernel_launch(void* const* d_in, const int* in_sizes, int n_in,
                              void* d_out, int out_size, void* d_ws, size_t ws_size,
                              hipStream_t stream)
{
  const float* img   = (const float*)d_in[0];
  const float* txt   = (const float*)d_in[1];
  const float* dens  = (const float*)d_in[2];
  const float* tp_w  = (const float*)d_in[3];
  const float* tp_b  = (const float*)d_in[4];
  const float* wv    = (const float*)d_in[9];
  const float* bv    = (const float*)d_in[10];
  const float* wo    = (const float*)d_in[11];
  const float* bo    = (const float*)d_in[12];
  const float* ln_g  = (const float*)d_in[13];
  const float* ln_b  = (const float*)d_in[14];
  const float* op_w  = (const float*)d_in[15];
  const float* op_b  = (const float*)d_in[16];
  const float* hm1_w = (const float*)d_in[17];
  const float* hm1_b = (const float*)d_in[18];
  const float* hm_g  = (const float*)d_in[19];
  const float* hm_b  = (const float*)d_in[20];
  const float* hm2_w = (const float*)d_in[21];
  const float* hm2_b = (const float*)d_in[22];
  const float* hv1_w = (const float*)d_in[23];
  const float* hv1_b = (const float*)d_in[24];
  const float* hv_g  = (const float*)d_in[25];
  const float* hv_b  = (const float*)d_in[26];
  const float* hv2_w = (const float*)d_in[27];
  const float* hv2_b = (const float*)d_in[28];
  const float* temp  = (const float*)d_in[29];

  char* wsb = (char*)d_ws;
  size_t off = 0;
  auto alloc = [&](size_t bytes) -> void* {
    void* p = wsb + off;
    off += (bytes + 255) & ~(size_t)255;
    return p;
  };
  u8*    Km     = (u8*)   alloc((size_t)B_ * N_ * N_ * sizeof(u8));    // 33.5 MB (fp8)
  u16*   snb16  = (u16*)  alloc((size_t)B_ * N_ * C_ * sizeof(u16));   // 4.19 MB (part0 alias)
  u16*   srcT16 = (u16*)  alloc((size_t)B_ * C_ * N_ * sizeof(u16));   // 4.19 MB
  u16*   usrcT  = (u16*)  alloc((size_t)B_ * C_ * N_ * sizeof(u16));   // 4.19 MB
  u16*   part1  = (u16*)  alloc((size_t)B_ * N_ * C_ * sizeof(u16));   // 4.19 MB
  u16*   part2  = (u16*)  alloc((size_t)B_ * N_ * C_ * sizeof(u16));   // 4.19 MB
  u16*   part3  = (u16*)  alloc((size_t)B_ * N_ * C_ * sizeof(u16));   // 4.19 MB
  u16*   inTp   = (u16*)  alloc((size_t)B_ * PXTOT * C_ * sizeof(u16));// 4.52 MB
  u16*   Wt     = (u16*)  alloc((size_t)9 * 256 * C_ * sizeof(u16));   // 1.18 MB
  u16*   opwB   = (u16*)  alloc((size_t)C_ * C_ * sizeof(u16));        // 131 KB
  float* biasF  = (float*)alloc(256 * sizeof(float));
  float* txt_emb= (float*)alloc(B_ * C_ * sizeof(float));
  float* attn_c = (float*)alloc(B_ * C_ * sizeof(float));
  float* txt_n  = (float*)alloc(B_ * C_ * sizeof(float));
  float* cosv   = (float*)alloc(B_ * N_ * sizeof(float));
  float* qm     = (float*)alloc(B_ * N_ * sizeof(float));
  float* pm     = (float*)alloc(B_ * N_ * sizeof(float));
  float* uu     = (float*)alloc(B_ * N_ * sizeof(float));
  float* vvv    = (float*)alloc(B_ * N_ * sizeof(float));
  float* colsum = (float*)alloc(B_ * N_ * sizeof(float));
  float* stats  = (float*)alloc(256 * 2 * sizeof(float));

  // alias: part0 over snb16 (snb dead after kgen; part0 written by k_full)
  u16* part0 = snb16;

  float* outf  = (float*)d_out;
  float* outhm = outf + (size_t)B_ * C_ * N_;
  float* outhv = outhm + (size_t)B_ * 2 * N_;

  k_text<<<B_, 256, 0, stream>>>(txt, tp_w, tp_b, wv, bv, wo, bo, txt_emb, attn_c, txt_n);
  k_source<<<dim3(N_ / TN, B_), 256, 0, stream>>>(img, attn_c, ln_g, ln_b, txt_n, srcT16, snb16, cosv);
  k_qmarg<<<B_, 256, 0, stream>>>(dens, qm);
  k_pmarg<<<B_, 256, 0, stream>>>(cosv, temp, pm);
  k_zero<<<(B_ * N_ + 255) / 256, 256, 0, stream>>>(colsum, B_ * N_);
  // conv/opconv prep with no deps on GEMM chain
  k_wtr<<<9 * 256, 256, 0, stream>>>(hm1_w, hv1_w, hm1_b, hv1_b, Wt, biasF);
  k_wcast<<<C_ * C_ / 256, 256, 0, stream>>>(op_w, opwB);
  k_zero<<<((int)((size_t)B_ * PXTOT * C_ / 2) + 255) / 256, 256, 0, stream>>>((float*)inTp, (int)((size_t)B_ * PXTOT * C_ / 2));
  // K generation (fp8 e4m3 output, full grid)
  k_kgen<<<dim3(N_ / 128, N_ / 128, B_), 256, 0, stream>>>(snb16, Km, colsum);
  // Sinkhorn (K symmetric: K^T x == K x)
  k_div<<<(B_ * N_ + 255) / 256, 256, 0, stream>>>(qm, colsum, vvv);        // vv1
  k_mv<<<B_ * N_ / 8, 256, 0, stream>>>(Km, vvv, pm, uu);                   // u1
  k_mv<<<B_ * N_ / 8, 256, 0, stream>>>(Km, uu, qm, vvv);                   // vv2
  k_mv<<<B_ * N_ / 8, 256, 0, stream>>>(Km, vvv, pm, uu);                   // u2
  k_mv<<<B_ * N_ / 8, 256, 0, stream>>>(Km, uu, qm, vvv);                   // vv3
  k_mv<<<B_ * N_ / 8, 256, 0, stream>>>(Km, vvv, pm, uu);                   // u3
  k_uscale<<<(B_ * C_ * N_ / 8 + 255) / 256, 256, 0, stream>>>(srcT16, uu, usrcT);
  k_full<<<dim3(N_ / 64, 1, B_ * KSPLIT), 512, 0, stream>>>(Km, usrcT, vvv, part0, part1, part2, part3);
  k_opconv<<<dim3(N_ / 64, C_ / 128, B_), 256, 0, stream>>>(opwB, op_b, part0, part1, part2, part3, img, outf);
  // fused heads: transpose -> implicit-GEMM conv (both heads) -> BN stats -> heads
  k_tr<<<dim3(N_ / 64, 4, B_), 256, 0, stream>>>(outf, inTp);
  k_conv3m<<<dim3(33, 2, B_ * KSPLIT), 256, 0, stream>>>(inTp, Wt, biasF, part0, part1, part2, part3);
  k_bnstats2<<<256, 256, 0, stream>>>(part0, part1, part2, part3, stats);
  k_headF<<<B_ * N_ / 32, 256, 0, stream>>>(part0, part1, part2, part3, stats,
      hm_g, hm_b, hm2_w, hm2_b, hv_g, hv_b, hv2_w, hv2_b, outhm, outhv);
}

// Round 10
// 242.382 us; speedup vs baseline: 1.2441x; 1.2441x over previous
//
#include <hip/hip_runtime.h>

#define B_ 2
#define C_ 256
#define N_ 4096
#define TXT_ 512
#define CH_ 128
#define TN 32
#define KSPLIT 4
#define PXR 4224          // 64 * 66 padded-pixel rows per batch
#define PXPAD 96          // halo pad rows each side
#define PXTOT (PXR + 2 * PXPAD)
#define L2E 28.853900817779268f

typedef unsigned short u16;
typedef unsigned char u8;
typedef __attribute__((ext_vector_type(8))) short short8;
typedef __attribute__((ext_vector_type(4))) float f32x4;
typedef __attribute__((ext_vector_type(2))) float f32x2;

__device__ __forceinline__ float bf2f(u16 v){
  union { unsigned u; float f; } w; w.u = ((unsigned)v) << 16; return w.f;
}
__device__ __forceinline__ u16 f2bf(float f){
  union { float f; unsigned u; } w; w.f = f;
  unsigned r = w.u + 0x7fffu + ((w.u >> 16) & 1u);
  return (u16)(r >> 16);
}

#define MFMA_BF16(a,b,c) __builtin_amdgcn_mfma_f32_16x16x32_bf16(a,b,c,0,0,0)

// Stage a 128-row x 64-col bf16 tile (256 threads). Pre-swizzled source, linear LDS dest.
__device__ __forceinline__ void stage_tile(const u16* __restrict__ g, int stride, u16* lds, int t)
{
  #pragma unroll
  for (int q = 0; q < 4; q++){
    int e = q * 256 + t;          // 16B unit index
    int row = e >> 3;
    int slot = e & 7;
    const u16* gp = g + (size_t)row * stride + ((slot ^ (row & 7)) << 3);
    u16* lp = lds + (size_t)e * 8;
    __builtin_amdgcn_global_load_lds((const __attribute__((address_space(1))) void*)gp,
                                     (__attribute__((address_space(3))) void*)lp, 16, 0, 0);
  }
}

// 512-thread variant: 256 rows.
__device__ __forceinline__ void stage_tile512_256(const u16* __restrict__ g, int stride, u16* lds, int t)
{
  #pragma unroll
  for (int q = 0; q < 4; q++){
    int e = q * 512 + t;          // 2048 units
    int row = e >> 3;
    int slot = e & 7;
    const u16* gp = g + (size_t)row * stride + ((slot ^ (row & 7)) << 3);
    u16* lp = lds + (size_t)e * 8;
    __builtin_amdgcn_global_load_lds((const __attribute__((address_space(1))) void*)gp,
                                     (__attribute__((address_space(3))) void*)lp, 16, 0, 0);
  }
}

__device__ __forceinline__ short8 frag_ld(const u16* lds, int row, int slot)
{
  return *(const short8*)(lds + row * 64 + ((slot ^ (row & 7)) << 3));
}

// ---------- text pipeline: txt_emb, attn constant (v@wo^T+bo), txt_n ----------
__global__ __launch_bounds__(256) void k_text(
    const float* __restrict__ txt, const float* __restrict__ tpw,
    const float* __restrict__ tpb, const float* __restrict__ wv,
    const float* __restrict__ bv, const float* __restrict__ wo,
    const float* __restrict__ bo,
    float* __restrict__ txt_emb, float* __restrict__ attn_c, float* __restrict__ txt_n)
{
  int b = blockIdx.x, t = threadIdx.x;
  __shared__ float te[C_], vs[C_], red[C_];
  const float* tb = txt + b * TXT_;
  const float* wr = tpw + (size_t)t * TXT_;
  float s = 0.f;
  for (int j = 0; j < TXT_; j++) s += tb[j] * wr[j];
  s += tpb[t];
  te[t] = s;
  txt_emb[b * C_ + t] = s;
  __syncthreads();
  float sv = 0.f;
  const float* wvr = wv + (size_t)t * C_;
  for (int j = 0; j < C_; j++) sv += te[j] * wvr[j];
  sv += bv[t];
  vs[t] = sv;
  __syncthreads();
  float sa = 0.f;
  const float* wor = wo + (size_t)t * C_;
  for (int j = 0; j < C_; j++) sa += vs[j] * wor[j];
  sa += bo[t];
  attn_c[b * C_ + t] = sa;
  red[t] = te[t] * te[t];
  __syncthreads();
  for (int o = 128; o > 0; o >>= 1){ if (t < o) red[t] += red[t + o]; __syncthreads(); }
  float nrm = sqrtf(red[0]);
  float inv = 1.f / fmaxf(nrm, 1e-12f);
  txt_n[b * C_ + t] = te[t] * inv;
}

// ---------- source (residual+LN) -> srcT bf16 [C][N], snb bf16 [N][C], cos ----------
__global__ __launch_bounds__(256) void k_source(
    const float* __restrict__ img, const float* __restrict__ attn_c,
    const float* __restrict__ ln_g, const float* __restrict__ ln_b,
    const float* __restrict__ txt_n,
    u16* __restrict__ srcT, u16* __restrict__ snb, float* __restrict__ cosv)
{
  int b = blockIdx.y;
  int n0 = blockIdx.x * TN;
  int t = threadIdx.x;
  __shared__ float x[C_][TN + 1];
  __shared__ float ps[8][TN];
  __shared__ float ps2[8][TN];
  __shared__ float ac_s[C_], g_s[C_], bb_s[C_], tn_s[C_];
  __shared__ float mean_s[TN], rstd_s[TN], rn_s[TN];
  ac_s[t] = attn_c[b * C_ + t];
  g_s[t]  = ln_g[t];
  bb_s[t] = ln_b[t];
  tn_s[t] = txt_n[b * C_ + t];
  const float* ib = img + (size_t)b * C_ * N_ + n0;
  for (int k = 0; k < TN; k++){
    int e = t + k * 256;
    int c = e >> 5, nn = e & 31;
    x[c][nn] = ib[(size_t)c * N_ + nn];
  }
  __syncthreads();
  for (int k = 0; k < TN; k++){
    int e = t + k * 256;
    int c = e >> 5, nn = e & 31;
    x[c][nn] += ac_s[c];
  }
  __syncthreads();
  {
    int p = t >> 5, nn = t & 31;
    float s1 = 0.f, s2 = 0.f;
    for (int j = 0; j < 32; j++){
      float v = x[p + 8 * j][nn];
      s1 += v; s2 += v * v;
    }
    ps[p][nn] = s1; ps2[p][nn] = s2;
  }
  __syncthreads();
  if (t < TN){
    float S1 = 0.f, S2 = 0.f;
    for (int pp = 0; pp < 8; pp++){ S1 += ps[pp][t]; S2 += ps2[pp][t]; }
    float mean = S1 * (1.f / C_);
    float var = S2 * (1.f / C_) - mean * mean;
    mean_s[t] = mean;
    rstd_s[t] = rsqrtf(var + 1e-5f);
  }
  __syncthreads();
  for (int k = 0; k < TN; k++){
    float sval = (x[t][k] - mean_s[k]) * rstd_s[k] * g_s[t] + bb_s[t];
    x[t][k] = sval;
  }
  for (int kq = 0; kq < TN; kq += 4){
    ushort4 pkv;
    pkv.x = f2bf(x[t][kq + 0]);
    pkv.y = f2bf(x[t][kq + 1]);
    pkv.z = f2bf(x[t][kq + 2]);
    pkv.w = f2bf(x[t][kq + 3]);
    *reinterpret_cast<ushort4*>(&srcT[(size_t)(b * C_ + t) * N_ + n0 + kq]) = pkv;
  }
  __syncthreads();
  {
    int p = t >> 5, nn = t & 31;
    float s2 = 0.f, sd = 0.f;
    for (int j = 0; j < 32; j++){
      int c = p + 8 * j;
      float v = x[c][nn];
      s2 += v * v; sd += v * tn_s[c];
    }
    ps[p][nn] = s2; ps2[p][nn] = sd;
  }
  __syncthreads();
  if (t < TN){
    float S2 = 0.f, SD = 0.f;
    for (int pp = 0; pp < 8; pp++){ S2 += ps[pp][t]; SD += ps2[pp][t]; }
    float nrm = sqrtf(S2);
    float rn = 1.f / fmaxf(nrm, 1e-12f);
    rn_s[t] = rn;
    cosv[(b << 12) + n0 + t] = SD * rn;
  }
  __syncthreads();
  for (int k = 0; k < TN; k++){
    snb[(size_t)((b << 12) + n0 + k) * C_ + t] = f2bf(x[t][k] * rn_s[k]);
  }
}

// ---------- marginals ----------
__global__ __launch_bounds__(256) void k_qmarg(const float* __restrict__ dens, float* __restrict__ q){
  int b = blockIdx.x, t = threadIdx.x;
  __shared__ float red[256];
  const float* d = dens + (size_t)b * N_;
  float s = 0.f;
  for (int n = t; n < N_; n += 256) s += fmaxf(d[n], 0.f) + 1e-6f;
  red[t] = s; __syncthreads();
  for (int o = 128; o > 0; o >>= 1){ if (t < o) red[t] += red[t + o]; __syncthreads(); }
  float inv = 1.f / red[0];
  for (int n = t; n < N_; n += 256) q[b * N_ + n] = (fmaxf(d[n], 0.f) + 1e-6f) * inv;
}

__global__ __launch_bounds__(256) void k_pmarg(const float* __restrict__ cosv,
    const float* __restrict__ temp_p, float* __restrict__ p){
  int b = blockIdx.x, t = threadIdx.x;
  __shared__ float red[256];
  float temp = fmaxf(temp_p[0], 0.01f);
  float inv_t = 1.f / temp;
  const float* cb = cosv + (size_t)b * N_;
  float m = -1e30f;
  for (int n = t; n < N_; n += 256) m = fmaxf(m, cb[n] * inv_t);
  red[t] = m; __syncthreads();
  for (int o = 128; o > 0; o >>= 1){ if (t < o) red[t] = fmaxf(red[t], red[t + o]); __syncthreads(); }
  m = red[0]; __syncthreads();
  float s = 0.f;
  for (int n = t; n < N_; n += 256) s += expf(cb[n] * inv_t - m);
  red[t] = s; __syncthreads();
  for (int o = 128; o > 0; o >>= 1){ if (t < o) red[t] += red[t + o]; __syncthreads(); }
  float invs = 1.f / red[0];
  for (int n = t; n < N_; n += 256) p[b * N_ + n] = expf(cb[n] * inv_t - m) * invs;
}

__global__ __launch_bounds__(256) void k_zero(float* __restrict__ p, int n){
  int i = blockIdx.x * 256 + threadIdx.x;
  if (i < n) p[i] = 0.f;
}

// ---------- K = exp(20*(sn sn^T - 1)) -> FP8 e4m3 via MFMA + column sums ----------
// Full grid. HW converters (v_exp_f32 + cvt_pk_fp8_f32); each block stores the
// TRANSPOSED tile (K symmetric; mirror block produces the bit-identical values),
// so each lane's 4 consecutive rows pack into one u32 word -> 16 ds_write_b32.
__global__ __launch_bounds__(256) void k_kgen(
    const u16* __restrict__ snb, u8* __restrict__ Kp, float* __restrict__ colsum)
{
  int b = blockIdx.z;
  int m0 = blockIdx.x << 7, n0 = blockIdx.y << 7;
  int t = threadIdx.x;
  int lane = t & 63, w = t >> 6;
  int wr = w >> 1, wc = w & 1;
  __shared__ __align__(16) u16 shbuf[128 * 128];   // 32 KB: Al|Bl, low 16KB reused as CtT
  u16* Al = shbuf;
  u16* Bl = shbuf + 128 * 64;
  __shared__ float cs[128];
  if (t < 128) cs[t] = 0.f;
  f32x4 zero = {0.f, 0.f, 0.f, 0.f};
  f32x4 acc[4][4];
  #pragma unroll
  for (int i = 0; i < 4; i++){
    #pragma unroll
    for (int j = 0; j < 4; j++) acc[i][j] = zero;
  }
  const u16* sb = snb + (size_t)b * N_ * C_;
  const u16* ga = sb + (size_t)m0 * C_;
  const u16* gb = sb + (size_t)n0 * C_;
  for (int kt = 0; kt < C_; kt += 64){
    stage_tile(ga + kt, C_, Al, t);
    stage_tile(gb + kt, C_, Bl, t);
    __syncthreads();
    #pragma unroll
    for (int kh = 0; kh < 2; kh++){
      short8 af[4], bfv[4];
      #pragma unroll
      for (int i = 0; i < 4; i++){
        af[i]  = frag_ld(Al, wr * 64 + i * 16 + (lane & 15), kh * 4 + (lane >> 4));
        bfv[i] = frag_ld(Bl, wc * 64 + i * 16 + (lane & 15), kh * 4 + (lane >> 4));
      }
      #pragma unroll
      for (int i = 0; i < 4; i++){
        #pragma unroll
        for (int j = 0; j < 4; j++)
          acc[i][j] = MFMA_BF16(af[i], bfv[j], acc[i][j]);
      }
    }
    __syncthreads();
  }
  // epilogue: exp2 -> hw fp8 pack -> transposed tile CtT[col][row] (word-swizzled)
  u8* CtT = (u8*)shbuf;
  #pragma unroll
  for (int j = 0; j < 4; j++){
    int col = wc * 64 + j * 16 + (lane & 15);
    float csum = 0.f;
    #pragma unroll
    for (int i = 0; i < 4; i++){
      int rb = wr * 64 + i * 16 + (lane >> 4) * 4;
      float e0 = __builtin_amdgcn_exp2f(fmaf(acc[i][j][0], L2E, -L2E));
      float e1 = __builtin_amdgcn_exp2f(fmaf(acc[i][j][1], L2E, -L2E));
      float e2 = __builtin_amdgcn_exp2f(fmaf(acc[i][j][2], L2E, -L2E));
      float e3 = __builtin_amdgcn_exp2f(fmaf(acc[i][j][3], L2E, -L2E));
      int pk = __builtin_amdgcn_cvt_pk_fp8_f32(e0, e1, 0, false);
      pk = __builtin_amdgcn_cvt_pk_fp8_f32(e2, e3, pk, true);
      f32x2 d0 = __builtin_amdgcn_cvt_pk_f32_fp8(pk, false);
      f32x2 d1 = __builtin_amdgcn_cvt_pk_f32_fp8(pk, true);
      csum += (d0.x + d0.y) + (d1.x + d1.y);
      int wq = rb >> 2;
      *reinterpret_cast<unsigned*>(CtT + col * 128 + ((wq ^ ((col & 7) << 2)) << 2)) = (unsigned)pk;
    }
    atomicAdd(&cs[col], csum);
  }
  __syncthreads();
  u8* Kb = Kp + (size_t)b * N_ * N_;
  // store transposed tile: K[n0+row][m0..] gets column `row` of this tile
  for (int e = t; e < 1024; e += 256){
    int row = e >> 3, un = e & 7;
    uint4 v = *(const uint4*)(CtT + row * 128 + ((un ^ (row & 7)) << 4));
    *reinterpret_cast<uint4*>(&Kb[(size_t)(n0 + row) * N_ + m0 + (un << 4)]) = v;
  }
  if (t < 128) atomicAdd(&colsum[b * N_ + n0 + t], cs[t]);
}

__global__ __launch_bounds__(256) void k_div(
    const float* __restrict__ marg, const float* __restrict__ denom, float* __restrict__ outp){
  int i = blockIdx.x * 256 + threadIdx.x;
  if (i < B_ * N_) outp[i] = marg[i] / (denom[i] + 1e-8f);
}

// ---------- out[r] = marg[r] / (K_row_r . x + 1e-8)  (K symmetric, fp8), 8 rows/block ----------
__global__ __launch_bounds__(256) void k_mv(
    const u8* __restrict__ Kp, const float* __restrict__ x,
    const float* __restrict__ marg, float* __restrict__ outp)
{
  int r0 = blockIdx.x * 8;
  int b = r0 >> 12;
  int t = threadIdx.x, w = t >> 6, lane = t & 63;
  __shared__ __align__(16) float xs[N_];
  const float* xb = x + b * N_;
  for (int i = t; i < N_ / 4; i += 256)
    reinterpret_cast<float4*>(xs)[i] = reinterpret_cast<const float4*>(xb)[i];
  __syncthreads();
  int r = r0 + w * 2;
  const u8* Kr0 = Kp + (size_t)b * N_ * N_ + (size_t)(r & (N_ - 1)) * N_;
  const u8* Kr1 = Kr0 + N_;
  float acc0 = 0.f, acc1 = 0.f;
  #pragma unroll
  for (int p = 0; p < 4; p++){
    int idx = p * 1024 + lane * 16;
    uint4 a = *reinterpret_cast<const uint4*>(Kr0 + idx);
    uint4 c = *reinterpret_cast<const uint4*>(Kr1 + idx);
    #pragma unroll
    for (int q = 0; q < 4; q++){
      unsigned aw = (q == 0) ? a.x : (q == 1) ? a.y : (q == 2) ? a.z : a.w;
      unsigned cw = (q == 0) ? c.x : (q == 1) ? c.y : (q == 2) ? c.z : c.w;
      float4 xv = *reinterpret_cast<const float4*>(xs + idx + q * 4);
      f32x2 al = __builtin_amdgcn_cvt_pk_f32_fp8((int)aw, false);
      f32x2 ah = __builtin_amdgcn_cvt_pk_f32_fp8((int)aw, true);
      f32x2 cl = __builtin_amdgcn_cvt_pk_f32_fp8((int)cw, false);
      f32x2 ch = __builtin_amdgcn_cvt_pk_f32_fp8((int)cw, true);
      acc0 += al.x * xv.x + al.y * xv.y + ah.x * xv.z + ah.y * xv.w;
      acc1 += cl.x * xv.x + cl.y * xv.y + ch.x * xv.z + ch.y * xv.w;
    }
  }
  for (int o = 32; o > 0; o >>= 1){
    acc0 += __shfl_down(acc0, o);
    acc1 += __shfl_down(acc1, o);
  }
  if (lane == 0){
    outp[r] = marg[r] / (acc0 + 1e-8f);
    outp[r + 1] = marg[r + 1] / (acc1 + 1e-8f);
  }
}

// ---------- usrcT[c][n] = srcT[c][n] * u[n] ----------
__global__ __launch_bounds__(256) void k_uscale(
    const u16* __restrict__ srcT, const float* __restrict__ uu, u16* __restrict__ usrcT)
{
  int i = blockIdx.x * 256 + threadIdx.x;
  int n8 = i & (N_ / 8 - 1);
  int row = i >> 9;
  int b = row >> 8;
  const u16* s = srcT + (size_t)row * N_ + n8 * 8;
  short8 v = *reinterpret_cast<const short8*>(s);
  const float* ub = uu + b * N_ + n8 * 8;
  short8 o;
  #pragma unroll
  for (int q = 0; q < 8; q++) o[q] = (short)f2bf(bf2f((u16)v[q]) * ub[q]);
  *reinterpret_cast<short8*>(usrcT + (size_t)row * N_ + n8 * 8) = o;
}

// ---------- part[ks][m][c] = vv[m] * sum_{n in ks chunk} K[m][n]*usrc[n][c] ----------
// 512 threads, tile 64m x 256c, fp8 K A-operand decoded via hw cvt to bf16.
__global__ __launch_bounds__(512) void k_full(
    const u8* __restrict__ Kp, const u16* __restrict__ usrcT,
    const float* __restrict__ vvv,
    u16* __restrict__ p0, u16* __restrict__ p1,
    u16* __restrict__ p2, u16* __restrict__ p3)
{
  int m0 = blockIdx.x << 6;
  int b = blockIdx.z >> 2, ks = blockIdx.z & 3;
  int t = threadIdx.x, lane = t & 63, w = t >> 6;   // w: 0..7 -> c-stripe of 32
  __shared__ __align__(16) u16 shbuf[64 * 64 + 256 * 64];  // Al 8KB | Bl 32KB
  __shared__ float vsm[64];
  u16* Al = shbuf;
  u16* Bl = shbuf + 64 * 64;
  if (t < 64) vsm[t] = vvv[b * N_ + m0 + t];
  f32x4 zero = {0.f, 0.f, 0.f, 0.f};
  f32x4 acc[4][2];
  #pragma unroll
  for (int i = 0; i < 4; i++){
    #pragma unroll
    for (int j = 0; j < 2; j++) acc[i][j] = zero;
  }
  const u8* ka = Kp + (size_t)b * N_ * N_ + (size_t)m0 * N_ + ks * (N_ / KSPLIT);
  const u16* ub = usrcT + (size_t)b * C_ * N_ + ks * (N_ / KSPLIT);
  for (int kt = 0; kt < N_ / KSPLIT; kt += 64){
    // A: 64x64 fp8 -> hw decode to bf16, reg-stage into swizzled-content linear LDS
    {
      int row = t >> 3, slot = t & 7;
      const u8* gp = ka + (size_t)row * N_ + kt + ((slot ^ (row & 7)) << 3);
      uint2 v8 = *reinterpret_cast<const uint2*>(gp);
      f32x2 q0 = __builtin_amdgcn_cvt_pk_f32_fp8((int)v8.x, false);
      f32x2 q1 = __builtin_amdgcn_cvt_pk_f32_fp8((int)v8.x, true);
      f32x2 q2 = __builtin_amdgcn_cvt_pk_f32_fp8((int)v8.y, false);
      f32x2 q3 = __builtin_amdgcn_cvt_pk_f32_fp8((int)v8.y, true);
      union { short8 s; unsigned u[4]; } o;
      asm("v_cvt_pk_bf16_f32 %0, %1, %2" : "=v"(o.u[0]) : "v"(q0.x), "v"(q0.y));
      asm("v_cvt_pk_bf16_f32 %0, %1, %2" : "=v"(o.u[1]) : "v"(q1.x), "v"(q1.y));
      asm("v_cvt_pk_bf16_f32 %0, %1, %2" : "=v"(o.u[2]) : "v"(q2.x), "v"(q2.y));
      asm("v_cvt_pk_bf16_f32 %0, %1, %2" : "=v"(o.u[3]) : "v"(q3.x), "v"(q3.y));
      *reinterpret_cast<short8*>(Al + (size_t)t * 8) = o.s;
    }
    stage_tile512_256(ub + kt, N_, Bl, t);
    __syncthreads();
    #pragma unroll
    for (int kh = 0; kh < 2; kh++){
      short8 af[4], bfv[2];
      #pragma unroll
      for (int i = 0; i < 4; i++)
        af[i] = frag_ld(Al, i * 16 + (lane & 15), kh * 4 + (lane >> 4));
      #pragma unroll
      for (int j = 0; j < 2; j++)
        bfv[j] = frag_ld(Bl, w * 32 + j * 16 + (lane & 15), kh * 4 + (lane >> 4));
      #pragma unroll
      for (int i = 0; i < 4; i++){
        #pragma unroll
        for (int j = 0; j < 2; j++)
          acc[i][j] = MFMA_BF16(af[i], bfv[j], acc[i][j]);
      }
    }
    __syncthreads();
  }
  // restage [64m][256c] bf16 (vv-scaled) into swizzled Ct, then fully-linear stores
  u16* Ct = shbuf;
  #pragma unroll
  for (int j = 0; j < 2; j++){
    int col = w * 32 + j * 16 + (lane & 15);
    #pragma unroll
    for (int i = 0; i < 4; i++){
      int rb = i * 16 + (lane >> 4) * 4;
      #pragma unroll
      for (int r = 0; r < 4; r++){
        int row = rb + r;
        Ct[row * 256 + ((((col >> 3) ^ (row & 7)) << 3) | (col & 7))] =
            f2bf(acc[i][j][r] * vsm[row]);
      }
    }
  }
  __syncthreads();
  u16* P = (ks == 0) ? p0 : (ks == 1) ? p1 : (ks == 2) ? p2 : p3;
  for (int e = t; e < 2048; e += 512){
    int row = e >> 5, un = e & 31;
    short8 v8 = *(const short8*)(Ct + row * 256 + ((un ^ (row & 7)) << 3));
    *reinterpret_cast<short8*>(&P[(size_t)((b << 12) + m0 + row) * C_ + (un << 3)]) = v8;
  }
}

// ---------- cast opw (f32 256x256) to bf16 ----------
__global__ __launch_bounds__(256) void k_wcast(const float* __restrict__ w, u16* __restrict__ o){
  int i = blockIdx.x * 256 + threadIdx.x;
  o[i] = f2bf(w[i]);
}

// ---------- out_feat = img + 1x1conv(p0+p1+p2+p3) via MFMA; tile 64n x 128co ----------
__global__ __launch_bounds__(256) void k_opconv(
    const u16* __restrict__ opwB, const float* __restrict__ opb,
    const u16* __restrict__ p0, const u16* __restrict__ p1,
    const u16* __restrict__ p2, const u16* __restrict__ p3,
    const float* __restrict__ img, float* __restrict__ outf)
{
  int b = blockIdx.z;
  int n0 = blockIdx.x << 6;
  int co0 = blockIdx.y << 7;
  int t = threadIdx.x, lane = t & 63, w = t >> 6;
  int wr = w >> 1, wc = w & 1;              // wr: co half (64), wc: n half (32)
  __shared__ __align__(16) u16 Al[128 * 64];   // opw rows=co
  __shared__ __align__(16) u16 Bl[64 * 64];    // fused rows=n
  f32x4 zero = {0.f, 0.f, 0.f, 0.f};
  f32x4 acc[4][2];
  #pragma unroll
  for (int i = 0; i < 4; i++){
    #pragma unroll
    for (int j = 0; j < 2; j++) acc[i][j] = zero;
  }
  for (int ct = 0; ct < C_; ct += 64){
    stage_tile(opwB + (size_t)co0 * C_ + ct, C_, Al, t);
    // reg-stage B: sum 4 bf16 partials into swizzled layout (512 units, 2 iters)
    #pragma unroll
    for (int q = 0; q < 2; q++){
      int e = q * 256 + t;
      int row = e >> 3, slot = e & 7;
      int col = ct + ((slot ^ (row & 7)) << 3);
      size_t idx = (size_t)((b << 12) + n0 + row) * C_ + col;
      short8 a0 = *reinterpret_cast<const short8*>(p0 + idx);
      short8 a1 = *reinterpret_cast<const short8*>(p1 + idx);
      short8 a2 = *reinterpret_cast<const short8*>(p2 + idx);
      short8 a3 = *reinterpret_cast<const short8*>(p3 + idx);
      short8 o;
      #pragma unroll
      for (int k = 0; k < 8; k++)
        o[k] = (short)f2bf(bf2f((u16)a0[k]) + bf2f((u16)a1[k]) + bf2f((u16)a2[k]) + bf2f((u16)a3[k]));
      *reinterpret_cast<short8*>(Bl + (size_t)e * 8) = o;
    }
    __syncthreads();
    #pragma unroll
    for (int kh = 0; kh < 2; kh++){
      short8 af[4], bfv[2];
      #pragma unroll
      for (int i = 0; i < 4; i++)
        af[i] = frag_ld(Al, wr * 64 + i * 16 + (lane & 15), kh * 4 + (lane >> 4));
      #pragma unroll
      for (int j = 0; j < 2; j++)
        bfv[j] = frag_ld(Bl, wc * 32 + j * 16 + (lane & 15), kh * 4 + (lane >> 4));
      #pragma unroll
      for (int i = 0; i < 4; i++){
        #pragma unroll
        for (int j = 0; j < 2; j++)
          acc[i][j] = MFMA_BF16(af[i], bfv[j], acc[i][j]);
      }
    }
    __syncthreads();
  }
  #pragma unroll
  for (int i = 0; i < 4; i++){
    int cb = co0 + wr * 64 + i * 16 + (lane >> 4) * 4;
    #pragma unroll
    for (int j = 0; j < 2; j++){
      int nc = n0 + wc * 32 + j * 16 + (lane & 15);
      #pragma unroll
      for (int r = 0; r < 4; r++){
        int co = cb + r;
        size_t oi = (size_t)(b * C_ + co) * N_ + nc;
        outf[oi] = acc[i][j][r] + img[oi] + opb[co];
      }
    }
  }
}

// ---------- transpose out_feat -> padded bf16 [b][px'][ci] ----------
__global__ __launch_bounds__(256) void k_tr(const float* __restrict__ outf, u16* __restrict__ inTp)
{
  int b = blockIdx.z;
  int c0 = blockIdx.y << 6;
  int px0 = blockIdx.x << 6;
  int t = threadIdx.x;
  __shared__ float tile[64][65];
  int tx = t & 63, ty4 = t >> 6;
  for (int cc = ty4; cc < 64; cc += 4)
    tile[cc][tx] = outf[((size_t)(b * C_) + c0 + cc) * N_ + px0 + tx];
  __syncthreads();
  int p = t >> 2, cg = (t & 3) << 4;
  int px = px0 + p;
  int y = px >> 6, x = px & 63;
  int pxp = y * 66 + x + 1;
  u16* dst = inTp + ((size_t)b * PXTOT + PXPAD + pxp) * C_ + c0 + cg;
  #pragma unroll
  for (int q = 0; q < 16; q += 4){
    ushort4 pk;
    pk.x = f2bf(tile[cg + q + 0][p]);
    pk.y = f2bf(tile[cg + q + 1][p]);
    pk.z = f2bf(tile[cg + q + 2][p]);
    pk.w = f2bf(tile[cg + q + 3][p]);
    *reinterpret_cast<ushort4*>(dst + q) = pk;
  }
}

// ---------- weights -> Wt[tap][co(256 fused)][ci] bf16, fused bias ----------
__global__ __launch_bounds__(256) void k_wtr(
    const float* __restrict__ hm1_w, const float* __restrict__ hv1_w,
    const float* __restrict__ hm1_b, const float* __restrict__ hv1_b,
    u16* __restrict__ Wt, float* __restrict__ biasF)
{
  int i = blockIdx.x * 256 + threadIdx.x;   // < 9*256*256
  int ci = i & 255, co = (i >> 8) & 255, tap = i >> 16;
  float v = (co < CH_) ? hm1_w[((size_t)co * C_ + ci) * 9 + tap]
                       : hv1_w[((size_t)(co - CH_) * C_ + ci) * 9 + tap];
  Wt[i] = f2bf(v);
  if (i < CH_) biasF[i] = hm1_b[i];
  else if (i < 2 * CH_) biasF[i] = hv1_b[i - CH_];
}

// ---------- fused 3x3 conv (both heads) as implicit GEMM: C[co][px'] (bf16 out) ----------
__global__ __launch_bounds__(256) void k_conv3m(
    const u16* __restrict__ inTp, const u16* __restrict__ Wt,
    const float* __restrict__ biasF,
    u16* __restrict__ q0, u16* __restrict__ q1,
    u16* __restrict__ q2, u16* __restrict__ q3)
{
  int px0 = blockIdx.x << 7;           // 0..32 (33 tiles of 128 px')
  int cot = blockIdx.y;                // 0..1 (co halves of 256 fused)
  int b = blockIdx.z >> 2, ks = blockIdx.z & 3;
  int t = threadIdx.x, lane = t & 63, w = t >> 6;
  int wr = w >> 1, wc = w & 1;
  __shared__ __align__(16) u16 Al[128 * 64];   // weights: 128 co rows x 64 ci
  __shared__ __align__(16) u16 Bl[128 * 64];   // input:   128 px rows x 64 ci
  f32x4 zero = {0.f, 0.f, 0.f, 0.f};
  f32x4 acc[4][4];
  #pragma unroll
  for (int i = 0; i < 4; i++){
    #pragma unroll
    for (int j = 0; j < 4; j++) acc[i][j] = zero;
  }
  const u16* inb = inTp + ((size_t)b * PXTOT + PXPAD + px0) * C_;
  for (int s = ks * 9; s < ks * 9 + 9; s++){
    int tap = s >> 2, cic = (s & 3) << 6;
    int ky = tap / 3, kx = tap - ky * 3;
    int off = (ky - 1) * 66 + (kx - 1);
    stage_tile(Wt + ((size_t)tap * 256 + cot * 128) * C_ + cic, C_, Al, t);
    stage_tile(inb + (ptrdiff_t)off * C_ + cic, C_, Bl, t);
    __syncthreads();
    #pragma unroll
    for (int kh = 0; kh < 2; kh++){
      short8 af[4], bfv[4];
      #pragma unroll
      for (int i = 0; i < 4; i++){
        af[i]  = frag_ld(Al, wr * 64 + i * 16 + (lane & 15), kh * 4 + (lane >> 4));
        bfv[i] = frag_ld(Bl, wc * 64 + i * 16 + (lane & 15), kh * 4 + (lane >> 4));
      }
      #pragma unroll
      for (int i = 0; i < 4; i++){
        #pragma unroll
        for (int j = 0; j < 4; j++)
          acc[i][j] = MFMA_BF16(af[i], bfv[j], acc[i][j]);
      }
    }
    __syncthreads();
  }
  u16* P = (ks == 0) ? q0 : (ks == 1) ? q1 : (ks == 2) ? q2 : q3;
  #pragma unroll
  for (int i = 0; i < 4; i++){
    #pragma unroll
    for (int j = 0; j < 4; j++){
      int pxp = px0 + wc * 64 + j * 16 + (lane & 15);
      int y = pxp / 66;
      int xm = pxp - y * 66;
      bool valid = (xm >= 1 && xm <= 64);
      int outn = y * 64 + xm - 1;
      #pragma unroll
      for (int r = 0; r < 4; r++){
        int co = cot * 128 + wr * 64 + i * 16 + (lane >> 4) * 4 + r;
        if (valid){
          float bco = (ks == 0) ? biasF[co] : 0.f;
          P[((size_t)(b * 256 + co)) * N_ + outn] = f2bf(acc[i][j][r] + bco);
        }
      }
    }
  }
}

// ---------- batchnorm stats over (B,H,W) per fused channel (sums 4 K-parts) ----------
__global__ __launch_bounds__(256) void k_bnstats2(
    const u16* __restrict__ p0, const u16* __restrict__ p1,
    const u16* __restrict__ p2, const u16* __restrict__ p3,
    float* __restrict__ stats)
{
  int ch = blockIdx.x, t = threadIdx.x;   // ch in [0,256)
  __shared__ float r1[256], r2[256];
  float s1 = 0.f, s2 = 0.f;
  for (int i = t; i < B_ * N_; i += 256){
    int b = i >> 12, n = i & (N_ - 1);
    size_t idx = ((size_t)(b * 256 + ch)) * N_ + n;
    float v = bf2f(p0[idx]) + bf2f(p1[idx]) + bf2f(p2[idx]) + bf2f(p3[idx]);
    s1 += v; s2 += v * v;
  }
  r1[t] = s1; r2[t] = s2; __syncthreads();
  for (int o = 128; o > 0; o >>= 1){
    if (t < o){ r1[t] += r1[t + o]; r2[t] += r2[t + o]; }
    __syncthreads();
  }
  if (t == 0){
    float mean = r1[0] / (float)(B_ * N_);
    float var = r2[0] / (float)(B_ * N_) - mean * mean;
    stats[ch * 2] = mean;
    stats[ch * 2 + 1] = rsqrtf(var + 1e-5f);
  }
}

// ---------- fused dual-head: relu(bn(mid)) -> 1x1 conv to 2 ch per head ----------
__global__ __launch_bounds__(256) void k_headF(
    const u16* __restrict__ p0, const u16* __restrict__ p1,
    const u16* __restrict__ p2, const u16* __restrict__ p3,
    const float* __restrict__ stats,
    const float* __restrict__ hm_g, const float* __restrict__ hm_b,
    const float* __restrict__ hm2_w, const float* __restrict__ hm2_b,
    const float* __restrict__ hv_g, const float* __restrict__ hv_b,
    const float* __restrict__ hv2_w, const float* __restrict__ hv2_b,
    float* __restrict__ outhm, float* __restrict__ outhv)
{
  int t = threadIdx.x;
  int nl = t & 31, g = t >> 5;
  int idx0 = blockIdx.x * 32;
  int idx = idx0 + nl;
  int b = idx >> 12, n = idx & (N_ - 1);
  int head = g >> 2;
  int ch0 = (g & 3) * 32;
  const float* gg = head ? hv_g : hm_g;
  const float* gb = head ? hv_b : hm_b;
  const float* w2 = head ? hv2_w : hm2_w;
  float a0 = 0.f, a1 = 0.f;
  #pragma unroll 8
  for (int cc = 0; cc < 32; cc++){
    int ch = ch0 + cc;
    int fc = head * CH_ + ch;
    size_t id = ((size_t)(b * 256 + fc)) * N_ + n;
    float v = bf2f(p0[id]) + bf2f(p1[id]) + bf2f(p2[id]) + bf2f(p3[id]);
    float rr = fmaxf((v - stats[fc * 2]) * stats[fc * 2 + 1] * gg[ch] + gb[ch], 0.f);
    a0 += w2[ch] * rr;
    a1 += w2[CH_ + ch] * rr;
  }
  __shared__ float r0[8][32], r1[8][32];
  r0[g][nl] = a0; r1[g][nl] = a1;
  __syncthreads();
  if (t < 64){
    int hh = t >> 5, n2 = t & 31;
    int base = hh * 4;
    float s0 = r0[base][n2] + r0[base + 1][n2] + r0[base + 2][n2] + r0[base + 3][n2];
    float s1 = r1[base][n2] + r1[base + 1][n2] + r1[base + 2][n2] + r1[base + 3][n2];
    int idx2 = idx0 + n2;
    int b2 = idx2 >> 12, nn = idx2 & (N_ - 1);
    float* op = hh ? outhv : outhm;
    const float* bp = hh ? hv2_b : hm2_b;
    op[(size_t)(b2 * 2) * N_ + nn] = s0 + bp[0];
    op[(size_t)(b2 * 2 + 1) * N_ + nn] = s1 + bp[1];
  }
}

extern "C" void kernel_launch(void* const* d_in, const int* in_sizes, int n_in,
                              void* d_out, int out_size, void* d_ws, size_t ws_size,
                              hipStream_t stream)
{
  const float* img   = (const float*)d_in[0];
  const float* txt   = (const float*)d_in[1];
  const float* dens  = (const float*)d_in[2];
  const float* tp_w  = (const float*)d_in[3];
  const float* tp_b  = (const float*)d_in[4];
  const float* wv    = (const float*)d_in[9];
  const float* bv    = (const float*)d_in[10];
  const float* wo    = (const float*)d_in[11];
  const float* bo    = (const float*)d_in[12];
  const float* ln_g  = (const float*)d_in[13];
  const float* ln_b  = (const float*)d_in[14];
  const float* op_w  = (const float*)d_in[15];
  const float* op_b  = (const float*)d_in[16];
  const float* hm1_w = (const float*)d_in[17];
  const float* hm1_b = (const float*)d_in[18];
  const float* hm_g  = (const float*)d_in[19];
  const float* hm_b  = (const float*)d_in[20];
  const float* hm2_w = (const float*)d_in[21];
  const float* hm2_b = (const float*)d_in[22];
  const float* hv1_w = (const float*)d_in[23];
  const float* hv1_b = (const float*)d_in[24];
  const float* hv_g  = (const float*)d_in[25];
  const float* hv_b  = (const float*)d_in[26];
  const float* hv2_w = (const float*)d_in[27];
  const float* hv2_b = (const float*)d_in[28];
  const float* temp  = (const float*)d_in[29];

  char* wsb = (char*)d_ws;
  size_t off = 0;
  auto alloc = [&](size_t bytes) -> void* {
    void* p = wsb + off;
    off += (bytes + 255) & ~(size_t)255;
    return p;
  };
  u8*    Km     = (u8*)   alloc((size_t)B_ * N_ * N_ * sizeof(u8));    // 33.5 MB (fp8)
  u16*   snb16  = (u16*)  alloc((size_t)B_ * N_ * C_ * sizeof(u16));   // 4.19 MB (part0 alias)
  u16*   srcT16 = (u16*)  alloc((size_t)B_ * C_ * N_ * sizeof(u16));   // 4.19 MB
  u16*   usrcT  = (u16*)  alloc((size_t)B_ * C_ * N_ * sizeof(u16));   // 4.19 MB
  u16*   part1  = (u16*)  alloc((size_t)B_ * N_ * C_ * sizeof(u16));   // 4.19 MB
  u16*   part2  = (u16*)  alloc((size_t)B_ * N_ * C_ * sizeof(u16));   // 4.19 MB
  u16*   part3  = (u16*)  alloc((size_t)B_ * N_ * C_ * sizeof(u16));   // 4.19 MB
  u16*   inTp   = (u16*)  alloc((size_t)B_ * PXTOT * C_ * sizeof(u16));// 4.52 MB
  u16*   Wt     = (u16*)  alloc((size_t)9 * 256 * C_ * sizeof(u16));   // 1.18 MB
  u16*   opwB   = (u16*)  alloc((size_t)C_ * C_ * sizeof(u16));        // 131 KB
  float* biasF  = (float*)alloc(256 * sizeof(float));
  float* txt_emb= (float*)alloc(B_ * C_ * sizeof(float));
  float* attn_c = (float*)alloc(B_ * C_ * sizeof(float));
  float* txt_n  = (float*)alloc(B_ * C_ * sizeof(float));
  float* cosv   = (float*)alloc(B_ * N_ * sizeof(float));
  float* qm     = (float*)alloc(B_ * N_ * sizeof(float));
  float* pm     = (float*)alloc(B_ * N_ * sizeof(float));
  float* uu     = (float*)alloc(B_ * N_ * sizeof(float));
  float* vvv    = (float*)alloc(B_ * N_ * sizeof(float));
  float* colsum = (float*)alloc(B_ * N_ * sizeof(float));
  float* stats  = (float*)alloc(256 * 2 * sizeof(float));

  // alias: part0 over snb16 (snb dead after kgen; part0 written by k_full)
  u16* part0 = snb16;

  float* outf  = (float*)d_out;
  float* outhm = outf + (size_t)B_ * C_ * N_;
  float* outhv = outhm + (size_t)B_ * 2 * N_;

  k_text<<<B_, 256, 0, stream>>>(txt, tp_w, tp_b, wv, bv, wo, bo, txt_emb, attn_c, txt_n);
  k_source<<<dim3(N_ / TN, B_), 256, 0, stream>>>(img, attn_c, ln_g, ln_b, txt_n, srcT16, snb16, cosv);
  k_qmarg<<<B_, 256, 0, stream>>>(dens, qm);
  k_pmarg<<<B_, 256, 0, stream>>>(cosv, temp, pm);
  k_zero<<<(B_ * N_ + 255) / 256, 256, 0, stream>>>(colsum, B_ * N_);
  // conv/opconv prep with no deps on GEMM chain
  k_wtr<<<9 * 256, 256, 0, stream>>>(hm1_w, hv1_w, hm1_b, hv1_b, Wt, biasF);
  k_wcast<<<C_ * C_ / 256, 256, 0, stream>>>(op_w, opwB);
  k_zero<<<((int)((size_t)B_ * PXTOT * C_ / 2) + 255) / 256, 256, 0, stream>>>((float*)inTp, (int)((size_t)B_ * PXTOT * C_ / 2));
  // K generation (fp8 e4m3 output via hw converters, full grid)
  k_kgen<<<dim3(N_ / 128, N_ / 128, B_), 256, 0, stream>>>(snb16, Km, colsum);
  // Sinkhorn (K symmetric: K^T x == K x)
  k_div<<<(B_ * N_ + 255) / 256, 256, 0, stream>>>(qm, colsum, vvv);        // vv1
  k_mv<<<B_ * N_ / 8, 256, 0, stream>>>(Km, vvv, pm, uu);                   // u1
  k_mv<<<B_ * N_ / 8, 256, 0, stream>>>(Km, uu, qm, vvv);                   // vv2
  k_mv<<<B_ * N_ / 8, 256, 0, stream>>>(Km, vvv, pm, uu);                   // u2
  k_mv<<<B_ * N_ / 8, 256, 0, stream>>>(Km, uu, qm, vvv);                   // vv3
  k_mv<<<B_ * N_ / 8, 256, 0, stream>>>(Km, vvv, pm, uu);                   // u3
  k_uscale<<<(B_ * C_ * N_ / 8 + 255) / 256, 256, 0, stream>>>(srcT16, uu, usrcT);
  k_full<<<dim3(N_ / 64, 1, B_ * KSPLIT), 512, 0, stream>>>(Km, usrcT, vvv, part0, part1, part2, part3);
  k_opconv<<<dim3(N_ / 64, C_ / 128, B_), 256, 0, stream>>>(opwB, op_b, part0, part1, part2, part3, img, outf);
  // fused heads: transpose -> implicit-GEMM conv (both heads) -> BN stats -> heads
  k_tr<<<dim3(N_ / 64, 4, B_), 256, 0, stream>>>(outf, inTp);
  k_conv3m<<<dim3(33, 2, B_ * KSPLIT), 256, 0, stream>>>(inTp, Wt, biasF, part0, part1, part2, part3);
  k_bnstats2<<<256, 256, 0, stream>>>(part0, part1, part2, part3, stats);
  k_headF<<<B_ * N_ / 32, 256, 0, stream>>>(part0, part1, part2, part3, stats,
      hm_g, hm_b, hm2_w, hm2_b, hv_g, hv_b, hv2_w, hv2_b, outhm, outhv);
}

// Round 11
// 230.217 us; speedup vs baseline: 1.3098x; 1.0528x over previous
//
#include <hip/hip_runtime.h>

#define B_ 2
#define C_ 256
#define N_ 4096
#define TXT_ 512
#define CH_ 128
#define TN 32
#define KSPLIT 4
#define PXR 4224          // 64 * 66 padded-pixel rows per batch
#define PXPAD 96          // halo pad rows each side
#define PXTOT (PXR + 2 * PXPAD)
#define L2E 28.853900817779268f

typedef unsigned short u16;
typedef unsigned char u8;
typedef __attribute__((ext_vector_type(8))) short short8;
typedef __attribute__((ext_vector_type(4))) float f32x4;
typedef __attribute__((ext_vector_type(2))) float f32x2;

__device__ __forceinline__ float bf2f(u16 v){
  union { unsigned u; float f; } w; w.u = ((unsigned)v) << 16; return w.f;
}
__device__ __forceinline__ u16 f2bf(float f){
  union { float f; unsigned u; } w; w.f = f;
  unsigned r = w.u + 0x7fffu + ((w.u >> 16) & 1u);
  return (u16)(r >> 16);
}

#define MFMA_BF16(a,b,c) __builtin_amdgcn_mfma_f32_16x16x32_bf16(a,b,c,0,0,0)

// Stage a 128-row x 64-col bf16 tile (256 threads). Pre-swizzled source, linear LDS dest.
__device__ __forceinline__ void stage_tile(const u16* __restrict__ g, int stride, u16* lds, int t)
{
  #pragma unroll
  for (int q = 0; q < 4; q++){
    int e = q * 256 + t;          // 16B unit index
    int row = e >> 3;
    int slot = e & 7;
    const u16* gp = g + (size_t)row * stride + ((slot ^ (row & 7)) << 3);
    u16* lp = lds + (size_t)e * 8;
    __builtin_amdgcn_global_load_lds((const __attribute__((address_space(1))) void*)gp,
                                     (__attribute__((address_space(3))) void*)lp, 16, 0, 0);
  }
}

// 256 threads, 64 rows.
__device__ __forceinline__ void stage_tile256_64(const u16* __restrict__ g, int stride, u16* lds, int t)
{
  #pragma unroll
  for (int q = 0; q < 2; q++){
    int e = q * 256 + t;          // 512 units
    int row = e >> 3;
    int slot = e & 7;
    const u16* gp = g + (size_t)row * stride + ((slot ^ (row & 7)) << 3);
    u16* lp = lds + (size_t)e * 8;
    __builtin_amdgcn_global_load_lds((const __attribute__((address_space(1))) void*)gp,
                                     (__attribute__((address_space(3))) void*)lp, 16, 0, 0);
  }
}

// 512-thread variant: 256 rows.
__device__ __forceinline__ void stage_tile512_256(const u16* __restrict__ g, int stride, u16* lds, int t)
{
  #pragma unroll
  for (int q = 0; q < 4; q++){
    int e = q * 512 + t;          // 2048 units
    int row = e >> 3;
    int slot = e & 7;
    const u16* gp = g + (size_t)row * stride + ((slot ^ (row & 7)) << 3);
    u16* lp = lds + (size_t)e * 8;
    __builtin_amdgcn_global_load_lds((const __attribute__((address_space(1))) void*)gp,
                                     (__attribute__((address_space(3))) void*)lp, 16, 0, 0);
  }
}

__device__ __forceinline__ short8 frag_ld(const u16* lds, int row, int slot)
{
  return *(const short8*)(lds + row * 64 + ((slot ^ (row & 7)) << 3));
}

// ---------- text stage 1: te = txt @ tp_w.T + tp_b  (wave-per-channel GEMV) ----------
__global__ __launch_bounds__(256) void k_text1(
    const float* __restrict__ txt, const float* __restrict__ tpw,
    const float* __restrict__ tpb, float* __restrict__ te)
{
  int b = blockIdx.y;
  int ch = blockIdx.x * 4 + (threadIdx.x >> 6);
  int lane = threadIdx.x & 63;
  const float* tb = txt + (size_t)b * TXT_;
  const float* wr = tpw + (size_t)ch * TXT_;
  float4 a0 = *reinterpret_cast<const float4*>(wr + lane * 4);
  float4 a1 = *reinterpret_cast<const float4*>(wr + 256 + lane * 4);
  float4 b0 = *reinterpret_cast<const float4*>(tb + lane * 4);
  float4 b1 = *reinterpret_cast<const float4*>(tb + 256 + lane * 4);
  float s = a0.x * b0.x + a0.y * b0.y + a0.z * b0.z + a0.w * b0.w
          + a1.x * b1.x + a1.y * b1.y + a1.z * b1.z + a1.w * b1.w;
  for (int o = 32; o > 0; o >>= 1) s += __shfl_down(s, o);
  if (lane == 0) te[b * C_ + ch] = s + tpb[ch];
}

// ---------- text stage 2: attn_c = (te@wv.T+bv)@wo.T+bo ; txt_n = l2norm(te) ----------
__global__ __launch_bounds__(1024) void k_text2(
    const float* __restrict__ te, const float* __restrict__ wv,
    const float* __restrict__ bv, const float* __restrict__ wo,
    const float* __restrict__ bo,
    float* __restrict__ attn_c, float* __restrict__ txt_n)
{
  int b = blockIdx.x, t = threadIdx.x;
  int w = t >> 6, lane = t & 63;
  __shared__ float te_s[C_], vs_s[C_];
  __shared__ float red[16];
  __shared__ float inv_s;
  if (t < C_) te_s[t] = te[b * C_ + t];
  __syncthreads();
  // norm of te
  {
    float nv = (t < C_) ? te_s[t] * te_s[t] : 0.f;
    for (int o = 32; o > 0; o >>= 1) nv += __shfl_down(nv, o);
    if (lane == 0) red[w] = nv;
  }
  __syncthreads();
  if (t == 0){
    float S = 0.f;
    for (int q = 0; q < 16; q++) S += red[q];
    inv_s = 1.f / fmaxf(sqrtf(S), 1e-12f);
  }
  // vs = te @ wv.T + bv  (16 waves x 16 rounds)
  #pragma unroll
  for (int r = 0; r < 16; r++){
    int ch = r * 16 + w;
    float4 av = *reinterpret_cast<const float4*>(wv + (size_t)ch * C_ + lane * 4);
    float s = av.x * te_s[lane * 4] + av.y * te_s[lane * 4 + 1]
            + av.z * te_s[lane * 4 + 2] + av.w * te_s[lane * 4 + 3];
    for (int o = 32; o > 0; o >>= 1) s += __shfl_down(s, o);
    if (lane == 0) vs_s[ch] = s + bv[ch];
  }
  __syncthreads();
  // attn_c = vs @ wo.T + bo
  #pragma unroll
  for (int r = 0; r < 16; r++){
    int ch = r * 16 + w;
    float4 av = *reinterpret_cast<const float4*>(wo + (size_t)ch * C_ + lane * 4);
    float s = av.x * vs_s[lane * 4] + av.y * vs_s[lane * 4 + 1]
            + av.z * vs_s[lane * 4 + 2] + av.w * vs_s[lane * 4 + 3];
    for (int o = 32; o > 0; o >>= 1) s += __shfl_down(s, o);
    if (lane == 0) attn_c[b * C_ + ch] = s + bo[ch];
  }
  if (t < C_) txt_n[b * C_ + t] = te_s[t] * inv_s;
}

// ---------- source (residual+LN) -> srcT bf16 [C][N], snb bf16 [N][C], cos ----------
__global__ __launch_bounds__(256) void k_source(
    const float* __restrict__ img, const float* __restrict__ attn_c,
    const float* __restrict__ ln_g, const float* __restrict__ ln_b,
    const float* __restrict__ txt_n,
    u16* __restrict__ srcT, u16* __restrict__ snb, float* __restrict__ cosv)
{
  int b = blockIdx.y;
  int n0 = blockIdx.x * TN;
  int t = threadIdx.x;
  __shared__ float x[C_][TN + 1];
  __shared__ float ps[8][TN];
  __shared__ float ps2[8][TN];
  __shared__ float ac_s[C_], g_s[C_], bb_s[C_], tn_s[C_];
  __shared__ float mean_s[TN], rstd_s[TN], rn_s[TN];
  ac_s[t] = attn_c[b * C_ + t];
  g_s[t]  = ln_g[t];
  bb_s[t] = ln_b[t];
  tn_s[t] = txt_n[b * C_ + t];
  const float* ib = img + (size_t)b * C_ * N_ + n0;
  for (int k = 0; k < TN; k++){
    int e = t + k * 256;
    int c = e >> 5, nn = e & 31;
    x[c][nn] = ib[(size_t)c * N_ + nn];
  }
  __syncthreads();
  for (int k = 0; k < TN; k++){
    int e = t + k * 256;
    int c = e >> 5, nn = e & 31;
    x[c][nn] += ac_s[c];
  }
  __syncthreads();
  {
    int p = t >> 5, nn = t & 31;
    float s1 = 0.f, s2 = 0.f;
    for (int j = 0; j < 32; j++){
      float v = x[p + 8 * j][nn];
      s1 += v; s2 += v * v;
    }
    ps[p][nn] = s1; ps2[p][nn] = s2;
  }
  __syncthreads();
  if (t < TN){
    float S1 = 0.f, S2 = 0.f;
    for (int pp = 0; pp < 8; pp++){ S1 += ps[pp][t]; S2 += ps2[pp][t]; }
    float mean = S1 * (1.f / C_);
    float var = S2 * (1.f / C_) - mean * mean;
    mean_s[t] = mean;
    rstd_s[t] = rsqrtf(var + 1e-5f);
  }
  __syncthreads();
  for (int k = 0; k < TN; k++){
    float sval = (x[t][k] - mean_s[k]) * rstd_s[k] * g_s[t] + bb_s[t];
    x[t][k] = sval;
  }
  for (int kq = 0; kq < TN; kq += 4){
    ushort4 pkv;
    pkv.x = f2bf(x[t][kq + 0]);
    pkv.y = f2bf(x[t][kq + 1]);
    pkv.z = f2bf(x[t][kq + 2]);
    pkv.w = f2bf(x[t][kq + 3]);
    *reinterpret_cast<ushort4*>(&srcT[(size_t)(b * C_ + t) * N_ + n0 + kq]) = pkv;
  }
  __syncthreads();
  {
    int p = t >> 5, nn = t & 31;
    float s2 = 0.f, sd = 0.f;
    for (int j = 0; j < 32; j++){
      int c = p + 8 * j;
      float v = x[c][nn];
      s2 += v * v; sd += v * tn_s[c];
    }
    ps[p][nn] = s2; ps2[p][nn] = sd;
  }
  __syncthreads();
  if (t < TN){
    float S2 = 0.f, SD = 0.f;
    for (int pp = 0; pp < 8; pp++){ S2 += ps[pp][t]; SD += ps2[pp][t]; }
    float nrm = sqrtf(S2);
    float rn = 1.f / fmaxf(nrm, 1e-12f);
    rn_s[t] = rn;
    cosv[(b << 12) + n0 + t] = SD * rn;
  }
  __syncthreads();
  for (int k = 0; k < TN; k++){
    snb[(size_t)((b << 12) + n0 + k) * C_ + t] = f2bf(x[t][k] * rn_s[k]);
  }
}

// ---------- marginals ----------
__global__ __launch_bounds__(256) void k_qmarg(const float* __restrict__ dens, float* __restrict__ q){
  int b = blockIdx.x, t = threadIdx.x;
  __shared__ float red[256];
  const float* d = dens + (size_t)b * N_;
  float s = 0.f;
  for (int n = t; n < N_; n += 256) s += fmaxf(d[n], 0.f) + 1e-6f;
  red[t] = s; __syncthreads();
  for (int o = 128; o > 0; o >>= 1){ if (t < o) red[t] += red[t + o]; __syncthreads(); }
  float inv = 1.f / red[0];
  for (int n = t; n < N_; n += 256) q[b * N_ + n] = (fmaxf(d[n], 0.f) + 1e-6f) * inv;
}

__global__ __launch_bounds__(256) void k_pmarg(const float* __restrict__ cosv,
    const float* __restrict__ temp_p, float* __restrict__ p){
  int b = blockIdx.x, t = threadIdx.x;
  __shared__ float red[256];
  float temp = fmaxf(temp_p[0], 0.01f);
  float inv_t = 1.f / temp;
  const float* cb = cosv + (size_t)b * N_;
  float m = -1e30f;
  for (int n = t; n < N_; n += 256) m = fmaxf(m, cb[n] * inv_t);
  red[t] = m; __syncthreads();
  for (int o = 128; o > 0; o >>= 1){ if (t < o) red[t] = fmaxf(red[t], red[t + o]); __syncthreads(); }
  m = red[0]; __syncthreads();
  float s = 0.f;
  for (int n = t; n < N_; n += 256) s += expf(cb[n] * inv_t - m);
  red[t] = s; __syncthreads();
  for (int o = 128; o > 0; o >>= 1){ if (t < o) red[t] += red[t + o]; __syncthreads(); }
  float invs = 1.f / red[0];
  for (int n = t; n < N_; n += 256) p[b * N_ + n] = expf(cb[n] * inv_t - m) * invs;
}

__global__ __launch_bounds__(256) void k_zero(float* __restrict__ p, int n){
  int i = blockIdx.x * 256 + threadIdx.x;
  if (i < n) p[i] = 0.f;
}

// ---------- K = exp(20*(sn sn^T - 1)) -> FP8 e4m3 via MFMA + column sums ----------
__global__ __launch_bounds__(256) void k_kgen(
    const u16* __restrict__ snb, u8* __restrict__ Kp, float* __restrict__ colsum)
{
  int b = blockIdx.z;
  int m0 = blockIdx.x << 7, n0 = blockIdx.y << 7;
  int t = threadIdx.x;
  int lane = t & 63, w = t >> 6;
  int wr = w >> 1, wc = w & 1;
  __shared__ __align__(16) u16 shbuf[128 * 128];   // 32 KB: Al|Bl, low 16KB reused as CtT
  u16* Al = shbuf;
  u16* Bl = shbuf + 128 * 64;
  __shared__ float cs[128];
  if (t < 128) cs[t] = 0.f;
  f32x4 zero = {0.f, 0.f, 0.f, 0.f};
  f32x4 acc[4][4];
  #pragma unroll
  for (int i = 0; i < 4; i++){
    #pragma unroll
    for (int j = 0; j < 4; j++) acc[i][j] = zero;
  }
  const u16* sb = snb + (size_t)b * N_ * C_;
  const u16* ga = sb + (size_t)m0 * C_;
  const u16* gb = sb + (size_t)n0 * C_;
  for (int kt = 0; kt < C_; kt += 64){
    stage_tile(ga + kt, C_, Al, t);
    stage_tile(gb + kt, C_, Bl, t);
    __syncthreads();
    #pragma unroll
    for (int kh = 0; kh < 2; kh++){
      short8 af[4], bfv[4];
      #pragma unroll
      for (int i = 0; i < 4; i++){
        af[i]  = frag_ld(Al, wr * 64 + i * 16 + (lane & 15), kh * 4 + (lane >> 4));
        bfv[i] = frag_ld(Bl, wc * 64 + i * 16 + (lane & 15), kh * 4 + (lane >> 4));
      }
      #pragma unroll
      for (int i = 0; i < 4; i++){
        #pragma unroll
        for (int j = 0; j < 4; j++)
          acc[i][j] = MFMA_BF16(af[i], bfv[j], acc[i][j]);
      }
    }
    __syncthreads();
  }
  // epilogue: exp2 -> hw fp8 pack -> transposed tile CtT[col][row] (word-swizzled)
  u8* CtT = (u8*)shbuf;
  #pragma unroll
  for (int j = 0; j < 4; j++){
    int col = wc * 64 + j * 16 + (lane & 15);
    float csum = 0.f;
    #pragma unroll
    for (int i = 0; i < 4; i++){
      int rb = wr * 64 + i * 16 + (lane >> 4) * 4;
      float e0 = __builtin_amdgcn_exp2f(fmaf(acc[i][j][0], L2E, -L2E));
      float e1 = __builtin_amdgcn_exp2f(fmaf(acc[i][j][1], L2E, -L2E));
      float e2 = __builtin_amdgcn_exp2f(fmaf(acc[i][j][2], L2E, -L2E));
      float e3 = __builtin_amdgcn_exp2f(fmaf(acc[i][j][3], L2E, -L2E));
      int pk = __builtin_amdgcn_cvt_pk_fp8_f32(e0, e1, 0, false);
      pk = __builtin_amdgcn_cvt_pk_fp8_f32(e2, e3, pk, true);
      f32x2 d0 = __builtin_amdgcn_cvt_pk_f32_fp8(pk, false);
      f32x2 d1 = __builtin_amdgcn_cvt_pk_f32_fp8(pk, true);
      csum += (d0.x + d0.y) + (d1.x + d1.y);
      int wq = rb >> 2;
      *reinterpret_cast<unsigned*>(CtT + col * 128 + ((wq ^ ((col & 7) << 2)) << 2)) = (unsigned)pk;
    }
    atomicAdd(&cs[col], csum);
  }
  __syncthreads();
  u8* Kb = Kp + (size_t)b * N_ * N_;
  // store transposed tile: K[n0+row][m0..] gets column `row` of this tile
  for (int e = t; e < 1024; e += 256){
    int row = e >> 3, un = e & 7;
    uint4 v = *(const uint4*)(CtT + row * 128 + ((un ^ (row & 7)) << 4));
    *reinterpret_cast<uint4*>(&Kb[(size_t)(n0 + row) * N_ + m0 + (un << 4)]) = v;
  }
  if (t < 128) atomicAdd(&colsum[b * N_ + n0 + t], cs[t]);
}

__global__ __launch_bounds__(256) void k_div(
    const float* __restrict__ marg, const float* __restrict__ denom, float* __restrict__ outp){
  int i = blockIdx.x * 256 + threadIdx.x;
  if (i < B_ * N_) outp[i] = marg[i] / (denom[i] + 1e-8f);
}

// ---------- out[r] = marg[r] / (K_row_r . x + 1e-8)  (K symmetric, fp8), 8 rows/block ----------
__global__ __launch_bounds__(256) void k_mv(
    const u8* __restrict__ Kp, const float* __restrict__ x,
    const float* __restrict__ marg, float* __restrict__ outp)
{
  int r0 = blockIdx.x * 8;
  int b = r0 >> 12;
  int t = threadIdx.x, w = t >> 6, lane = t & 63;
  __shared__ __align__(16) float xs[N_];
  const float* xb = x + b * N_;
  for (int i = t; i < N_ / 4; i += 256)
    reinterpret_cast<float4*>(xs)[i] = reinterpret_cast<const float4*>(xb)[i];
  __syncthreads();
  int r = r0 + w * 2;
  const u8* Kr0 = Kp + (size_t)b * N_ * N_ + (size_t)(r & (N_ - 1)) * N_;
  const u8* Kr1 = Kr0 + N_;
  float acc0 = 0.f, acc1 = 0.f;
  #pragma unroll
  for (int p = 0; p < 4; p++){
    int idx = p * 1024 + lane * 16;
    uint4 a = *reinterpret_cast<const uint4*>(Kr0 + idx);
    uint4 c = *reinterpret_cast<const uint4*>(Kr1 + idx);
    #pragma unroll
    for (int q = 0; q < 4; q++){
      unsigned aw = (q == 0) ? a.x : (q == 1) ? a.y : (q == 2) ? a.z : a.w;
      unsigned cw = (q == 0) ? c.x : (q == 1) ? c.y : (q == 2) ? c.z : c.w;
      float4 xv = *reinterpret_cast<const float4*>(xs + idx + q * 4);
      f32x2 al = __builtin_amdgcn_cvt_pk_f32_fp8((int)aw, false);
      f32x2 ah = __builtin_amdgcn_cvt_pk_f32_fp8((int)aw, true);
      f32x2 cl = __builtin_amdgcn_cvt_pk_f32_fp8((int)cw, false);
      f32x2 ch = __builtin_amdgcn_cvt_pk_f32_fp8((int)cw, true);
      acc0 += al.x * xv.x + al.y * xv.y + ah.x * xv.z + ah.y * xv.w;
      acc1 += cl.x * xv.x + cl.y * xv.y + ch.x * xv.z + ch.y * xv.w;
    }
  }
  for (int o = 32; o > 0; o >>= 1){
    acc0 += __shfl_down(acc0, o);
    acc1 += __shfl_down(acc1, o);
  }
  if (lane == 0){
    outp[r] = marg[r] / (acc0 + 1e-8f);
    outp[r + 1] = marg[r + 1] / (acc1 + 1e-8f);
  }
}

// ---------- usrcT[c][n] = srcT[c][n] * u[n] ----------
__global__ __launch_bounds__(256) void k_uscale(
    const u16* __restrict__ srcT, const float* __restrict__ uu, u16* __restrict__ usrcT)
{
  int i = blockIdx.x * 256 + threadIdx.x;
  int n8 = i & (N_ / 8 - 1);
  int row = i >> 9;
  int b = row >> 8;
  const u16* s = srcT + (size_t)row * N_ + n8 * 8;
  short8 v = *reinterpret_cast<const short8*>(s);
  const float* ub = uu + b * N_ + n8 * 8;
  short8 o;
  #pragma unroll
  for (int q = 0; q < 8; q++) o[q] = (short)f2bf(bf2f((u16)v[q]) * ub[q]);
  *reinterpret_cast<short8*>(usrcT + (size_t)row * N_ + n8 * 8) = o;
}

// ---------- part[ks][m][c] = vv[m] * sum_{n in ks chunk} K[m][n]*usrc[n][c] ----------
// 512 threads, tile 64m x 256c, fp8 K A-operand decoded via hw cvt to bf16.
__global__ __launch_bounds__(512) void k_full(
    const u8* __restrict__ Kp, const u16* __restrict__ usrcT,
    const float* __restrict__ vvv,
    u16* __restrict__ p0, u16* __restrict__ p1,
    u16* __restrict__ p2, u16* __restrict__ p3)
{
  int m0 = blockIdx.x << 6;
  int b = blockIdx.z >> 2, ks = blockIdx.z & 3;
  int t = threadIdx.x, lane = t & 63, w = t >> 6;   // w: 0..7 -> c-stripe of 32
  __shared__ __align__(16) u16 shbuf[64 * 64 + 256 * 64];  // Al 8KB | Bl 32KB
  __shared__ float vsm[64];
  u16* Al = shbuf;
  u16* Bl = shbuf + 64 * 64;
  if (t < 64) vsm[t] = vvv[b * N_ + m0 + t];
  f32x4 zero = {0.f, 0.f, 0.f, 0.f};
  f32x4 acc[4][2];
  #pragma unroll
  for (int i = 0; i < 4; i++){
    #pragma unroll
    for (int j = 0; j < 2; j++) acc[i][j] = zero;
  }
  const u8* ka = Kp + (size_t)b * N_ * N_ + (size_t)m0 * N_ + ks * (N_ / KSPLIT);
  const u16* ub = usrcT + (size_t)b * C_ * N_ + ks * (N_ / KSPLIT);
  for (int kt = 0; kt < N_ / KSPLIT; kt += 64){
    // A: 64x64 fp8 -> hw decode to bf16, reg-stage into swizzled-content linear LDS
    {
      int row = t >> 3, slot = t & 7;
      const u8* gp = ka + (size_t)row * N_ + kt + ((slot ^ (row & 7)) << 3);
      uint2 v8 = *reinterpret_cast<const uint2*>(gp);
      f32x2 q0 = __builtin_amdgcn_cvt_pk_f32_fp8((int)v8.x, false);
      f32x2 q1 = __builtin_amdgcn_cvt_pk_f32_fp8((int)v8.x, true);
      f32x2 q2 = __builtin_amdgcn_cvt_pk_f32_fp8((int)v8.y, false);
      f32x2 q3 = __builtin_amdgcn_cvt_pk_f32_fp8((int)v8.y, true);
      union { short8 s; unsigned u[4]; } o;
      asm("v_cvt_pk_bf16_f32 %0, %1, %2" : "=v"(o.u[0]) : "v"(q0.x), "v"(q0.y));
      asm("v_cvt_pk_bf16_f32 %0, %1, %2" : "=v"(o.u[1]) : "v"(q1.x), "v"(q1.y));
      asm("v_cvt_pk_bf16_f32 %0, %1, %2" : "=v"(o.u[2]) : "v"(q2.x), "v"(q2.y));
      asm("v_cvt_pk_bf16_f32 %0, %1, %2" : "=v"(o.u[3]) : "v"(q3.x), "v"(q3.y));
      *reinterpret_cast<short8*>(Al + (size_t)t * 8) = o.s;
    }
    stage_tile512_256(ub + kt, N_, Bl, t);
    __syncthreads();
    #pragma unroll
    for (int kh = 0; kh < 2; kh++){
      short8 af[4], bfv[2];
      #pragma unroll
      for (int i = 0; i < 4; i++)
        af[i] = frag_ld(Al, i * 16 + (lane & 15), kh * 4 + (lane >> 4));
      #pragma unroll
      for (int j = 0; j < 2; j++)
        bfv[j] = frag_ld(Bl, w * 32 + j * 16 + (lane & 15), kh * 4 + (lane >> 4));
      #pragma unroll
      for (int i = 0; i < 4; i++){
        #pragma unroll
        for (int j = 0; j < 2; j++)
          acc[i][j] = MFMA_BF16(af[i], bfv[j], acc[i][j]);
      }
    }
    __syncthreads();
  }
  // restage [64m][256c] bf16 (vv-scaled) into swizzled Ct, then fully-linear stores
  u16* Ct = shbuf;
  #pragma unroll
  for (int j = 0; j < 2; j++){
    int col = w * 32 + j * 16 + (lane & 15);
    #pragma unroll
    for (int i = 0; i < 4; i++){
      int rb = i * 16 + (lane >> 4) * 4;
      #pragma unroll
      for (int r = 0; r < 4; r++){
        int row = rb + r;
        Ct[row * 256 + ((((col >> 3) ^ (row & 7)) << 3) | (col & 7))] =
            f2bf(acc[i][j][r] * vsm[row]);
      }
    }
  }
  __syncthreads();
  u16* P = (ks == 0) ? p0 : (ks == 1) ? p1 : (ks == 2) ? p2 : p3;
  for (int e = t; e < 2048; e += 512){
    int row = e >> 5, un = e & 31;
    short8 v8 = *(const short8*)(Ct + row * 256 + ((un ^ (row & 7)) << 3));
    *reinterpret_cast<short8*>(&P[(size_t)((b << 12) + m0 + row) * C_ + (un << 3)]) = v8;
  }
}

// ---------- cast opw (f32 256x256) to bf16 ----------
__global__ __launch_bounds__(256) void k_wcast(const float* __restrict__ w, u16* __restrict__ o){
  int i = blockIdx.x * 256 + threadIdx.x;
  o[i] = f2bf(w[i]);
}

// ---------- out_feat = img + 1x1conv(p0+p1+p2+p3) via MFMA; tile 64n x 128co ----------
__global__ __launch_bounds__(256) void k_opconv(
    const u16* __restrict__ opwB, const float* __restrict__ opb,
    const u16* __restrict__ p0, const u16* __restrict__ p1,
    const u16* __restrict__ p2, const u16* __restrict__ p3,
    const float* __restrict__ img, float* __restrict__ outf)
{
  int b = blockIdx.z;
  int n0 = blockIdx.x << 6;
  int co0 = blockIdx.y << 7;
  int t = threadIdx.x, lane = t & 63, w = t >> 6;
  int wr = w >> 1, wc = w & 1;              // wr: co half (64), wc: n half (32)
  __shared__ __align__(16) u16 Al[128 * 64];   // opw rows=co
  __shared__ __align__(16) u16 Bl[64 * 64];    // fused rows=n
  f32x4 zero = {0.f, 0.f, 0.f, 0.f};
  f32x4 acc[4][2];
  #pragma unroll
  for (int i = 0; i < 4; i++){
    #pragma unroll
    for (int j = 0; j < 2; j++) acc[i][j] = zero;
  }
  for (int ct = 0; ct < C_; ct += 64){
    stage_tile(opwB + (size_t)co0 * C_ + ct, C_, Al, t);
    // reg-stage B: sum 4 bf16 partials into swizzled layout (512 units, 2 iters)
    #pragma unroll
    for (int q = 0; q < 2; q++){
      int e = q * 256 + t;
      int row = e >> 3, slot = e & 7;
      int col = ct + ((slot ^ (row & 7)) << 3);
      size_t idx = (size_t)((b << 12) + n0 + row) * C_ + col;
      short8 a0 = *reinterpret_cast<const short8*>(p0 + idx);
      short8 a1 = *reinterpret_cast<const short8*>(p1 + idx);
      short8 a2 = *reinterpret_cast<const short8*>(p2 + idx);
      short8 a3 = *reinterpret_cast<const short8*>(p3 + idx);
      short8 o;
      #pragma unroll
      for (int k = 0; k < 8; k++)
        o[k] = (short)f2bf(bf2f((u16)a0[k]) + bf2f((u16)a1[k]) + bf2f((u16)a2[k]) + bf2f((u16)a3[k]));
      *reinterpret_cast<short8*>(Bl + (size_t)e * 8) = o;
    }
    __syncthreads();
    #pragma unroll
    for (int kh = 0; kh < 2; kh++){
      short8 af[4], bfv[2];
      #pragma unroll
      for (int i = 0; i < 4; i++)
        af[i] = frag_ld(Al, wr * 64 + i * 16 + (lane & 15), kh * 4 + (lane >> 4));
      #pragma unroll
      for (int j = 0; j < 2; j++)
        bfv[j] = frag_ld(Bl, wc * 32 + j * 16 + (lane & 15), kh * 4 + (lane >> 4));
      #pragma unroll
      for (int i = 0; i < 4; i++){
        #pragma unroll
        for (int j = 0; j < 2; j++)
          acc[i][j] = MFMA_BF16(af[i], bfv[j], acc[i][j]);
      }
    }
    __syncthreads();
  }
  #pragma unroll
  for (int i = 0; i < 4; i++){
    int cb = co0 + wr * 64 + i * 16 + (lane >> 4) * 4;
    #pragma unroll
    for (int j = 0; j < 2; j++){
      int nc = n0 + wc * 32 + j * 16 + (lane & 15);
      #pragma unroll
      for (int r = 0; r < 4; r++){
        int co = cb + r;
        size_t oi = (size_t)(b * C_ + co) * N_ + nc;
        outf[oi] = acc[i][j][r] + img[oi] + opb[co];
      }
    }
  }
}

// ---------- transpose out_feat -> padded bf16 [b][px'][ci] ----------
__global__ __launch_bounds__(256) void k_tr(const float* __restrict__ outf, u16* __restrict__ inTp)
{
  int b = blockIdx.z;
  int c0 = blockIdx.y << 6;
  int px0 = blockIdx.x << 6;
  int t = threadIdx.x;
  __shared__ float tile[64][65];
  int tx = t & 63, ty4 = t >> 6;
  for (int cc = ty4; cc < 64; cc += 4)
    tile[cc][tx] = outf[((size_t)(b * C_) + c0 + cc) * N_ + px0 + tx];
  __syncthreads();
  int p = t >> 2, cg = (t & 3) << 4;
  int px = px0 + p;
  int y = px >> 6, x = px & 63;
  int pxp = y * 66 + x + 1;
  u16* dst = inTp + ((size_t)b * PXTOT + PXPAD + pxp) * C_ + c0 + cg;
  #pragma unroll
  for (int q = 0; q < 16; q += 4){
    ushort4 pk;
    pk.x = f2bf(tile[cg + q + 0][p]);
    pk.y = f2bf(tile[cg + q + 1][p]);
    pk.z = f2bf(tile[cg + q + 2][p]);
    pk.w = f2bf(tile[cg + q + 3][p]);
    *reinterpret_cast<ushort4*>(dst + q) = pk;
  }
}

// ---------- weights -> Wt[tap][co(256 fused)][ci] bf16, fused bias ----------
__global__ __launch_bounds__(256) void k_wtr(
    const float* __restrict__ hm1_w, const float* __restrict__ hv1_w,
    const float* __restrict__ hm1_b, const float* __restrict__ hv1_b,
    u16* __restrict__ Wt, float* __restrict__ biasF)
{
  int i = blockIdx.x * 256 + threadIdx.x;   // < 9*256*256
  int ci = i & 255, co = (i >> 8) & 255, tap = i >> 16;
  float v = (co < CH_) ? hm1_w[((size_t)co * C_ + ci) * 9 + tap]
                       : hv1_w[((size_t)(co - CH_) * C_ + ci) * 9 + tap];
  Wt[i] = f2bf(v);
  if (i < CH_) biasF[i] = hm1_b[i];
  else if (i < 2 * CH_) biasF[i] = hv1_b[i - CH_];
}

// ---------- fused 3x3 conv (both heads) as implicit GEMM: C[co][px'] (bf16 out) ----------
// 64-px tiles -> 1056 blocks for occupancy.
__global__ __launch_bounds__(256) void k_conv3m(
    const u16* __restrict__ inTp, const u16* __restrict__ Wt,
    const float* __restrict__ biasF,
    u16* __restrict__ q0, u16* __restrict__ q1,
    u16* __restrict__ q2, u16* __restrict__ q3)
{
  int px0 = blockIdx.x << 6;           // 0..65 (66 tiles of 64 px')
  int cot = blockIdx.y;                // 0..1 (co halves of 256 fused)
  int b = blockIdx.z >> 2, ks = blockIdx.z & 3;
  int t = threadIdx.x, lane = t & 63, w = t >> 6;
  int wr = w >> 1, wc = w & 1;         // wr: co half (64), wc: px half (32)
  __shared__ __align__(16) u16 Al[128 * 64];   // weights: 128 co rows x 64 ci
  __shared__ __align__(16) u16 Bl[64 * 64];    // input:   64 px rows x 64 ci
  f32x4 zero = {0.f, 0.f, 0.f, 0.f};
  f32x4 acc[4][2];
  #pragma unroll
  for (int i = 0; i < 4; i++){
    #pragma unroll
    for (int j = 0; j < 2; j++) acc[i][j] = zero;
  }
  const u16* inb = inTp + ((size_t)b * PXTOT + PXPAD + px0) * C_;
  for (int s = ks * 9; s < ks * 9 + 9; s++){
    int tap = s >> 2, cic = (s & 3) << 6;
    int ky = tap / 3, kx = tap - ky * 3;
    int off = (ky - 1) * 66 + (kx - 1);
    stage_tile(Wt + ((size_t)tap * 256 + cot * 128) * C_ + cic, C_, Al, t);
    stage_tile256_64(inb + (ptrdiff_t)off * C_ + cic, C_, Bl, t);
    __syncthreads();
    #pragma unroll
    for (int kh = 0; kh < 2; kh++){
      short8 af[4], bfv[2];
      #pragma unroll
      for (int i = 0; i < 4; i++)
        af[i] = frag_ld(Al, wr * 64 + i * 16 + (lane & 15), kh * 4 + (lane >> 4));
      #pragma unroll
      for (int j = 0; j < 2; j++)
        bfv[j] = frag_ld(Bl, wc * 32 + j * 16 + (lane & 15), kh * 4 + (lane >> 4));
      #pragma unroll
      for (int i = 0; i < 4; i++){
        #pragma unroll
        for (int j = 0; j < 2; j++)
          acc[i][j] = MFMA_BF16(af[i], bfv[j], acc[i][j]);
      }
    }
    __syncthreads();
  }
  u16* P = (ks == 0) ? q0 : (ks == 1) ? q1 : (ks == 2) ? q2 : q3;
  #pragma unroll
  for (int i = 0; i < 4; i++){
    #pragma unroll
    for (int j = 0; j < 2; j++){
      int pxp = px0 + wc * 32 + j * 16 + (lane & 15);
      int y = pxp / 66;
      int xm = pxp - y * 66;
      bool valid = (xm >= 1 && xm <= 64);
      int outn = y * 64 + xm - 1;
      #pragma unroll
      for (int r = 0; r < 4; r++){
        int co = cot * 128 + wr * 64 + i * 16 + (lane >> 4) * 4 + r;
        if (valid){
          float bco = (ks == 0) ? biasF[co] : 0.f;
          P[((size_t)(b * 256 + co)) * N_ + outn] = f2bf(acc[i][j][r] + bco);
        }
      }
    }
  }
}

// ---------- batchnorm stats over (B,H,W) per fused channel (sums 4 K-parts) ----------
__global__ __launch_bounds__(256) void k_bnstats2(
    const u16* __restrict__ p0, const u16* __restrict__ p1,
    const u16* __restrict__ p2, const u16* __restrict__ p3,
    float* __restrict__ stats)
{
  int ch = blockIdx.x, t = threadIdx.x;   // ch in [0,256)
  __shared__ float r1[256], r2[256];
  float s1 = 0.f, s2 = 0.f;
  for (int i = t; i < B_ * N_; i += 256){
    int b = i >> 12, n = i & (N_ - 1);
    size_t idx = ((size_t)(b * 256 + ch)) * N_ + n;
    float v = bf2f(p0[idx]) + bf2f(p1[idx]) + bf2f(p2[idx]) + bf2f(p3[idx]);
    s1 += v; s2 += v * v;
  }
  r1[t] = s1; r2[t] = s2; __syncthreads();
  for (int o = 128; o > 0; o >>= 1){
    if (t < o){ r1[t] += r1[t + o]; r2[t] += r2[t + o]; }
    __syncthreads();
  }
  if (t == 0){
    float mean = r1[0] / (float)(B_ * N_);
    float var = r2[0] / (float)(B_ * N_) - mean * mean;
    stats[ch * 2] = mean;
    stats[ch * 2 + 1] = rsqrtf(var + 1e-5f);
  }
}

// ---------- fused dual-head: relu(bn(mid)) -> 1x1 conv to 2 ch per head ----------
__global__ __launch_bounds__(256) void k_headF(
    const u16* __restrict__ p0, const u16* __restrict__ p1,
    const u16* __restrict__ p2, const u16* __restrict__ p3,
    const float* __restrict__ stats,
    const float* __restrict__ hm_g, const float* __restrict__ hm_b,
    const float* __restrict__ hm2_w, const float* __restrict__ hm2_b,
    const float* __restrict__ hv_g, const float* __restrict__ hv_b,
    const float* __restrict__ hv2_w, const float* __restrict__ hv2_b,
    float* __restrict__ outhm, float* __restrict__ outhv)
{
  int t = threadIdx.x;
  int nl = t & 31, g = t >> 5;
  int idx0 = blockIdx.x * 32;
  int idx = idx0 + nl;
  int b = idx >> 12, n = idx & (N_ - 1);
  int head = g >> 2;
  int ch0 = (g & 3) * 32;
  const float* gg = head ? hv_g : hm_g;
  const float* gb = head ? hv_b : hm_b;
  const float* w2 = head ? hv2_w : hm2_w;
  float a0 = 0.f, a1 = 0.f;
  #pragma unroll 8
  for (int cc = 0; cc < 32; cc++){
    int ch = ch0 + cc;
    int fc = head * CH_ + ch;
    size_t id = ((size_t)(b * 256 + fc)) * N_ + n;
    float v = bf2f(p0[id]) + bf2f(p1[id]) + bf2f(p2[id]) + bf2f(p3[id]);
    float rr = fmaxf((v - stats[fc * 2]) * stats[fc * 2 + 1] * gg[ch] + gb[ch], 0.f);
    a0 += w2[ch] * rr;
    a1 += w2[CH_ + ch] * rr;
  }
  __shared__ float r0[8][32], r1[8][32];
  r0[g][nl] = a0; r1[g][nl] = a1;
  __syncthreads();
  if (t < 64){
    int hh = t >> 5, n2 = t & 31;
    int base = hh * 4;
    float s0 = r0[base][n2] + r0[base + 1][n2] + r0[base + 2][n2] + r0[base + 3][n2];
    float s1 = r1[base][n2] + r1[base + 1][n2] + r1[base + 2][n2] + r1[base + 3][n2];
    int idx2 = idx0 + n2;
    int b2 = idx2 >> 12, nn = idx2 & (N_ - 1);
    float* op = hh ? outhv : outhm;
    const float* bp = hh ? hv2_b : hm2_b;
    op[(size_t)(b2 * 2) * N_ + nn] = s0 + bp[0];
    op[(size_t)(b2 * 2 + 1) * N_ + nn] = s1 + bp[1];
  }
}

extern "C" void kernel_launch(void* const* d_in, const int* in_sizes, int n_in,
                              void* d_out, int out_size, void* d_ws, size_t ws_size,
                              hipStream_t stream)
{
  const float* img   = (const float*)d_in[0];
  const float* txt   = (const float*)d_in[1];
  const float* dens  = (const float*)d_in[2];
  const float* tp_w  = (const float*)d_in[3];
  const float* tp_b  = (const float*)d_in[4];
  const float* wv    = (const float*)d_in[9];
  const float* bv    = (const float*)d_in[10];
  const float* wo    = (const float*)d_in[11];
  const float* bo    = (const float*)d_in[12];
  const float* ln_g  = (const float*)d_in[13];
  const float* ln_b  = (const float*)d_in[14];
  const float* op_w  = (const float*)d_in[15];
  const float* op_b  = (const float*)d_in[16];
  const float* hm1_w = (const float*)d_in[17];
  const float* hm1_b = (const float*)d_in[18];
  const float* hm_g  = (const float*)d_in[19];
  const float* hm_b  = (const float*)d_in[20];
  const float* hm2_w = (const float*)d_in[21];
  const float* hm2_b = (const float*)d_in[22];
  const float* hv1_w = (const float*)d_in[23];
  const float* hv1_b = (const float*)d_in[24];
  const float* hv_g  = (const float*)d_in[25];
  const float* hv_b  = (const float*)d_in[26];
  const float* hv2_w = (const float*)d_in[27];
  const float* hv2_b = (const float*)d_in[28];
  const float* temp  = (const float*)d_in[29];

  char* wsb = (char*)d_ws;
  size_t off = 0;
  auto alloc = [&](size_t bytes) -> void* {
    void* p = wsb + off;
    off += (bytes + 255) & ~(size_t)255;
    return p;
  };
  u8*    Km     = (u8*)   alloc((size_t)B_ * N_ * N_ * sizeof(u8));    // 33.5 MB (fp8)
  u16*   snb16  = (u16*)  alloc((size_t)B_ * N_ * C_ * sizeof(u16));   // 4.19 MB (part0 alias)
  u16*   srcT16 = (u16*)  alloc((size_t)B_ * C_ * N_ * sizeof(u16));   // 4.19 MB
  u16*   usrcT  = (u16*)  alloc((size_t)B_ * C_ * N_ * sizeof(u16));   // 4.19 MB
  u16*   part1  = (u16*)  alloc((size_t)B_ * N_ * C_ * sizeof(u16));   // 4.19 MB
  u16*   part2  = (u16*)  alloc((size_t)B_ * N_ * C_ * sizeof(u16));   // 4.19 MB
  u16*   part3  = (u16*)  alloc((size_t)B_ * N_ * C_ * sizeof(u16));   // 4.19 MB
  u16*   inTp   = (u16*)  alloc((size_t)B_ * PXTOT * C_ * sizeof(u16));// 4.52 MB
  u16*   Wt     = (u16*)  alloc((size_t)9 * 256 * C_ * sizeof(u16));   // 1.18 MB
  u16*   opwB   = (u16*)  alloc((size_t)C_ * C_ * sizeof(u16));        // 131 KB
  float* biasF  = (float*)alloc(256 * sizeof(float));
  float* teb    = (float*)alloc(B_ * C_ * sizeof(float));
  float* attn_c = (float*)alloc(B_ * C_ * sizeof(float));
  float* txt_n  = (float*)alloc(B_ * C_ * sizeof(float));
  float* cosv   = (float*)alloc(B_ * N_ * sizeof(float));
  float* qm     = (float*)alloc(B_ * N_ * sizeof(float));
  float* pm     = (float*)alloc(B_ * N_ * sizeof(float));
  float* uu     = (float*)alloc(B_ * N_ * sizeof(float));
  float* vvv    = (float*)alloc(B_ * N_ * sizeof(float));
  float* colsum = (float*)alloc(B_ * N_ * sizeof(float));
  float* stats  = (float*)alloc(256 * 2 * sizeof(float));

  // alias: part0 over snb16 (snb dead after kgen; part0 written by k_full)
  u16* part0 = snb16;

  float* outf  = (float*)d_out;
  float* outhm = outf + (size_t)B_ * C_ * N_;
  float* outhv = outhm + (size_t)B_ * 2 * N_;

  k_text1<<<dim3(64, B_), 256, 0, stream>>>(txt, tp_w, tp_b, teb);
  k_text2<<<B_, 1024, 0, stream>>>(teb, wv, bv, wo, bo, attn_c, txt_n);
  k_source<<<dim3(N_ / TN, B_), 256, 0, stream>>>(img, attn_c, ln_g, ln_b, txt_n, srcT16, snb16, cosv);
  k_qmarg<<<B_, 256, 0, stream>>>(dens, qm);
  k_pmarg<<<B_, 256, 0, stream>>>(cosv, temp, pm);
  k_zero<<<(B_ * N_ + 255) / 256, 256, 0, stream>>>(colsum, B_ * N_);
  // conv/opconv prep with no deps on GEMM chain
  k_wtr<<<9 * 256, 256, 0, stream>>>(hm1_w, hv1_w, hm1_b, hv1_b, Wt, biasF);
  k_wcast<<<C_ * C_ / 256, 256, 0, stream>>>(op_w, opwB);
  k_zero<<<((int)((size_t)B_ * PXTOT * C_ / 2) + 255) / 256, 256, 0, stream>>>((float*)inTp, (int)((size_t)B_ * PXTOT * C_ / 2));
  // K generation (fp8 e4m3 output via hw converters, full grid)
  k_kgen<<<dim3(N_ / 128, N_ / 128, B_), 256, 0, stream>>>(snb16, Km, colsum);
  // Sinkhorn (K symmetric: K^T x == K x)
  k_div<<<(B_ * N_ + 255) / 256, 256, 0, stream>>>(qm, colsum, vvv);        // vv1
  k_mv<<<B_ * N_ / 8, 256, 0, stream>>>(Km, vvv, pm, uu);                   // u1
  k_mv<<<B_ * N_ / 8, 256, 0, stream>>>(Km, uu, qm, vvv);                   // vv2
  k_mv<<<B_ * N_ / 8, 256, 0, stream>>>(Km, vvv, pm, uu);                   // u2
  k_mv<<<B_ * N_ / 8, 256, 0, stream>>>(Km, uu, qm, vvv);                   // vv3
  k_mv<<<B_ * N_ / 8, 256, 0, stream>>>(Km, vvv, pm, uu);                   // u3
  k_uscale<<<(B_ * C_ * N_ / 8 + 255) / 256, 256, 0, stream>>>(srcT16, uu, usrcT);
  k_full<<<dim3(N_ / 64, 1, B_ * KSPLIT), 512, 0, stream>>>(Km, usrcT, vvv, part0, part1, part2, part3);
  k_opconv<<<dim3(N_ / 64, C_ / 128, B_), 256, 0, stream>>>(opwB, op_b, part0, part1, part2, part3, img, outf);
  // fused heads: transpose -> implicit-GEMM conv (both heads) -> BN stats -> heads
  k_tr<<<dim3(N_ / 64, 4, B_), 256, 0, stream>>>(outf, inTp);
  k_conv3m<<<dim3(66, 2, B_ * KSPLIT), 256, 0, stream>>>(inTp, Wt, biasF, part0, part1, part2, part3);
  k_bnstats2<<<256, 256, 0, stream>>>(part0, part1, part2, part3, stats);
  k_headF<<<B_ * N_ / 32, 256, 0, stream>>>(part0, part1, part2, part3, stats,
      hm_g, hm_b, hm2_w, hm2_b, hv_g, hv_b, hv2_w, hv2_b, outhm, outhv);
}

// Round 12
// 217.409 us; speedup vs baseline: 1.3870x; 1.0589x over previous
//
#include <hip/hip_runtime.h>

#define B_ 2
#define C_ 256
#define N_ 4096
#define TXT_ 512
#define CH_ 128
#define TN 32
#define KSPLIT 4
#define PXR 4224          // 64 * 66 padded-pixel rows per batch
#define PXPAD 96          // halo pad rows each side
#define PXTOT (PXR + 2 * PXPAD)
#define L2E 28.853900817779268f

typedef unsigned short u16;
typedef unsigned char u8;
typedef __attribute__((ext_vector_type(8))) short short8;
typedef __attribute__((ext_vector_type(4))) float f32x4;
typedef __attribute__((ext_vector_type(2))) float f32x2;

__device__ __forceinline__ float bf2f(u16 v){
  union { unsigned u; float f; } w; w.u = ((unsigned)v) << 16; return w.f;
}
__device__ __forceinline__ u16 f2bf(float f){
  union { float f; unsigned u; } w; w.f = f;
  unsigned r = w.u + 0x7fffu + ((w.u >> 16) & 1u);
  return (u16)(r >> 16);
}

#define MFMA_BF16(a,b,c) __builtin_amdgcn_mfma_f32_16x16x32_bf16(a,b,c,0,0,0)

// Stage a 128-row x 64-col bf16 tile (256 threads). Pre-swizzled source, linear LDS dest.
__device__ __forceinline__ void stage_tile(const u16* __restrict__ g, int stride, u16* lds, int t)
{
  #pragma unroll
  for (int q = 0; q < 4; q++){
    int e = q * 256 + t;          // 16B unit index
    int row = e >> 3;
    int slot = e & 7;
    const u16* gp = g + (size_t)row * stride + ((slot ^ (row & 7)) << 3);
    u16* lp = lds + (size_t)e * 8;
    __builtin_amdgcn_global_load_lds((const __attribute__((address_space(1))) void*)gp,
                                     (__attribute__((address_space(3))) void*)lp, 16, 0, 0);
  }
}

// 256 threads, 64 rows.
__device__ __forceinline__ void stage_tile256_64(const u16* __restrict__ g, int stride, u16* lds, int t)
{
  #pragma unroll
  for (int q = 0; q < 2; q++){
    int e = q * 256 + t;          // 512 units
    int row = e >> 3;
    int slot = e & 7;
    const u16* gp = g + (size_t)row * stride + ((slot ^ (row & 7)) << 3);
    u16* lp = lds + (size_t)e * 8;
    __builtin_amdgcn_global_load_lds((const __attribute__((address_space(1))) void*)gp,
                                     (__attribute__((address_space(3))) void*)lp, 16, 0, 0);
  }
}

// 512-thread variant: 256 rows.
__device__ __forceinline__ void stage_tile512_256(const u16* __restrict__ g, int stride, u16* lds, int t)
{
  #pragma unroll
  for (int q = 0; q < 4; q++){
    int e = q * 512 + t;          // 2048 units
    int row = e >> 3;
    int slot = e & 7;
    const u16* gp = g + (size_t)row * stride + ((slot ^ (row & 7)) << 3);
    u16* lp = lds + (size_t)e * 8;
    __builtin_amdgcn_global_load_lds((const __attribute__((address_space(1))) void*)gp,
                                     (__attribute__((address_space(3))) void*)lp, 16, 0, 0);
  }
}

__device__ __forceinline__ short8 frag_ld(const u16* lds, int row, int slot)
{
  return *(const short8*)(lds + row * 64 + ((slot ^ (row & 7)) << 3));
}

// ---------- text stage 1: te = txt @ tp_w.T + tp_b  (wave-per-channel GEMV) ----------
__global__ __launch_bounds__(256) void k_text1(
    const float* __restrict__ txt, const float* __restrict__ tpw,
    const float* __restrict__ tpb, float* __restrict__ te)
{
  int b = blockIdx.y;
  int ch = blockIdx.x * 4 + (threadIdx.x >> 6);
  int lane = threadIdx.x & 63;
  const float* tb = txt + (size_t)b * TXT_;
  const float* wr = tpw + (size_t)ch * TXT_;
  float4 a0 = *reinterpret_cast<const float4*>(wr + lane * 4);
  float4 a1 = *reinterpret_cast<const float4*>(wr + 256 + lane * 4);
  float4 b0 = *reinterpret_cast<const float4*>(tb + lane * 4);
  float4 b1 = *reinterpret_cast<const float4*>(tb + 256 + lane * 4);
  float s = a0.x * b0.x + a0.y * b0.y + a0.z * b0.z + a0.w * b0.w
          + a1.x * b1.x + a1.y * b1.y + a1.z * b1.z + a1.w * b1.w;
  for (int o = 32; o > 0; o >>= 1) s += __shfl_down(s, o);
  if (lane == 0) te[b * C_ + ch] = s + tpb[ch];
}

// ---------- text stage 2: attn_c = (te@wv.T+bv)@wo.T+bo ; txt_n = l2norm(te) ----------
__global__ __launch_bounds__(1024) void k_text2(
    const float* __restrict__ te, const float* __restrict__ wv,
    const float* __restrict__ bv, const float* __restrict__ wo,
    const float* __restrict__ bo,
    float* __restrict__ attn_c, float* __restrict__ txt_n)
{
  int b = blockIdx.x, t = threadIdx.x;
  int w = t >> 6, lane = t & 63;
  __shared__ float te_s[C_], vs_s[C_];
  __shared__ float red[16];
  __shared__ float inv_s;
  if (t < C_) te_s[t] = te[b * C_ + t];
  __syncthreads();
  {
    float nv = (t < C_) ? te_s[t] * te_s[t] : 0.f;
    for (int o = 32; o > 0; o >>= 1) nv += __shfl_down(nv, o);
    if (lane == 0) red[w] = nv;
  }
  __syncthreads();
  if (t == 0){
    float S = 0.f;
    for (int q = 0; q < 16; q++) S += red[q];
    inv_s = 1.f / fmaxf(sqrtf(S), 1e-12f);
  }
  #pragma unroll
  for (int r = 0; r < 16; r++){
    int ch = r * 16 + w;
    float4 av = *reinterpret_cast<const float4*>(wv + (size_t)ch * C_ + lane * 4);
    float s = av.x * te_s[lane * 4] + av.y * te_s[lane * 4 + 1]
            + av.z * te_s[lane * 4 + 2] + av.w * te_s[lane * 4 + 3];
    for (int o = 32; o > 0; o >>= 1) s += __shfl_down(s, o);
    if (lane == 0) vs_s[ch] = s + bv[ch];
  }
  __syncthreads();
  #pragma unroll
  for (int r = 0; r < 16; r++){
    int ch = r * 16 + w;
    float4 av = *reinterpret_cast<const float4*>(wo + (size_t)ch * C_ + lane * 4);
    float s = av.x * vs_s[lane * 4] + av.y * vs_s[lane * 4 + 1]
            + av.z * vs_s[lane * 4 + 2] + av.w * vs_s[lane * 4 + 3];
    for (int o = 32; o > 0; o >>= 1) s += __shfl_down(s, o);
    if (lane == 0) attn_c[b * C_ + ch] = s + bo[ch];
  }
  if (t < C_) txt_n[b * C_ + t] = te_s[t] * inv_s;
}

// ---------- source (residual+LN) -> srcT bf16 [C][N], snb bf16 [N][C], cos ----------
__global__ __launch_bounds__(256) void k_source(
    const float* __restrict__ img, const float* __restrict__ attn_c,
    const float* __restrict__ ln_g, const float* __restrict__ ln_b,
    const float* __restrict__ txt_n,
    u16* __restrict__ srcT, u16* __restrict__ snb, float* __restrict__ cosv)
{
  int b = blockIdx.y;
  int n0 = blockIdx.x * TN;
  int t = threadIdx.x;
  __shared__ float x[C_][TN + 1];
  __shared__ float ps[8][TN];
  __shared__ float ps2[8][TN];
  __shared__ float ac_s[C_], g_s[C_], bb_s[C_], tn_s[C_];
  __shared__ float mean_s[TN], rstd_s[TN], rn_s[TN];
  ac_s[t] = attn_c[b * C_ + t];
  g_s[t]  = ln_g[t];
  bb_s[t] = ln_b[t];
  tn_s[t] = txt_n[b * C_ + t];
  const float* ib = img + (size_t)b * C_ * N_ + n0;
  for (int k = 0; k < TN; k++){
    int e = t + k * 256;
    int c = e >> 5, nn = e & 31;
    x[c][nn] = ib[(size_t)c * N_ + nn];
  }
  __syncthreads();
  for (int k = 0; k < TN; k++){
    int e = t + k * 256;
    int c = e >> 5, nn = e & 31;
    x[c][nn] += ac_s[c];
  }
  __syncthreads();
  {
    int p = t >> 5, nn = t & 31;
    float s1 = 0.f, s2 = 0.f;
    for (int j = 0; j < 32; j++){
      float v = x[p + 8 * j][nn];
      s1 += v; s2 += v * v;
    }
    ps[p][nn] = s1; ps2[p][nn] = s2;
  }
  __syncthreads();
  if (t < TN){
    float S1 = 0.f, S2 = 0.f;
    for (int pp = 0; pp < 8; pp++){ S1 += ps[pp][t]; S2 += ps2[pp][t]; }
    float mean = S1 * (1.f / C_);
    float var = S2 * (1.f / C_) - mean * mean;
    mean_s[t] = mean;
    rstd_s[t] = rsqrtf(var + 1e-5f);
  }
  __syncthreads();
  for (int k = 0; k < TN; k++){
    float sval = (x[t][k] - mean_s[k]) * rstd_s[k] * g_s[t] + bb_s[t];
    x[t][k] = sval;
  }
  for (int kq = 0; kq < TN; kq += 4){
    ushort4 pkv;
    pkv.x = f2bf(x[t][kq + 0]);
    pkv.y = f2bf(x[t][kq + 1]);
    pkv.z = f2bf(x[t][kq + 2]);
    pkv.w = f2bf(x[t][kq + 3]);
    *reinterpret_cast<ushort4*>(&srcT[(size_t)(b * C_ + t) * N_ + n0 + kq]) = pkv;
  }
  __syncthreads();
  {
    int p = t >> 5, nn = t & 31;
    float s2 = 0.f, sd = 0.f;
    for (int j = 0; j < 32; j++){
      int c = p + 8 * j;
      float v = x[c][nn];
      s2 += v * v; sd += v * tn_s[c];
    }
    ps[p][nn] = s2; ps2[p][nn] = sd;
  }
  __syncthreads();
  if (t < TN){
    float S2 = 0.f, SD = 0.f;
    for (int pp = 0; pp < 8; pp++){ S2 += ps[pp][t]; SD += ps2[pp][t]; }
    float nrm = sqrtf(S2);
    float rn = 1.f / fmaxf(nrm, 1e-12f);
    rn_s[t] = rn;
    cosv[(b << 12) + n0 + t] = SD * rn;
  }
  __syncthreads();
  for (int k = 0; k < TN; k++){
    snb[(size_t)((b << 12) + n0 + k) * C_ + t] = f2bf(x[t][k] * rn_s[k]);
  }
}

// ---------- fused marginals + colsum zero: roles by blockIdx ----------
__global__ __launch_bounds__(256) void k_marg(
    const float* __restrict__ dens, const float* __restrict__ cosv,
    const float* __restrict__ temp_p,
    float* __restrict__ q, float* __restrict__ p, float* __restrict__ colsum)
{
  int bid = blockIdx.x, t = threadIdx.x;
  __shared__ float red[256];
  if (bid < B_){
    int b = bid;
    const float* d = dens + (size_t)b * N_;
    float s = 0.f;
    for (int n = t; n < N_; n += 256) s += fmaxf(d[n], 0.f) + 1e-6f;
    red[t] = s; __syncthreads();
    for (int o = 128; o > 0; o >>= 1){ if (t < o) red[t] += red[t + o]; __syncthreads(); }
    float inv = 1.f / red[0];
    for (int n = t; n < N_; n += 256) q[b * N_ + n] = (fmaxf(d[n], 0.f) + 1e-6f) * inv;
  } else if (bid < 2 * B_){
    int b = bid - B_;
    float temp = fmaxf(temp_p[0], 0.01f);
    float inv_t = 1.f / temp;
    const float* cb = cosv + (size_t)b * N_;
    float m = -1e30f;
    for (int n = t; n < N_; n += 256) m = fmaxf(m, cb[n] * inv_t);
    red[t] = m; __syncthreads();
    for (int o = 128; o > 0; o >>= 1){ if (t < o) red[t] = fmaxf(red[t], red[t + o]); __syncthreads(); }
    m = red[0]; __syncthreads();
    float s = 0.f;
    for (int n = t; n < N_; n += 256) s += expf(cb[n] * inv_t - m);
    red[t] = s; __syncthreads();
    for (int o = 128; o > 0; o >>= 1){ if (t < o) red[t] += red[t + o]; __syncthreads(); }
    float invs = 1.f / red[0];
    for (int n = t; n < N_; n += 256) p[b * N_ + n] = expf(cb[n] * inv_t - m) * invs;
  } else {
    int i = (bid - 2 * B_) * 256 + t;
    if (i < B_ * N_) colsum[i] = 0.f;
  }
}

// ---------- fused prep: conv-weight transpose + opw cast + inTp zero ----------
__global__ __launch_bounds__(256) void k_prep(
    const float* __restrict__ hm1_w, const float* __restrict__ hv1_w,
    const float* __restrict__ hm1_b, const float* __restrict__ hv1_b,
    const float* __restrict__ op_w,
    u16* __restrict__ Wt, float* __restrict__ biasF,
    u16* __restrict__ opwB, float* __restrict__ inTpf4)
{
  int bid = blockIdx.x, t = threadIdx.x;
  if (bid < 2304){
    int i = bid * 256 + t;   // < 9*256*256
    int ci = i & 255, co = (i >> 8) & 255, tap = i >> 16;
    float v = (co < CH_) ? hm1_w[((size_t)co * C_ + ci) * 9 + tap]
                         : hv1_w[((size_t)(co - CH_) * C_ + ci) * 9 + tap];
    Wt[i] = f2bf(v);
    if (i < CH_) biasF[i] = hm1_b[i];
    else if (i < 2 * CH_) biasF[i] = hv1_b[i - CH_];
  } else if (bid < 2560){
    int i = (bid - 2304) * 256 + t;
    opwB[i] = f2bf(op_w[i]);
  } else {
    int i = (bid - 2560) * 256 + t;   // float4 chunks: 282624 total
    if (i < (int)((size_t)B_ * PXTOT * C_ * 2 / 16)){
      float4 z = {0.f, 0.f, 0.f, 0.f};
      reinterpret_cast<float4*>(inTpf4)[i] = z;
    }
  }
}

// ---------- K = exp(20*(sn sn^T - 1)) -> FP8 e4m3 via MFMA + column sums ----------
__global__ __launch_bounds__(256) void k_kgen(
    const u16* __restrict__ snb, u8* __restrict__ Kp, float* __restrict__ colsum)
{
  int b = blockIdx.z;
  int m0 = blockIdx.x << 7, n0 = blockIdx.y << 7;
  int t = threadIdx.x;
  int lane = t & 63, w = t >> 6;
  int wr = w >> 1, wc = w & 1;
  __shared__ __align__(16) u16 shbuf[128 * 128];   // 32 KB: Al|Bl, low 16KB reused as CtT
  u16* Al = shbuf;
  u16* Bl = shbuf + 128 * 64;
  __shared__ float cs[128];
  if (t < 128) cs[t] = 0.f;
  f32x4 zero = {0.f, 0.f, 0.f, 0.f};
  f32x4 acc[4][4];
  #pragma unroll
  for (int i = 0; i < 4; i++){
    #pragma unroll
    for (int j = 0; j < 4; j++) acc[i][j] = zero;
  }
  const u16* sb = snb + (size_t)b * N_ * C_;
  const u16* ga = sb + (size_t)m0 * C_;
  const u16* gb = sb + (size_t)n0 * C_;
  for (int kt = 0; kt < C_; kt += 64){
    stage_tile(ga + kt, C_, Al, t);
    stage_tile(gb + kt, C_, Bl, t);
    __syncthreads();
    #pragma unroll
    for (int kh = 0; kh < 2; kh++){
      short8 af[4], bfv[4];
      #pragma unroll
      for (int i = 0; i < 4; i++){
        af[i]  = frag_ld(Al, wr * 64 + i * 16 + (lane & 15), kh * 4 + (lane >> 4));
        bfv[i] = frag_ld(Bl, wc * 64 + i * 16 + (lane & 15), kh * 4 + (lane >> 4));
      }
      #pragma unroll
      for (int i = 0; i < 4; i++){
        #pragma unroll
        for (int j = 0; j < 4; j++)
          acc[i][j] = MFMA_BF16(af[i], bfv[j], acc[i][j]);
      }
    }
    __syncthreads();
  }
  u8* CtT = (u8*)shbuf;
  #pragma unroll
  for (int j = 0; j < 4; j++){
    int col = wc * 64 + j * 16 + (lane & 15);
    float csum = 0.f;
    #pragma unroll
    for (int i = 0; i < 4; i++){
      int rb = wr * 64 + i * 16 + (lane >> 4) * 4;
      float e0 = __builtin_amdgcn_exp2f(fmaf(acc[i][j][0], L2E, -L2E));
      float e1 = __builtin_amdgcn_exp2f(fmaf(acc[i][j][1], L2E, -L2E));
      float e2 = __builtin_amdgcn_exp2f(fmaf(acc[i][j][2], L2E, -L2E));
      float e3 = __builtin_amdgcn_exp2f(fmaf(acc[i][j][3], L2E, -L2E));
      int pk = __builtin_amdgcn_cvt_pk_fp8_f32(e0, e1, 0, false);
      pk = __builtin_amdgcn_cvt_pk_fp8_f32(e2, e3, pk, true);
      f32x2 d0 = __builtin_amdgcn_cvt_pk_f32_fp8(pk, false);
      f32x2 d1 = __builtin_amdgcn_cvt_pk_f32_fp8(pk, true);
      csum += (d0.x + d0.y) + (d1.x + d1.y);
      int wq = rb >> 2;
      *reinterpret_cast<unsigned*>(CtT + col * 128 + ((wq ^ ((col & 7) << 2)) << 2)) = (unsigned)pk;
    }
    atomicAdd(&cs[col], csum);
  }
  __syncthreads();
  u8* Kb = Kp + (size_t)b * N_ * N_;
  for (int e = t; e < 1024; e += 256){
    int row = e >> 3, un = e & 7;
    uint4 v = *(const uint4*)(CtT + row * 128 + ((un ^ (row & 7)) << 4));
    *reinterpret_cast<uint4*>(&Kb[(size_t)(n0 + row) * N_ + m0 + (un << 4)]) = v;
  }
  if (t < 128) atomicAdd(&colsum[b * N_ + n0 + t], cs[t]);
}

// ---------- out[r] = marg[r] / (K_row_r . x + 1e-8), 16 rows/block; optional denom fuse ----------
__global__ __launch_bounds__(256) void k_mv(
    const u8* __restrict__ Kp, const float* __restrict__ x,
    const float* __restrict__ denom,
    const float* __restrict__ marg, float* __restrict__ outp)
{
  int r0 = blockIdx.x * 16;
  int b = r0 >> 12;
  int t = threadIdx.x, w = t >> 6, lane = t & 63;
  __shared__ __align__(16) float xs[N_];
  const float* xb = x + b * N_;
  if (denom){
    const float* db = denom + b * N_;
    for (int i = t; i < N_; i += 256) xs[i] = xb[i] / (db[i] + 1e-8f);
  } else {
    for (int i = t; i < N_ / 4; i += 256)
      reinterpret_cast<float4*>(xs)[i] = reinterpret_cast<const float4*>(xb)[i];
  }
  __syncthreads();
  int rbase = r0 + w * 4;
  const u8* Kr = Kp + (size_t)b * N_ * N_ + (size_t)(rbase & (N_ - 1)) * N_;
  float acc[4] = {0.f, 0.f, 0.f, 0.f};
  #pragma unroll
  for (int p = 0; p < 4; p++){
    int idx = p * 1024 + lane * 16;
    float4 xv0 = *reinterpret_cast<const float4*>(xs + idx);
    float4 xv1 = *reinterpret_cast<const float4*>(xs + idx + 4);
    float4 xv2 = *reinterpret_cast<const float4*>(xs + idx + 8);
    float4 xv3 = *reinterpret_cast<const float4*>(xs + idx + 12);
    #pragma unroll
    for (int k = 0; k < 4; k++){
      uint4 a = *reinterpret_cast<const uint4*>(Kr + (size_t)k * N_ + idx);
      f32x2 l0 = __builtin_amdgcn_cvt_pk_f32_fp8((int)a.x, false);
      f32x2 h0 = __builtin_amdgcn_cvt_pk_f32_fp8((int)a.x, true);
      f32x2 l1 = __builtin_amdgcn_cvt_pk_f32_fp8((int)a.y, false);
      f32x2 h1 = __builtin_amdgcn_cvt_pk_f32_fp8((int)a.y, true);
      f32x2 l2 = __builtin_amdgcn_cvt_pk_f32_fp8((int)a.z, false);
      f32x2 h2 = __builtin_amdgcn_cvt_pk_f32_fp8((int)a.z, true);
      f32x2 l3 = __builtin_amdgcn_cvt_pk_f32_fp8((int)a.w, false);
      f32x2 h3 = __builtin_amdgcn_cvt_pk_f32_fp8((int)a.w, true);
      acc[k] += l0.x * xv0.x + l0.y * xv0.y + h0.x * xv0.z + h0.y * xv0.w
              + l1.x * xv1.x + l1.y * xv1.y + h1.x * xv1.z + h1.y * xv1.w
              + l2.x * xv2.x + l2.y * xv2.y + h2.x * xv2.z + h2.y * xv2.w
              + l3.x * xv3.x + l3.y * xv3.y + h3.x * xv3.z + h3.y * xv3.w;
    }
  }
  #pragma unroll
  for (int k = 0; k < 4; k++)
    for (int o = 32; o > 0; o >>= 1) acc[k] += __shfl_down(acc[k], o);
  if (lane == 0){
    #pragma unroll
    for (int k = 0; k < 4; k++)
      outp[rbase + k] = marg[rbase + k] / (acc[k] + 1e-8f);
  }
}

// ---------- usrcT[c][n] = srcT[c][n] * u[n] ----------
__global__ __launch_bounds__(256) void k_uscale(
    const u16* __restrict__ srcT, const float* __restrict__ uu, u16* __restrict__ usrcT)
{
  int i = blockIdx.x * 256 + threadIdx.x;
  int n8 = i & (N_ / 8 - 1);
  int row = i >> 9;
  int b = row >> 8;
  const u16* s = srcT + (size_t)row * N_ + n8 * 8;
  short8 v = *reinterpret_cast<const short8*>(s);
  const float* ub = uu + b * N_ + n8 * 8;
  short8 o;
  #pragma unroll
  for (int q = 0; q < 8; q++) o[q] = (short)f2bf(bf2f((u16)v[q]) * ub[q]);
  *reinterpret_cast<short8*>(usrcT + (size_t)row * N_ + n8 * 8) = o;
}

// ---------- part[ks][m][c] = vv[m] * sum_{n in ks chunk} K[m][n]*usrc[n][c] ----------
__global__ __launch_bounds__(512) void k_full(
    const u8* __restrict__ Kp, const u16* __restrict__ usrcT,
    const float* __restrict__ vvv,
    u16* __restrict__ p0, u16* __restrict__ p1,
    u16* __restrict__ p2, u16* __restrict__ p3)
{
  int m0 = blockIdx.x << 6;
  int b = blockIdx.z >> 2, ks = blockIdx.z & 3;
  int t = threadIdx.x, lane = t & 63, w = t >> 6;   // w: 0..7 -> c-stripe of 32
  __shared__ __align__(16) u16 shbuf[64 * 64 + 256 * 64];  // Al 8KB | Bl 32KB
  __shared__ float vsm[64];
  u16* Al = shbuf;
  u16* Bl = shbuf + 64 * 64;
  if (t < 64) vsm[t] = vvv[b * N_ + m0 + t];
  f32x4 zero = {0.f, 0.f, 0.f, 0.f};
  f32x4 acc[4][2];
  #pragma unroll
  for (int i = 0; i < 4; i++){
    #pragma unroll
    for (int j = 0; j < 2; j++) acc[i][j] = zero;
  }
  const u8* ka = Kp + (size_t)b * N_ * N_ + (size_t)m0 * N_ + ks * (N_ / KSPLIT);
  const u16* ub = usrcT + (size_t)b * C_ * N_ + ks * (N_ / KSPLIT);
  for (int kt = 0; kt < N_ / KSPLIT; kt += 64){
    {
      int row = t >> 3, slot = t & 7;
      const u8* gp = ka + (size_t)row * N_ + kt + ((slot ^ (row & 7)) << 3);
      uint2 v8 = *reinterpret_cast<const uint2*>(gp);
      f32x2 q0 = __builtin_amdgcn_cvt_pk_f32_fp8((int)v8.x, false);
      f32x2 q1 = __builtin_amdgcn_cvt_pk_f32_fp8((int)v8.x, true);
      f32x2 q2 = __builtin_amdgcn_cvt_pk_f32_fp8((int)v8.y, false);
      f32x2 q3 = __builtin_amdgcn_cvt_pk_f32_fp8((int)v8.y, true);
      union { short8 s; unsigned u[4]; } o;
      asm("v_cvt_pk_bf16_f32 %0, %1, %2" : "=v"(o.u[0]) : "v"(q0.x), "v"(q0.y));
      asm("v_cvt_pk_bf16_f32 %0, %1, %2" : "=v"(o.u[1]) : "v"(q1.x), "v"(q1.y));
      asm("v_cvt_pk_bf16_f32 %0, %1, %2" : "=v"(o.u[2]) : "v"(q2.x), "v"(q2.y));
      asm("v_cvt_pk_bf16_f32 %0, %1, %2" : "=v"(o.u[3]) : "v"(q3.x), "v"(q3.y));
      *reinterpret_cast<short8*>(Al + (size_t)t * 8) = o.s;
    }
    stage_tile512_256(ub + kt, N_, Bl, t);
    __syncthreads();
    #pragma unroll
    for (int kh = 0; kh < 2; kh++){
      short8 af[4], bfv[2];
      #pragma unroll
      for (int i = 0; i < 4; i++)
        af[i] = frag_ld(Al, i * 16 + (lane & 15), kh * 4 + (lane >> 4));
      #pragma unroll
      for (int j = 0; j < 2; j++)
        bfv[j] = frag_ld(Bl, w * 32 + j * 16 + (lane & 15), kh * 4 + (lane >> 4));
      #pragma unroll
      for (int i = 0; i < 4; i++){
        #pragma unroll
        for (int j = 0; j < 2; j++)
          acc[i][j] = MFMA_BF16(af[i], bfv[j], acc[i][j]);
      }
    }
    __syncthreads();
  }
  u16* Ct = shbuf;
  #pragma unroll
  for (int j = 0; j < 2; j++){
    int col = w * 32 + j * 16 + (lane & 15);
    #pragma unroll
    for (int i = 0; i < 4; i++){
      int rb = i * 16 + (lane >> 4) * 4;
      #pragma unroll
      for (int r = 0; r < 4; r++){
        int row = rb + r;
        Ct[row * 256 + ((((col >> 3) ^ (row & 7)) << 3) | (col & 7))] =
            f2bf(acc[i][j][r] * vsm[row]);
      }
    }
  }
  __syncthreads();
  u16* P = (ks == 0) ? p0 : (ks == 1) ? p1 : (ks == 2) ? p2 : p3;
  for (int e = t; e < 2048; e += 512){
    int row = e >> 5, un = e & 31;
    short8 v8 = *(const short8*)(Ct + row * 256 + ((un ^ (row & 7)) << 3));
    *reinterpret_cast<short8*>(&P[(size_t)((b << 12) + m0 + row) * C_ + (un << 3)]) = v8;
  }
}

// ---------- out_feat = img + 1x1conv(p0+p1+p2+p3); also writes transposed bf16 inTp ----------
__global__ __launch_bounds__(256) void k_opconv(
    const u16* __restrict__ opwB, const float* __restrict__ opb,
    const u16* __restrict__ p0, const u16* __restrict__ p1,
    const u16* __restrict__ p2, const u16* __restrict__ p3,
    const float* __restrict__ img, float* __restrict__ outf,
    u16* __restrict__ inTp)
{
  int b = blockIdx.z;
  int n0 = blockIdx.x << 6;
  int co0 = blockIdx.y << 7;
  int t = threadIdx.x, lane = t & 63, w = t >> 6;
  int wr = w >> 1, wc = w & 1;              // wr: co half (64), wc: n half (32)
  __shared__ __align__(16) u16 Al[128 * 64];   // opw rows=co (reused as T in epilogue)
  __shared__ __align__(16) u16 Bl[64 * 64];    // fused rows=n
  f32x4 zero = {0.f, 0.f, 0.f, 0.f};
  f32x4 acc[4][2];
  #pragma unroll
  for (int i = 0; i < 4; i++){
    #pragma unroll
    for (int j = 0; j < 2; j++) acc[i][j] = zero;
  }
  for (int ct = 0; ct < C_; ct += 64){
    stage_tile(opwB + (size_t)co0 * C_ + ct, C_, Al, t);
    #pragma unroll
    for (int q = 0; q < 2; q++){
      int e = q * 256 + t;
      int row = e >> 3, slot = e & 7;
      int col = ct + ((slot ^ (row & 7)) << 3);
      size_t idx = (size_t)((b << 12) + n0 + row) * C_ + col;
      short8 a0 = *reinterpret_cast<const short8*>(p0 + idx);
      short8 a1 = *reinterpret_cast<const short8*>(p1 + idx);
      short8 a2 = *reinterpret_cast<const short8*>(p2 + idx);
      short8 a3 = *reinterpret_cast<const short8*>(p3 + idx);
      short8 o;
      #pragma unroll
      for (int k = 0; k < 8; k++)
        o[k] = (short)f2bf(bf2f((u16)a0[k]) + bf2f((u16)a1[k]) + bf2f((u16)a2[k]) + bf2f((u16)a3[k]));
      *reinterpret_cast<short8*>(Bl + (size_t)e * 8) = o;
    }
    __syncthreads();
    #pragma unroll
    for (int kh = 0; kh < 2; kh++){
      short8 af[4], bfv[2];
      #pragma unroll
      for (int i = 0; i < 4; i++)
        af[i] = frag_ld(Al, wr * 64 + i * 16 + (lane & 15), kh * 4 + (lane >> 4));
      #pragma unroll
      for (int j = 0; j < 2; j++)
        bfv[j] = frag_ld(Bl, wc * 32 + j * 16 + (lane & 15), kh * 4 + (lane >> 4));
      #pragma unroll
      for (int i = 0; i < 4; i++){
        #pragma unroll
        for (int j = 0; j < 2; j++)
          acc[i][j] = MFMA_BF16(af[i], bfv[j], acc[i][j]);
      }
    }
    __syncthreads();
  }
  // f32 out_feat writes + accumulate final values in regs (with img+bias)
  float fin[4][2][4];
  #pragma unroll
  for (int i = 0; i < 4; i++){
    int cb = co0 + wr * 64 + i * 16 + (lane >> 4) * 4;
    #pragma unroll
    for (int j = 0; j < 2; j++){
      int nc = n0 + wc * 32 + j * 16 + (lane & 15);
      #pragma unroll
      for (int r = 0; r < 4; r++){
        int co = cb + r;
        size_t oi = (size_t)(b * C_ + co) * N_ + nc;
        float v = acc[i][j][r] + img[oi] + opb[co];
        outf[oi] = v;
        fin[i][j][r] = v;
      }
    }
  }
  // transposed bf16 restage into T (= Al, 16KB): T[ncLocal][coLocal], 4-co packed,
  // swizzle: u16 idx = nc*128 + (cb4 ^ ((nc&15)<<3))
  u16* T = Al;
  #pragma unroll
  for (int i = 0; i < 4; i++){
    int cb4 = wr * 64 + i * 16 + (lane >> 4) * 4;
    #pragma unroll
    for (int j = 0; j < 2; j++){
      int ncL = wc * 32 + j * 16 + (lane & 15);
      ushort4 pk;
      pk.x = f2bf(fin[i][j][0]);
      pk.y = f2bf(fin[i][j][1]);
      pk.z = f2bf(fin[i][j][2]);
      pk.w = f2bf(fin[i][j][3]);
      *reinterpret_cast<ushort4*>(T + ncL * 128 + (cb4 ^ ((ncL & 15) << 3))) = pk;
    }
  }
  __syncthreads();
  // write 64 px rows x 128 ci (this co-half) to inTp, 16B units
  int y = n0 >> 6;
  for (int e = t; e < 1024; e += 256){
    int px = e >> 4, u = e & 15;
    uint4 v = *reinterpret_cast<const uint4*>(T + px * 128 + ((u << 3) ^ ((px & 15) << 3)));
    int pxp = y * 66 + px + 1;
    *reinterpret_cast<uint4*>(inTp + ((size_t)b * PXTOT + PXPAD + pxp) * C_ + co0 + u * 8) = v;
  }
}

// ---------- fused 3x3 conv (both heads) as implicit GEMM: C[co][px'] (bf16 out) ----------
__global__ __launch_bounds__(256) void k_conv3m(
    const u16* __restrict__ inTp, const u16* __restrict__ Wt,
    const float* __restrict__ biasF,
    u16* __restrict__ q0, u16* __restrict__ q1,
    u16* __restrict__ q2, u16* __restrict__ q3)
{
  int px0 = blockIdx.x << 6;           // 0..65 (66 tiles of 64 px')
  int cot = blockIdx.y;                // 0..1 (co halves of 256 fused)
  int b = blockIdx.z >> 2, ks = blockIdx.z & 3;
  int t = threadIdx.x, lane = t & 63, w = t >> 6;
  int wr = w >> 1, wc = w & 1;         // wr: co half (64), wc: px half (32)
  __shared__ __align__(16) u16 Al[128 * 64];   // weights: 128 co rows x 64 ci
  __shared__ __align__(16) u16 Bl[64 * 64];    // input:   64 px rows x 64 ci
  f32x4 zero = {0.f, 0.f, 0.f, 0.f};
  f32x4 acc[4][2];
  #pragma unroll
  for (int i = 0; i < 4; i++){
    #pragma unroll
    for (int j = 0; j < 2; j++) acc[i][j] = zero;
  }
  const u16* inb = inTp + ((size_t)b * PXTOT + PXPAD + px0) * C_;
  for (int s = ks * 9; s < ks * 9 + 9; s++){
    int tap = s >> 2, cic = (s & 3) << 6;
    int ky = tap / 3, kx = tap - ky * 3;
    int off = (ky - 1) * 66 + (kx - 1);
    stage_tile(Wt + ((size_t)tap * 256 + cot * 128) * C_ + cic, C_, Al, t);
    stage_tile256_64(inb + (ptrdiff_t)off * C_ + cic, C_, Bl, t);
    __syncthreads();
    #pragma unroll
    for (int kh = 0; kh < 2; kh++){
      short8 af[4], bfv[2];
      #pragma unroll
      for (int i = 0; i < 4; i++)
        af[i] = frag_ld(Al, wr * 64 + i * 16 + (lane & 15), kh * 4 + (lane >> 4));
      #pragma unroll
      for (int j = 0; j < 2; j++)
        bfv[j] = frag_ld(Bl, wc * 32 + j * 16 + (lane & 15), kh * 4 + (lane >> 4));
      #pragma unroll
      for (int i = 0; i < 4; i++){
        #pragma unroll
        for (int j = 0; j < 2; j++)
          acc[i][j] = MFMA_BF16(af[i], bfv[j], acc[i][j]);
      }
    }
    __syncthreads();
  }
  u16* P = (ks == 0) ? q0 : (ks == 1) ? q1 : (ks == 2) ? q2 : q3;
  #pragma unroll
  for (int i = 0; i < 4; i++){
    #pragma unroll
    for (int j = 0; j < 2; j++){
      int pxp = px0 + wc * 32 + j * 16 + (lane & 15);
      int y = pxp / 66;
      int xm = pxp - y * 66;
      bool valid = (xm >= 1 && xm <= 64);
      int outn = y * 64 + xm - 1;
      #pragma unroll
      for (int r = 0; r < 4; r++){
        int co = cot * 128 + wr * 64 + i * 16 + (lane >> 4) * 4 + r;
        if (valid){
          float bco = (ks == 0) ? biasF[co] : 0.f;
          P[((size_t)(b * 256 + co)) * N_ + outn] = f2bf(acc[i][j][r] + bco);
        }
      }
    }
  }
}

// ---------- batchnorm stats over (B,H,W) per fused channel (sums 4 K-parts) ----------
__global__ __launch_bounds__(256) void k_bnstats2(
    const u16* __restrict__ p0, const u16* __restrict__ p1,
    const u16* __restrict__ p2, const u16* __restrict__ p3,
    float* __restrict__ stats)
{
  int ch = blockIdx.x, t = threadIdx.x;   // ch in [0,256)
  __shared__ float r1[256], r2[256];
  float s1 = 0.f, s2 = 0.f;
  for (int i = t; i < B_ * N_; i += 256){
    int b = i >> 12, n = i & (N_ - 1);
    size_t idx = ((size_t)(b * 256 + ch)) * N_ + n;
    float v = bf2f(p0[idx]) + bf2f(p1[idx]) + bf2f(p2[idx]) + bf2f(p3[idx]);
    s1 += v; s2 += v * v;
  }
  r1[t] = s1; r2[t] = s2; __syncthreads();
  for (int o = 128; o > 0; o >>= 1){
    if (t < o){ r1[t] += r1[t + o]; r2[t] += r2[t + o]; }
    __syncthreads();
  }
  if (t == 0){
    float mean = r1[0] / (float)(B_ * N_);
    float var = r2[0] / (float)(B_ * N_) - mean * mean;
    stats[ch * 2] = mean;
    stats[ch * 2 + 1] = rsqrtf(var + 1e-5f);
  }
}

// ---------- fused dual-head: relu(bn(mid)) -> 1x1 conv to 2 ch per head ----------
__global__ __launch_bounds__(256) void k_headF(
    const u16* __restrict__ p0, const u16* __restrict__ p1,
    const u16* __restrict__ p2, const u16* __restrict__ p3,
    const float* __restrict__ stats,
    const float* __restrict__ hm_g, const float* __restrict__ hm_b,
    const float* __restrict__ hm2_w, const float* __restrict__ hm2_b,
    const float* __restrict__ hv_g, const float* __restrict__ hv_b,
    const float* __restrict__ hv2_w, const float* __restrict__ hv2_b,
    float* __restrict__ outhm, float* __restrict__ outhv)
{
  int t = threadIdx.x;
  int nl = t & 31, g = t >> 5;
  int idx0 = blockIdx.x * 32;
  int idx = idx0 + nl;
  int b = idx >> 12, n = idx & (N_ - 1);
  int head = g >> 2;
  int ch0 = (g & 3) * 32;
  const float* gg = head ? hv_g : hm_g;
  const float* gb = head ? hv_b : hm_b;
  const float* w2 = head ? hv2_w : hm2_w;
  float a0 = 0.f, a1 = 0.f;
  #pragma unroll 8
  for (int cc = 0; cc < 32; cc++){
    int ch = ch0 + cc;
    int fc = head * CH_ + ch;
    size_t id = ((size_t)(b * 256 + fc)) * N_ + n;
    float v = bf2f(p0[id]) + bf2f(p1[id]) + bf2f(p2[id]) + bf2f(p3[id]);
    float rr = fmaxf((v - stats[fc * 2]) * stats[fc * 2 + 1] * gg[ch] + gb[ch], 0.f);
    a0 += w2[ch] * rr;
    a1 += w2[CH_ + ch] * rr;
  }
  __shared__ float r0[8][32], r1[8][32];
  r0[g][nl] = a0; r1[g][nl] = a1;
  __syncthreads();
  if (t < 64){
    int hh = t >> 5, n2 = t & 31;
    int base = hh * 4;
    float s0 = r0[base][n2] + r0[base + 1][n2] + r0[base + 2][n2] + r0[base + 3][n2];
    float s1 = r1[base][n2] + r1[base + 1][n2] + r1[base + 2][n2] + r1[base + 3][n2];
    int idx2 = idx0 + n2;
    int b2 = idx2 >> 12, nn = idx2 & (N_ - 1);
    float* op = hh ? outhv : outhm;
    const float* bp = hh ? hv2_b : hm2_b;
    op[(size_t)(b2 * 2) * N_ + nn] = s0 + bp[0];
    op[(size_t)(b2 * 2 + 1) * N_ + nn] = s1 + bp[1];
  }
}

extern "C" void kernel_launch(void* const* d_in, const int* in_sizes, int n_in,
                              void* d_out, int out_size, void* d_ws, size_t ws_size,
                              hipStream_t stream)
{
  const float* img   = (const float*)d_in[0];
  const float* txt   = (const float*)d_in[1];
  const float* dens  = (const float*)d_in[2];
  const float* tp_w  = (const float*)d_in[3];
  const float* tp_b  = (const float*)d_in[4];
  const float* wv    = (const float*)d_in[9];
  const float* bv    = (const float*)d_in[10];
  const float* wo    = (const float*)d_in[11];
  const float* bo    = (const float*)d_in[12];
  const float* ln_g  = (const float*)d_in[13];
  const float* ln_b  = (const float*)d_in[14];
  const float* op_w  = (const float*)d_in[15];
  const float* op_b  = (const float*)d_in[16];
  const float* hm1_w = (const float*)d_in[17];
  const float* hm1_b = (const float*)d_in[18];
  const float* hm_g  = (const float*)d_in[19];
  const float* hm_b  = (const float*)d_in[20];
  const float* hm2_w = (const float*)d_in[21];
  const float* hm2_b = (const float*)d_in[22];
  const float* hv1_w = (const float*)d_in[23];
  const float* hv1_b = (const float*)d_in[24];
  const float* hv_g  = (const float*)d_in[25];
  const float* hv_b  = (const float*)d_in[26];
  const float* hv2_w = (const float*)d_in[27];
  const float* hv2_b = (const float*)d_in[28];
  const float* temp  = (const float*)d_in[29];

  char* wsb = (char*)d_ws;
  size_t off = 0;
  auto alloc = [&](size_t bytes) -> void* {
    void* p = wsb + off;
    off += (bytes + 255) & ~(size_t)255;
    return p;
  };
  u8*    Km     = (u8*)   alloc((size_t)B_ * N_ * N_ * sizeof(u8));    // 33.5 MB (fp8)
  u16*   snb16  = (u16*)  alloc((size_t)B_ * N_ * C_ * sizeof(u16));   // 4.19 MB (part0 alias)
  u16*   srcT16 = (u16*)  alloc((size_t)B_ * C_ * N_ * sizeof(u16));   // 4.19 MB
  u16*   usrcT  = (u16*)  alloc((size_t)B_ * C_ * N_ * sizeof(u16));   // 4.19 MB
  u16*   part1  = (u16*)  alloc((size_t)B_ * N_ * C_ * sizeof(u16));   // 4.19 MB
  u16*   part2  = (u16*)  alloc((size_t)B_ * N_ * C_ * sizeof(u16));   // 4.19 MB
  u16*   part3  = (u16*)  alloc((size_t)B_ * N_ * C_ * sizeof(u16));   // 4.19 MB
  u16*   inTp   = (u16*)  alloc((size_t)B_ * PXTOT * C_ * sizeof(u16));// 4.52 MB
  u16*   Wt     = (u16*)  alloc((size_t)9 * 256 * C_ * sizeof(u16));   // 1.18 MB
  u16*   opwB   = (u16*)  alloc((size_t)C_ * C_ * sizeof(u16));        // 131 KB
  float* biasF  = (float*)alloc(256 * sizeof(float));
  float* teb    = (float*)alloc(B_ * C_ * sizeof(float));
  float* attn_c = (float*)alloc(B_ * C_ * sizeof(float));
  float* txt_n  = (float*)alloc(B_ * C_ * sizeof(float));
  float* cosv   = (float*)alloc(B_ * N_ * sizeof(float));
  float* qm     = (float*)alloc(B_ * N_ * sizeof(float));
  float* pm     = (float*)alloc(B_ * N_ * sizeof(float));
  float* uu     = (float*)alloc(B_ * N_ * sizeof(float));
  float* vvv    = (float*)alloc(B_ * N_ * sizeof(float));
  float* colsum = (float*)alloc(B_ * N_ * sizeof(float));
  float* stats  = (float*)alloc(256 * 2 * sizeof(float));

  // alias: part0 over snb16 (snb dead after kgen; part0 written by k_full)
  u16* part0 = snb16;

  float* outf  = (float*)d_out;
  float* outhm = outf + (size_t)B_ * C_ * N_;
  float* outhv = outhm + (size_t)B_ * 2 * N_;

  k_text1<<<dim3(64, B_), 256, 0, stream>>>(txt, tp_w, tp_b, teb);
  k_text2<<<B_, 1024, 0, stream>>>(teb, wv, bv, wo, bo, attn_c, txt_n);
  k_prep<<<2560 + 1104, 256, 0, stream>>>(hm1_w, hv1_w, hm1_b, hv1_b, op_w, Wt, biasF, opwB, (float*)inTp);
  k_source<<<dim3(N_ / TN, B_), 256, 0, stream>>>(img, attn_c, ln_g, ln_b, txt_n, srcT16, snb16, cosv);
  k_marg<<<2 * B_ + B_ * N_ / 256, 256, 0, stream>>>(dens, cosv, temp, qm, pm, colsum);
  // K generation (fp8 e4m3 output via hw converters, full grid)
  k_kgen<<<dim3(N_ / 128, N_ / 128, B_), 256, 0, stream>>>(snb16, Km, colsum);
  // Sinkhorn (K symmetric: K^T x == K x); first mv fuses vv1 = qm/colsum
  k_mv<<<B_ * N_ / 16, 256, 0, stream>>>(Km, qm, colsum, pm, uu);            // u1
  k_mv<<<B_ * N_ / 16, 256, 0, stream>>>(Km, uu, nullptr, qm, vvv);          // vv2
  k_mv<<<B_ * N_ / 16, 256, 0, stream>>>(Km, vvv, nullptr, pm, uu);          // u2
  k_mv<<<B_ * N_ / 16, 256, 0, stream>>>(Km, uu, nullptr, qm, vvv);          // vv3
  k_mv<<<B_ * N_ / 16, 256, 0, stream>>>(Km, vvv, nullptr, pm, uu);          // u3
  k_uscale<<<(B_ * C_ * N_ / 8 + 255) / 256, 256, 0, stream>>>(srcT16, uu, usrcT);
  k_full<<<dim3(N_ / 64, 1, B_ * KSPLIT), 512, 0, stream>>>(Km, usrcT, vvv, part0, part1, part2, part3);
  k_opconv<<<dim3(N_ / 64, C_ / 128, B_), 256, 0, stream>>>(opwB, op_b, part0, part1, part2, part3, img, outf, inTp);
  k_conv3m<<<dim3(66, 2, B_ * KSPLIT), 256, 0, stream>>>(inTp, Wt, biasF, part0, part1, part2, part3);
  k_bnstats2<<<256, 256, 0, stream>>>(part0, part1, part2, part3, stats);
  k_headF<<<B_ * N_ / 32, 256, 0, stream>>>(part0, part1, part2, part3, stats,
      hm_g, hm_b, hm2_w, hm2_b, hv_g, hv_b, hv2_w, hv2_b, outhm, outhv);
}

// Round 13
// 211.780 us; speedup vs baseline: 1.4238x; 1.0266x over previous
//
#include <hip/hip_runtime.h>

#define B_ 2
#define C_ 256
#define N_ 4096
#define TXT_ 512
#define CH_ 128
#define TN 32
#define KSPLIT 4
#define PXR 4224          // 64 * 66 padded-pixel rows per batch
#define PXPAD 96          // halo pad rows each side
#define PXTOT (PXR + 2 * PXPAD)
#define L2E 28.853900817779268f

typedef unsigned short u16;
typedef unsigned char u8;
typedef __attribute__((ext_vector_type(8))) short short8;
typedef __attribute__((ext_vector_type(4))) float f32x4;
typedef __attribute__((ext_vector_type(2))) float f32x2;

__device__ __forceinline__ float bf2f(u16 v){
  union { unsigned u; float f; } w; w.u = ((unsigned)v) << 16; return w.f;
}
__device__ __forceinline__ u16 f2bf(float f){
  union { float f; unsigned u; } w; w.f = f;
  unsigned r = w.u + 0x7fffu + ((w.u >> 16) & 1u);
  return (u16)(r >> 16);
}

#define MFMA_BF16(a,b,c) __builtin_amdgcn_mfma_f32_16x16x32_bf16(a,b,c,0,0,0)

// Stage a 128-row x 64-col bf16 tile (256 threads). Pre-swizzled source, linear LDS dest.
__device__ __forceinline__ void stage_tile(const u16* __restrict__ g, int stride, u16* lds, int t)
{
  #pragma unroll
  for (int q = 0; q < 4; q++){
    int e = q * 256 + t;          // 16B unit index
    int row = e >> 3;
    int slot = e & 7;
    const u16* gp = g + (size_t)row * stride + ((slot ^ (row & 7)) << 3);
    u16* lp = lds + (size_t)e * 8;
    __builtin_amdgcn_global_load_lds((const __attribute__((address_space(1))) void*)gp,
                                     (__attribute__((address_space(3))) void*)lp, 16, 0, 0);
  }
}

// 256 threads, 64 rows.
__device__ __forceinline__ void stage_tile256_64(const u16* __restrict__ g, int stride, u16* lds, int t)
{
  #pragma unroll
  for (int q = 0; q < 2; q++){
    int e = q * 256 + t;          // 512 units
    int row = e >> 3;
    int slot = e & 7;
    const u16* gp = g + (size_t)row * stride + ((slot ^ (row & 7)) << 3);
    u16* lp = lds + (size_t)e * 8;
    __builtin_amdgcn_global_load_lds((const __attribute__((address_space(1))) void*)gp,
                                     (__attribute__((address_space(3))) void*)lp, 16, 0, 0);
  }
}

// 512-thread variant: 256 rows.
__device__ __forceinline__ void stage_tile512_256(const u16* __restrict__ g, int stride, u16* lds, int t)
{
  #pragma unroll
  for (int q = 0; q < 4; q++){
    int e = q * 512 + t;          // 2048 units
    int row = e >> 3;
    int slot = e & 7;
    const u16* gp = g + (size_t)row * stride + ((slot ^ (row & 7)) << 3);
    u16* lp = lds + (size_t)e * 8;
    __builtin_amdgcn_global_load_lds((const __attribute__((address_space(1))) void*)gp,
                                     (__attribute__((address_space(3))) void*)lp, 16, 0, 0);
  }
}

__device__ __forceinline__ short8 frag_ld(const u16* lds, int row, int slot)
{
  return *(const short8*)(lds + row * 64 + ((slot ^ (row & 7)) << 3));
}

// ---------- fused prep: text GEMV stage1 + conv-weight transpose + opw cast + inTp zero ----------
__global__ __launch_bounds__(256) void k_prep(
    const float* __restrict__ txt, const float* __restrict__ tpw,
    const float* __restrict__ tpb, float* __restrict__ te,
    const float* __restrict__ hm1_w, const float* __restrict__ hv1_w,
    const float* __restrict__ hm1_b, const float* __restrict__ hv1_b,
    const float* __restrict__ op_w,
    u16* __restrict__ Wt, float* __restrict__ biasF,
    u16* __restrict__ opwB, float* __restrict__ inTpf4)
{
  int bid = blockIdx.x, t = threadIdx.x;
  if (bid < 128){
    // text stage 1: te = txt @ tp_w.T + tp_b (wave-per-channel)
    int b = bid >> 6;
    int ch = (bid & 63) * 4 + (t >> 6);
    int lane = t & 63;
    const float* tb = txt + (size_t)b * TXT_;
    const float* wr = tpw + (size_t)ch * TXT_;
    float4 a0 = *reinterpret_cast<const float4*>(wr + lane * 4);
    float4 a1 = *reinterpret_cast<const float4*>(wr + 256 + lane * 4);
    float4 b0 = *reinterpret_cast<const float4*>(tb + lane * 4);
    float4 b1 = *reinterpret_cast<const float4*>(tb + 256 + lane * 4);
    float s = a0.x * b0.x + a0.y * b0.y + a0.z * b0.z + a0.w * b0.w
            + a1.x * b1.x + a1.y * b1.y + a1.z * b1.z + a1.w * b1.w;
    for (int o = 32; o > 0; o >>= 1) s += __shfl_down(s, o);
    if (lane == 0) te[b * C_ + ch] = s + tpb[ch];
  } else if (bid < 128 + 2304){
    int i = (bid - 128) * 256 + t;   // < 9*256*256
    int ci = i & 255, co = (i >> 8) & 255, tap = i >> 16;
    float v = (co < CH_) ? hm1_w[((size_t)co * C_ + ci) * 9 + tap]
                         : hv1_w[((size_t)(co - CH_) * C_ + ci) * 9 + tap];
    Wt[i] = f2bf(v);
    if (i < CH_) biasF[i] = hm1_b[i];
    else if (i < 2 * CH_) biasF[i] = hv1_b[i - CH_];
  } else if (bid < 128 + 2560){
    int i = (bid - 128 - 2304) * 256 + t;
    opwB[i] = f2bf(op_w[i]);
  } else {
    int i = (bid - 128 - 2560) * 256 + t;   // float4 chunks: 282624 total
    if (i < (int)((size_t)B_ * PXTOT * C_ * 2 / 16)){
      float4 z = {0.f, 0.f, 0.f, 0.f};
      reinterpret_cast<float4*>(inTpf4)[i] = z;
    }
  }
}

// ---------- text stage 2: attn_c = (te@wv.T+bv)@wo.T+bo ; txt_n = l2norm(te) ----------
__global__ __launch_bounds__(1024) void k_text2(
    const float* __restrict__ te, const float* __restrict__ wv,
    const float* __restrict__ bv, const float* __restrict__ wo,
    const float* __restrict__ bo,
    float* __restrict__ attn_c, float* __restrict__ txt_n)
{
  int b = blockIdx.x, t = threadIdx.x;
  int w = t >> 6, lane = t & 63;
  __shared__ float te_s[C_], vs_s[C_];
  __shared__ float red[16];
  __shared__ float inv_s;
  if (t < C_) te_s[t] = te[b * C_ + t];
  __syncthreads();
  {
    float nv = (t < C_) ? te_s[t] * te_s[t] : 0.f;
    for (int o = 32; o > 0; o >>= 1) nv += __shfl_down(nv, o);
    if (lane == 0) red[w] = nv;
  }
  __syncthreads();
  if (t == 0){
    float S = 0.f;
    for (int q = 0; q < 16; q++) S += red[q];
    inv_s = 1.f / fmaxf(sqrtf(S), 1e-12f);
  }
  #pragma unroll
  for (int r = 0; r < 16; r++){
    int ch = r * 16 + w;
    float4 av = *reinterpret_cast<const float4*>(wv + (size_t)ch * C_ + lane * 4);
    float s = av.x * te_s[lane * 4] + av.y * te_s[lane * 4 + 1]
            + av.z * te_s[lane * 4 + 2] + av.w * te_s[lane * 4 + 3];
    for (int o = 32; o > 0; o >>= 1) s += __shfl_down(s, o);
    if (lane == 0) vs_s[ch] = s + bv[ch];
  }
  __syncthreads();
  #pragma unroll
  for (int r = 0; r < 16; r++){
    int ch = r * 16 + w;
    float4 av = *reinterpret_cast<const float4*>(wo + (size_t)ch * C_ + lane * 4);
    float s = av.x * vs_s[lane * 4] + av.y * vs_s[lane * 4 + 1]
            + av.z * vs_s[lane * 4 + 2] + av.w * vs_s[lane * 4 + 3];
    for (int o = 32; o > 0; o >>= 1) s += __shfl_down(s, o);
    if (lane == 0) attn_c[b * C_ + ch] = s + bo[ch];
  }
  if (t < C_) txt_n[b * C_ + t] = te_s[t] * inv_s;
}

// ---------- source (residual+LN) -> srcT bf16 [C][N], snb bf16 [N][C], cos ----------
__global__ __launch_bounds__(256) void k_source(
    const float* __restrict__ img, const float* __restrict__ attn_c,
    const float* __restrict__ ln_g, const float* __restrict__ ln_b,
    const float* __restrict__ txt_n,
    u16* __restrict__ srcT, u16* __restrict__ snb, float* __restrict__ cosv)
{
  int b = blockIdx.y;
  int n0 = blockIdx.x * TN;
  int t = threadIdx.x;
  __shared__ float x[C_][TN + 1];
  __shared__ float ps[8][TN];
  __shared__ float ps2[8][TN];
  __shared__ float ac_s[C_], g_s[C_], bb_s[C_], tn_s[C_];
  __shared__ float mean_s[TN], rstd_s[TN], rn_s[TN];
  ac_s[t] = attn_c[b * C_ + t];
  g_s[t]  = ln_g[t];
  bb_s[t] = ln_b[t];
  tn_s[t] = txt_n[b * C_ + t];
  const float* ib = img + (size_t)b * C_ * N_ + n0;
  for (int k = 0; k < TN; k++){
    int e = t + k * 256;
    int c = e >> 5, nn = e & 31;
    x[c][nn] = ib[(size_t)c * N_ + nn];
  }
  __syncthreads();
  for (int k = 0; k < TN; k++){
    int e = t + k * 256;
    int c = e >> 5, nn = e & 31;
    x[c][nn] += ac_s[c];
  }
  __syncthreads();
  {
    int p = t >> 5, nn = t & 31;
    float s1 = 0.f, s2 = 0.f;
    for (int j = 0; j < 32; j++){
      float v = x[p + 8 * j][nn];
      s1 += v; s2 += v * v;
    }
    ps[p][nn] = s1; ps2[p][nn] = s2;
  }
  __syncthreads();
  if (t < TN){
    float S1 = 0.f, S2 = 0.f;
    for (int pp = 0; pp < 8; pp++){ S1 += ps[pp][t]; S2 += ps2[pp][t]; }
    float mean = S1 * (1.f / C_);
    float var = S2 * (1.f / C_) - mean * mean;
    mean_s[t] = mean;
    rstd_s[t] = rsqrtf(var + 1e-5f);
  }
  __syncthreads();
  for (int k = 0; k < TN; k++){
    float sval = (x[t][k] - mean_s[k]) * rstd_s[k] * g_s[t] + bb_s[t];
    x[t][k] = sval;
  }
  for (int kq = 0; kq < TN; kq += 4){
    ushort4 pkv;
    pkv.x = f2bf(x[t][kq + 0]);
    pkv.y = f2bf(x[t][kq + 1]);
    pkv.z = f2bf(x[t][kq + 2]);
    pkv.w = f2bf(x[t][kq + 3]);
    *reinterpret_cast<ushort4*>(&srcT[(size_t)(b * C_ + t) * N_ + n0 + kq]) = pkv;
  }
  __syncthreads();
  {
    int p = t >> 5, nn = t & 31;
    float s2 = 0.f, sd = 0.f;
    for (int j = 0; j < 32; j++){
      int c = p + 8 * j;
      float v = x[c][nn];
      s2 += v * v; sd += v * tn_s[c];
    }
    ps[p][nn] = s2; ps2[p][nn] = sd;
  }
  __syncthreads();
  if (t < TN){
    float S2 = 0.f, SD = 0.f;
    for (int pp = 0; pp < 8; pp++){ S2 += ps[pp][t]; SD += ps2[pp][t]; }
    float nrm = sqrtf(S2);
    float rn = 1.f / fmaxf(nrm, 1e-12f);
    rn_s[t] = rn;
    cosv[(b << 12) + n0 + t] = SD * rn;
  }
  __syncthreads();
  for (int k = 0; k < TN; k++){
    snb[(size_t)((b << 12) + n0 + k) * C_ + t] = f2bf(x[t][k] * rn_s[k]);
  }
}

// ---------- fused marginals + colsum zero: roles by blockIdx ----------
__global__ __launch_bounds__(256) void k_marg(
    const float* __restrict__ dens, const float* __restrict__ cosv,
    const float* __restrict__ temp_p,
    float* __restrict__ q, float* __restrict__ p, float* __restrict__ colsum)
{
  int bid = blockIdx.x, t = threadIdx.x;
  __shared__ float red[256];
  if (bid < B_){
    int b = bid;
    const float* d = dens + (size_t)b * N_;
    float s = 0.f;
    for (int n = t; n < N_; n += 256) s += fmaxf(d[n], 0.f) + 1e-6f;
    red[t] = s; __syncthreads();
    for (int o = 128; o > 0; o >>= 1){ if (t < o) red[t] += red[t + o]; __syncthreads(); }
    float inv = 1.f / red[0];
    for (int n = t; n < N_; n += 256) q[b * N_ + n] = (fmaxf(d[n], 0.f) + 1e-6f) * inv;
  } else if (bid < 2 * B_){
    int b = bid - B_;
    float temp = fmaxf(temp_p[0], 0.01f);
    float inv_t = 1.f / temp;
    const float* cb = cosv + (size_t)b * N_;
    float m = -1e30f;
    for (int n = t; n < N_; n += 256) m = fmaxf(m, cb[n] * inv_t);
    red[t] = m; __syncthreads();
    for (int o = 128; o > 0; o >>= 1){ if (t < o) red[t] = fmaxf(red[t], red[t + o]); __syncthreads(); }
    m = red[0]; __syncthreads();
    float s = 0.f;
    for (int n = t; n < N_; n += 256) s += expf(cb[n] * inv_t - m);
    red[t] = s; __syncthreads();
    for (int o = 128; o > 0; o >>= 1){ if (t < o) red[t] += red[t + o]; __syncthreads(); }
    float invs = 1.f / red[0];
    for (int n = t; n < N_; n += 256) p[b * N_ + n] = expf(cb[n] * inv_t - m) * invs;
  } else {
    int i = (bid - 2 * B_) * 256 + t;
    if (i < B_ * N_) colsum[i] = 0.f;
  }
}

// ---------- K = exp(20*(sn sn^T - 1)) -> FP8 e4m3 via MFMA + column sums ----------
__global__ __launch_bounds__(256) void k_kgen(
    const u16* __restrict__ snb, u8* __restrict__ Kp, float* __restrict__ colsum)
{
  int b = blockIdx.z;
  int m0 = blockIdx.x << 7, n0 = blockIdx.y << 7;
  int t = threadIdx.x;
  int lane = t & 63, w = t >> 6;
  int wr = w >> 1, wc = w & 1;
  __shared__ __align__(16) u16 shbuf[128 * 128];   // 32 KB: Al|Bl, low 16KB reused as CtT
  u16* Al = shbuf;
  u16* Bl = shbuf + 128 * 64;
  __shared__ float cs[128];
  if (t < 128) cs[t] = 0.f;
  f32x4 zero = {0.f, 0.f, 0.f, 0.f};
  f32x4 acc[4][4];
  #pragma unroll
  for (int i = 0; i < 4; i++){
    #pragma unroll
    for (int j = 0; j < 4; j++) acc[i][j] = zero;
  }
  const u16* sb = snb + (size_t)b * N_ * C_;
  const u16* ga = sb + (size_t)m0 * C_;
  const u16* gb = sb + (size_t)n0 * C_;
  for (int kt = 0; kt < C_; kt += 64){
    stage_tile(ga + kt, C_, Al, t);
    stage_tile(gb + kt, C_, Bl, t);
    __syncthreads();
    #pragma unroll
    for (int kh = 0; kh < 2; kh++){
      short8 af[4], bfv[4];
      #pragma unroll
      for (int i = 0; i < 4; i++){
        af[i]  = frag_ld(Al, wr * 64 + i * 16 + (lane & 15), kh * 4 + (lane >> 4));
        bfv[i] = frag_ld(Bl, wc * 64 + i * 16 + (lane & 15), kh * 4 + (lane >> 4));
      }
      #pragma unroll
      for (int i = 0; i < 4; i++){
        #pragma unroll
        for (int j = 0; j < 4; j++)
          acc[i][j] = MFMA_BF16(af[i], bfv[j], acc[i][j]);
      }
    }
    __syncthreads();
  }
  u8* CtT = (u8*)shbuf;
  #pragma unroll
  for (int j = 0; j < 4; j++){
    int col = wc * 64 + j * 16 + (lane & 15);
    float csum = 0.f;
    #pragma unroll
    for (int i = 0; i < 4; i++){
      int rb = wr * 64 + i * 16 + (lane >> 4) * 4;
      float e0 = __builtin_amdgcn_exp2f(fmaf(acc[i][j][0], L2E, -L2E));
      float e1 = __builtin_amdgcn_exp2f(fmaf(acc[i][j][1], L2E, -L2E));
      float e2 = __builtin_amdgcn_exp2f(fmaf(acc[i][j][2], L2E, -L2E));
      float e3 = __builtin_amdgcn_exp2f(fmaf(acc[i][j][3], L2E, -L2E));
      int pk = __builtin_amdgcn_cvt_pk_fp8_f32(e0, e1, 0, false);
      pk = __builtin_amdgcn_cvt_pk_fp8_f32(e2, e3, pk, true);
      f32x2 d0 = __builtin_amdgcn_cvt_pk_f32_fp8(pk, false);
      f32x2 d1 = __builtin_amdgcn_cvt_pk_f32_fp8(pk, true);
      csum += (d0.x + d0.y) + (d1.x + d1.y);
      int wq = rb >> 2;
      *reinterpret_cast<unsigned*>(CtT + col * 128 + ((wq ^ ((col & 7) << 2)) << 2)) = (unsigned)pk;
    }
    atomicAdd(&cs[col], csum);
  }
  __syncthreads();
  u8* Kb = Kp + (size_t)b * N_ * N_;
  for (int e = t; e < 1024; e += 256){
    int row = e >> 3, un = e & 7;
    uint4 v = *(const uint4*)(CtT + row * 128 + ((un ^ (row & 7)) << 4));
    *reinterpret_cast<uint4*>(&Kb[(size_t)(n0 + row) * N_ + m0 + (un << 4)]) = v;
  }
  if (t < 128) atomicAdd(&colsum[b * N_ + n0 + t], cs[t]);
}

// ---------- out[r] = marg[r] / (K_row_r . x + 1e-8), 16 rows/block; optional denom fuse ----------
__global__ __launch_bounds__(256) void k_mv(
    const u8* __restrict__ Kp, const float* __restrict__ x,
    const float* __restrict__ denom,
    const float* __restrict__ marg, float* __restrict__ outp)
{
  int r0 = blockIdx.x * 16;
  int b = r0 >> 12;
  int t = threadIdx.x, w = t >> 6, lane = t & 63;
  __shared__ __align__(16) float xs[N_];
  const float* xb = x + b * N_;
  if (denom){
    const float* db = denom + b * N_;
    for (int i = t; i < N_; i += 256) xs[i] = xb[i] / (db[i] + 1e-8f);
  } else {
    for (int i = t; i < N_ / 4; i += 256)
      reinterpret_cast<float4*>(xs)[i] = reinterpret_cast<const float4*>(xb)[i];
  }
  __syncthreads();
  int rbase = r0 + w * 4;
  const u8* Kr = Kp + (size_t)b * N_ * N_ + (size_t)(rbase & (N_ - 1)) * N_;
  float acc[4] = {0.f, 0.f, 0.f, 0.f};
  #pragma unroll
  for (int p = 0; p < 4; p++){
    int idx = p * 1024 + lane * 16;
    float4 xv0 = *reinterpret_cast<const float4*>(xs + idx);
    float4 xv1 = *reinterpret_cast<const float4*>(xs + idx + 4);
    float4 xv2 = *reinterpret_cast<const float4*>(xs + idx + 8);
    float4 xv3 = *reinterpret_cast<const float4*>(xs + idx + 12);
    #pragma unroll
    for (int k = 0; k < 4; k++){
      uint4 a = *reinterpret_cast<const uint4*>(Kr + (size_t)k * N_ + idx);
      f32x2 l0 = __builtin_amdgcn_cvt_pk_f32_fp8((int)a.x, false);
      f32x2 h0 = __builtin_amdgcn_cvt_pk_f32_fp8((int)a.x, true);
      f32x2 l1 = __builtin_amdgcn_cvt_pk_f32_fp8((int)a.y, false);
      f32x2 h1 = __builtin_amdgcn_cvt_pk_f32_fp8((int)a.y, true);
      f32x2 l2 = __builtin_amdgcn_cvt_pk_f32_fp8((int)a.z, false);
      f32x2 h2 = __builtin_amdgcn_cvt_pk_f32_fp8((int)a.z, true);
      f32x2 l3 = __builtin_amdgcn_cvt_pk_f32_fp8((int)a.w, false);
      f32x2 h3 = __builtin_amdgcn_cvt_pk_f32_fp8((int)a.w, true);
      acc[k] += l0.x * xv0.x + l0.y * xv0.y + h0.x * xv0.z + h0.y * xv0.w
              + l1.x * xv1.x + l1.y * xv1.y + h1.x * xv1.z + h1.y * xv1.w
              + l2.x * xv2.x + l2.y * xv2.y + h2.x * xv2.z + h2.y * xv2.w
              + l3.x * xv3.x + l3.y * xv3.y + h3.x * xv3.z + h3.y * xv3.w;
    }
  }
  #pragma unroll
  for (int k = 0; k < 4; k++)
    for (int o = 32; o > 0; o >>= 1) acc[k] += __shfl_down(acc[k], o);
  if (lane == 0){
    #pragma unroll
    for (int k = 0; k < 4; k++)
      outp[rbase + k] = marg[rbase + k] / (acc[k] + 1e-8f);
  }
}

// ---------- part[ks][m][c] = vv[m] * sum_{n in ks chunk} (K[m][n]*u[n]) * src[n][c] ----------
// 512 threads, tile 64m x 256c; u folded into fp8-A decode; B stages srcT directly.
__global__ __launch_bounds__(512) void k_full(
    const u8* __restrict__ Kp, const u16* __restrict__ srcT,
    const float* __restrict__ uu, const float* __restrict__ vvv,
    u16* __restrict__ p0, u16* __restrict__ p1,
    u16* __restrict__ p2, u16* __restrict__ p3)
{
  int m0 = blockIdx.x << 6;
  int b = blockIdx.z >> 2, ks = blockIdx.z & 3;
  int t = threadIdx.x, lane = t & 63, w = t >> 6;   // w: 0..7 -> c-stripe of 32
  __shared__ __align__(16) u16 shbuf[64 * 64 + 256 * 64];  // Al 8KB | Bl 32KB
  __shared__ float vsm[64];
  u16* Al = shbuf;
  u16* Bl = shbuf + 64 * 64;
  if (t < 64) vsm[t] = vvv[b * N_ + m0 + t];
  f32x4 zero = {0.f, 0.f, 0.f, 0.f};
  f32x4 acc[4][2];
  #pragma unroll
  for (int i = 0; i < 4; i++){
    #pragma unroll
    for (int j = 0; j < 2; j++) acc[i][j] = zero;
  }
  const u8* ka = Kp + (size_t)b * N_ * N_ + (size_t)m0 * N_ + ks * (N_ / KSPLIT);
  const u16* ub = srcT + (size_t)b * C_ * N_ + ks * (N_ / KSPLIT);
  const float* ubase = uu + b * N_ + ks * (N_ / KSPLIT);
  for (int kt = 0; kt < N_ / KSPLIT; kt += 64){
    // A: 64x64 fp8 * u[n] -> bf16, reg-stage into swizzled-content linear LDS
    {
      int row = t >> 3, slot = t & 7;
      int coff = kt + ((slot ^ (row & 7)) << 3);
      const u8* gp = ka + (size_t)row * N_ + coff;
      uint2 v8 = *reinterpret_cast<const uint2*>(gp);
      float4 u0 = *reinterpret_cast<const float4*>(ubase + coff);
      float4 u1 = *reinterpret_cast<const float4*>(ubase + coff + 4);
      f32x2 q0 = __builtin_amdgcn_cvt_pk_f32_fp8((int)v8.x, false);
      f32x2 q1 = __builtin_amdgcn_cvt_pk_f32_fp8((int)v8.x, true);
      f32x2 q2 = __builtin_amdgcn_cvt_pk_f32_fp8((int)v8.y, false);
      f32x2 q3 = __builtin_amdgcn_cvt_pk_f32_fp8((int)v8.y, true);
      union { short8 s; unsigned u[4]; } o;
      asm("v_cvt_pk_bf16_f32 %0, %1, %2" : "=v"(o.u[0]) : "v"(q0.x * u0.x), "v"(q0.y * u0.y));
      asm("v_cvt_pk_bf16_f32 %0, %1, %2" : "=v"(o.u[1]) : "v"(q1.x * u0.z), "v"(q1.y * u0.w));
      asm("v_cvt_pk_bf16_f32 %0, %1, %2" : "=v"(o.u[2]) : "v"(q2.x * u1.x), "v"(q2.y * u1.y));
      asm("v_cvt_pk_bf16_f32 %0, %1, %2" : "=v"(o.u[3]) : "v"(q3.x * u1.z), "v"(q3.y * u1.w));
      *reinterpret_cast<short8*>(Al + (size_t)t * 8) = o.s;
    }
    stage_tile512_256(ub + kt, N_, Bl, t);
    __syncthreads();
    #pragma unroll
    for (int kh = 0; kh < 2; kh++){
      short8 af[4], bfv[2];
      #pragma unroll
      for (int i = 0; i < 4; i++)
        af[i] = frag_ld(Al, i * 16 + (lane & 15), kh * 4 + (lane >> 4));
      #pragma unroll
      for (int j = 0; j < 2; j++)
        bfv[j] = frag_ld(Bl, w * 32 + j * 16 + (lane & 15), kh * 4 + (lane >> 4));
      #pragma unroll
      for (int i = 0; i < 4; i++){
        #pragma unroll
        for (int j = 0; j < 2; j++)
          acc[i][j] = MFMA_BF16(af[i], bfv[j], acc[i][j]);
      }
    }
    __syncthreads();
  }
  u16* Ct = shbuf;
  #pragma unroll
  for (int j = 0; j < 2; j++){
    int col = w * 32 + j * 16 + (lane & 15);
    #pragma unroll
    for (int i = 0; i < 4; i++){
      int rb = i * 16 + (lane >> 4) * 4;
      #pragma unroll
      for (int r = 0; r < 4; r++){
        int row = rb + r;
        Ct[row * 256 + ((((col >> 3) ^ (row & 7)) << 3) | (col & 7))] =
            f2bf(acc[i][j][r] * vsm[row]);
      }
    }
  }
  __syncthreads();
  u16* P = (ks == 0) ? p0 : (ks == 1) ? p1 : (ks == 2) ? p2 : p3;
  for (int e = t; e < 2048; e += 512){
    int row = e >> 5, un = e & 31;
    short8 v8 = *(const short8*)(Ct + row * 256 + ((un ^ (row & 7)) << 3));
    *reinterpret_cast<short8*>(&P[(size_t)((b << 12) + m0 + row) * C_ + (un << 3)]) = v8;
  }
}

// ---------- out_feat = img + 1x1conv(p0+p1+p2+p3); also writes transposed bf16 inTp ----------
__global__ __launch_bounds__(256) void k_opconv(
    const u16* __restrict__ opwB, const float* __restrict__ opb,
    const u16* __restrict__ p0, const u16* __restrict__ p1,
    const u16* __restrict__ p2, const u16* __restrict__ p3,
    const float* __restrict__ img, float* __restrict__ outf,
    u16* __restrict__ inTp)
{
  int b = blockIdx.z;
  int n0 = blockIdx.x << 6;
  int co0 = blockIdx.y << 7;
  int t = threadIdx.x, lane = t & 63, w = t >> 6;
  int wr = w >> 1, wc = w & 1;              // wr: co half (64), wc: n half (32)
  __shared__ __align__(16) u16 Al[128 * 64];   // opw rows=co (reused as T in epilogue)
  __shared__ __align__(16) u16 Bl[64 * 64];    // fused rows=n
  f32x4 zero = {0.f, 0.f, 0.f, 0.f};
  f32x4 acc[4][2];
  #pragma unroll
  for (int i = 0; i < 4; i++){
    #pragma unroll
    for (int j = 0; j < 2; j++) acc[i][j] = zero;
  }
  for (int ct = 0; ct < C_; ct += 64){
    stage_tile(opwB + (size_t)co0 * C_ + ct, C_, Al, t);
    #pragma unroll
    for (int q = 0; q < 2; q++){
      int e = q * 256 + t;
      int row = e >> 3, slot = e & 7;
      int col = ct + ((slot ^ (row & 7)) << 3);
      size_t idx = (size_t)((b << 12) + n0 + row) * C_ + col;
      short8 a0 = *reinterpret_cast<const short8*>(p0 + idx);
      short8 a1 = *reinterpret_cast<const short8*>(p1 + idx);
      short8 a2 = *reinterpret_cast<const short8*>(p2 + idx);
      short8 a3 = *reinterpret_cast<const short8*>(p3 + idx);
      short8 o;
      #pragma unroll
      for (int k = 0; k < 8; k++)
        o[k] = (short)f2bf(bf2f((u16)a0[k]) + bf2f((u16)a1[k]) + bf2f((u16)a2[k]) + bf2f((u16)a3[k]));
      *reinterpret_cast<short8*>(Bl + (size_t)e * 8) = o;
    }
    __syncthreads();
    #pragma unroll
    for (int kh = 0; kh < 2; kh++){
      short8 af[4], bfv[2];
      #pragma unroll
      for (int i = 0; i < 4; i++)
        af[i] = frag_ld(Al, wr * 64 + i * 16 + (lane & 15), kh * 4 + (lane >> 4));
      #pragma unroll
      for (int j = 0; j < 2; j++)
        bfv[j] = frag_ld(Bl, wc * 32 + j * 16 + (lane & 15), kh * 4 + (lane >> 4));
      #pragma unroll
      for (int i = 0; i < 4; i++){
        #pragma unroll
        for (int j = 0; j < 2; j++)
          acc[i][j] = MFMA_BF16(af[i], bfv[j], acc[i][j]);
      }
    }
    __syncthreads();
  }
  float fin[4][2][4];
  #pragma unroll
  for (int i = 0; i < 4; i++){
    int cb = co0 + wr * 64 + i * 16 + (lane >> 4) * 4;
    #pragma unroll
    for (int j = 0; j < 2; j++){
      int nc = n0 + wc * 32 + j * 16 + (lane & 15);
      #pragma unroll
      for (int r = 0; r < 4; r++){
        int co = cb + r;
        size_t oi = (size_t)(b * C_ + co) * N_ + nc;
        float v = acc[i][j][r] + img[oi] + opb[co];
        outf[oi] = v;
        fin[i][j][r] = v;
      }
    }
  }
  u16* T = Al;
  #pragma unroll
  for (int i = 0; i < 4; i++){
    int cb4 = wr * 64 + i * 16 + (lane >> 4) * 4;
    #pragma unroll
    for (int j = 0; j < 2; j++){
      int ncL = wc * 32 + j * 16 + (lane & 15);
      ushort4 pk;
      pk.x = f2bf(fin[i][j][0]);
      pk.y = f2bf(fin[i][j][1]);
      pk.z = f2bf(fin[i][j][2]);
      pk.w = f2bf(fin[i][j][3]);
      *reinterpret_cast<ushort4*>(T + ncL * 128 + (cb4 ^ ((ncL & 15) << 3))) = pk;
    }
  }
  __syncthreads();
  int y = n0 >> 6;
  for (int e = t; e < 1024; e += 256){
    int px = e >> 4, u = e & 15;
    uint4 v = *reinterpret_cast<const uint4*>(T + px * 128 + ((u << 3) ^ ((px & 15) << 3)));
    int pxp = y * 66 + px + 1;
    *reinterpret_cast<uint4*>(inTp + ((size_t)b * PXTOT + PXPAD + pxp) * C_ + co0 + u * 8) = v;
  }
}

// ---------- fused 3x3 conv (both heads) as implicit GEMM: C[co][px'] (bf16 out) ----------
__global__ __launch_bounds__(256) void k_conv3m(
    const u16* __restrict__ inTp, const u16* __restrict__ Wt,
    const float* __restrict__ biasF,
    u16* __restrict__ q0, u16* __restrict__ q1,
    u16* __restrict__ q2, u16* __restrict__ q3)
{
  int px0 = blockIdx.x << 6;           // 0..65 (66 tiles of 64 px')
  int cot = blockIdx.y;                // 0..1 (co halves of 256 fused)
  int b = blockIdx.z >> 2, ks = blockIdx.z & 3;
  int t = threadIdx.x, lane = t & 63, w = t >> 6;
  int wr = w >> 1, wc = w & 1;         // wr: co half (64), wc: px half (32)
  __shared__ __align__(16) u16 Al[128 * 64];   // weights: 128 co rows x 64 ci
  __shared__ __align__(16) u16 Bl[64 * 64];    // input:   64 px rows x 64 ci
  f32x4 zero = {0.f, 0.f, 0.f, 0.f};
  f32x4 acc[4][2];
  #pragma unroll
  for (int i = 0; i < 4; i++){
    #pragma unroll
    for (int j = 0; j < 2; j++) acc[i][j] = zero;
  }
  const u16* inb = inTp + ((size_t)b * PXTOT + PXPAD + px0) * C_;
  for (int s = ks * 9; s < ks * 9 + 9; s++){
    int tap = s >> 2, cic = (s & 3) << 6;
    int ky = tap / 3, kx = tap - ky * 3;
    int off = (ky - 1) * 66 + (kx - 1);
    stage_tile(Wt + ((size_t)tap * 256 + cot * 128) * C_ + cic, C_, Al, t);
    stage_tile256_64(inb + (ptrdiff_t)off * C_ + cic, C_, Bl, t);
    __syncthreads();
    #pragma unroll
    for (int kh = 0; kh < 2; kh++){
      short8 af[4], bfv[2];
      #pragma unroll
      for (int i = 0; i < 4; i++)
        af[i] = frag_ld(Al, wr * 64 + i * 16 + (lane & 15), kh * 4 + (lane >> 4));
      #pragma unroll
      for (int j = 0; j < 2; j++)
        bfv[j] = frag_ld(Bl, wc * 32 + j * 16 + (lane & 15), kh * 4 + (lane >> 4));
      #pragma unroll
      for (int i = 0; i < 4; i++){
        #pragma unroll
        for (int j = 0; j < 2; j++)
          acc[i][j] = MFMA_BF16(af[i], bfv[j], acc[i][j]);
      }
    }
    __syncthreads();
  }
  u16* P = (ks == 0) ? q0 : (ks == 1) ? q1 : (ks == 2) ? q2 : q3;
  #pragma unroll
  for (int i = 0; i < 4; i++){
    #pragma unroll
    for (int j = 0; j < 2; j++){
      int pxp = px0 + wc * 32 + j * 16 + (lane & 15);
      int y = pxp / 66;
      int xm = pxp - y * 66;
      bool valid = (xm >= 1 && xm <= 64);
      int outn = y * 64 + xm - 1;
      #pragma unroll
      for (int r = 0; r < 4; r++){
        int co = cot * 128 + wr * 64 + i * 16 + (lane >> 4) * 4 + r;
        if (valid){
          float bco = (ks == 0) ? biasF[co] : 0.f;
          P[((size_t)(b * 256 + co)) * N_ + outn] = f2bf(acc[i][j][r] + bco);
        }
      }
    }
  }
}

// ---------- batchnorm stats over (B,H,W) per fused channel (sums 4 K-parts) ----------
__global__ __launch_bounds__(256) void k_bnstats2(
    const u16* __restrict__ p0, const u16* __restrict__ p1,
    const u16* __restrict__ p2, const u16* __restrict__ p3,
    float* __restrict__ stats)
{
  int ch = blockIdx.x, t = threadIdx.x;   // ch in [0,256)
  __shared__ float r1[256], r2[256];
  float s1 = 0.f, s2 = 0.f;
  for (int i = t; i < B_ * N_; i += 256){
    int b = i >> 12, n = i & (N_ - 1);
    size_t idx = ((size_t)(b * 256 + ch)) * N_ + n;
    float v = bf2f(p0[idx]) + bf2f(p1[idx]) + bf2f(p2[idx]) + bf2f(p3[idx]);
    s1 += v; s2 += v * v;
  }
  r1[t] = s1; r2[t] = s2; __syncthreads();
  for (int o = 128; o > 0; o >>= 1){
    if (t < o){ r1[t] += r1[t + o]; r2[t] += r2[t + o]; }
    __syncthreads();
  }
  if (t == 0){
    float mean = r1[0] / (float)(B_ * N_);
    float var = r2[0] / (float)(B_ * N_) - mean * mean;
    stats[ch * 2] = mean;
    stats[ch * 2 + 1] = rsqrtf(var + 1e-5f);
  }
}

// ---------- fused dual-head: relu(bn(mid)) -> 1x1 conv to 2 ch per head ----------
__global__ __launch_bounds__(256) void k_headF(
    const u16* __restrict__ p0, const u16* __restrict__ p1,
    const u16* __restrict__ p2, const u16* __restrict__ p3,
    const float* __restrict__ stats,
    const float* __restrict__ hm_g, const float* __restrict__ hm_b,
    const float* __restrict__ hm2_w, const float* __restrict__ hm2_b,
    const float* __restrict__ hv_g, const float* __restrict__ hv_b,
    const float* __restrict__ hv2_w, const float* __restrict__ hv2_b,
    float* __restrict__ outhm, float* __restrict__ outhv)
{
  int t = threadIdx.x;
  int nl = t & 31, g = t >> 5;
  int idx0 = blockIdx.x * 32;
  int idx = idx0 + nl;
  int b = idx >> 12, n = idx & (N_ - 1);
  int head = g >> 2;
  int ch0 = (g & 3) * 32;
  const float* gg = head ? hv_g : hm_g;
  const float* gb = head ? hv_b : hm_b;
  const float* w2 = head ? hv2_w : hm2_w;
  float a0 = 0.f, a1 = 0.f;
  #pragma unroll 8
  for (int cc = 0; cc < 32; cc++){
    int ch = ch0 + cc;
    int fc = head * CH_ + ch;
    size_t id = ((size_t)(b * 256 + fc)) * N_ + n;
    float v = bf2f(p0[id]) + bf2f(p1[id]) + bf2f(p2[id]) + bf2f(p3[id]);
    float rr = fmaxf((v - stats[fc * 2]) * stats[fc * 2 + 1] * gg[ch] + gb[ch], 0.f);
    a0 += w2[ch] * rr;
    a1 += w2[CH_ + ch] * rr;
  }
  __shared__ float r0[8][32], r1[8][32];
  r0[g][nl] = a0; r1[g][nl] = a1;
  __syncthreads();
  if (t < 64){
    int hh = t >> 5, n2 = t & 31;
    int base = hh * 4;
    float s0 = r0[base][n2] + r0[base + 1][n2] + r0[base + 2][n2] + r0[base + 3][n2];
    float s1 = r1[base][n2] + r1[base + 1][n2] + r1[base + 2][n2] + r1[base + 3][n2];
    int idx2 = idx0 + n2;
    int b2 = idx2 >> 12, nn = idx2 & (N_ - 1);
    float* op = hh ? outhv : outhm;
    const float* bp = hh ? hv2_b : hm2_b;
    op[(size_t)(b2 * 2) * N_ + nn] = s0 + bp[0];
    op[(size_t)(b2 * 2 + 1) * N_ + nn] = s1 + bp[1];
  }
}

extern "C" void kernel_launch(void* const* d_in, const int* in_sizes, int n_in,
                              void* d_out, int out_size, void* d_ws, size_t ws_size,
                              hipStream_t stream)
{
  const float* img   = (const float*)d_in[0];
  const float* txt   = (const float*)d_in[1];
  const float* dens  = (const float*)d_in[2];
  const float* tp_w  = (const float*)d_in[3];
  const float* tp_b  = (const float*)d_in[4];
  const float* wv    = (const float*)d_in[9];
  const float* bv    = (const float*)d_in[10];
  const float* wo    = (const float*)d_in[11];
  const float* bo    = (const float*)d_in[12];
  const float* ln_g  = (const float*)d_in[13];
  const float* ln_b  = (const float*)d_in[14];
  const float* op_w  = (const float*)d_in[15];
  const float* op_b  = (const float*)d_in[16];
  const float* hm1_w = (const float*)d_in[17];
  const float* hm1_b = (const float*)d_in[18];
  const float* hm_g  = (const float*)d_in[19];
  const float* hm_b  = (const float*)d_in[20];
  const float* hm2_w = (const float*)d_in[21];
  const float* hm2_b = (const float*)d_in[22];
  const float* hv1_w = (const float*)d_in[23];
  const float* hv1_b = (const float*)d_in[24];
  const float* hv_g  = (const float*)d_in[25];
  const float* hv_b  = (const float*)d_in[26];
  const float* hv2_w = (const float*)d_in[27];
  const float* hv2_b = (const float*)d_in[28];
  const float* temp  = (const float*)d_in[29];

  char* wsb = (char*)d_ws;
  size_t off = 0;
  auto alloc = [&](size_t bytes) -> void* {
    void* p = wsb + off;
    off += (bytes + 255) & ~(size_t)255;
    return p;
  };
  u8*    Km     = (u8*)   alloc((size_t)B_ * N_ * N_ * sizeof(u8));    // 33.5 MB (fp8)
  u16*   snb16  = (u16*)  alloc((size_t)B_ * N_ * C_ * sizeof(u16));   // 4.19 MB (part0 alias)
  u16*   srcT16 = (u16*)  alloc((size_t)B_ * C_ * N_ * sizeof(u16));   // 4.19 MB
  u16*   part1  = (u16*)  alloc((size_t)B_ * N_ * C_ * sizeof(u16));   // 4.19 MB
  u16*   part2  = (u16*)  alloc((size_t)B_ * N_ * C_ * sizeof(u16));   // 4.19 MB
  u16*   part3  = (u16*)  alloc((size_t)B_ * N_ * C_ * sizeof(u16));   // 4.19 MB
  u16*   inTp   = (u16*)  alloc((size_t)B_ * PXTOT * C_ * sizeof(u16));// 4.52 MB
  u16*   Wt     = (u16*)  alloc((size_t)9 * 256 * C_ * sizeof(u16));   // 1.18 MB
  u16*   opwB   = (u16*)  alloc((size_t)C_ * C_ * sizeof(u16));        // 131 KB
  float* biasF  = (float*)alloc(256 * sizeof(float));
  float* teb    = (float*)alloc(B_ * C_ * sizeof(float));
  float* attn_c = (float*)alloc(B_ * C_ * sizeof(float));
  float* txt_n  = (float*)alloc(B_ * C_ * sizeof(float));
  float* cosv   = (float*)alloc(B_ * N_ * sizeof(float));
  float* qm     = (float*)alloc(B_ * N_ * sizeof(float));
  float* pm     = (float*)alloc(B_ * N_ * sizeof(float));
  float* uu     = (float*)alloc(B_ * N_ * sizeof(float));
  float* vvv    = (float*)alloc(B_ * N_ * sizeof(float));
  float* colsum = (float*)alloc(B_ * N_ * sizeof(float));
  float* stats  = (float*)alloc(256 * 2 * sizeof(float));

  // alias: part0 over snb16 (snb dead after kgen; part0 written by k_full)
  u16* part0 = snb16;

  float* outf  = (float*)d_out;
  float* outhm = outf + (size_t)B_ * C_ * N_;
  float* outhv = outhm + (size_t)B_ * 2 * N_;

  k_prep<<<128 + 2560 + 1104, 256, 0, stream>>>(txt, tp_w, tp_b, teb,
      hm1_w, hv1_w, hm1_b, hv1_b, op_w, Wt, biasF, opwB, (float*)inTp);
  k_text2<<<B_, 1024, 0, stream>>>(teb, wv, bv, wo, bo, attn_c, txt_n);
  k_source<<<dim3(N_ / TN, B_), 256, 0, stream>>>(img, attn_c, ln_g, ln_b, txt_n, srcT16, snb16, cosv);
  k_marg<<<2 * B_ + B_ * N_ / 256, 256, 0, stream>>>(dens, cosv, temp, qm, pm, colsum);
  // K generation (fp8 e4m3 output via hw converters, full grid)
  k_kgen<<<dim3(N_ / 128, N_ / 128, B_), 256, 0, stream>>>(snb16, Km, colsum);
  // Sinkhorn (K symmetric: K^T x == K x); first mv fuses vv1 = qm/colsum
  k_mv<<<B_ * N_ / 16, 256, 0, stream>>>(Km, qm, colsum, pm, uu);            // u1
  k_mv<<<B_ * N_ / 16, 256, 0, stream>>>(Km, uu, nullptr, qm, vvv);          // vv2
  k_mv<<<B_ * N_ / 16, 256, 0, stream>>>(Km, vvv, nullptr, pm, uu);          // u2
  k_mv<<<B_ * N_ / 16, 256, 0, stream>>>(Km, uu, nullptr, qm, vvv);          // vv3
  k_mv<<<B_ * N_ / 16, 256, 0, stream>>>(Km, vvv, nullptr, pm, uu);          // u3
  k_full<<<dim3(N_ / 64, 1, B_ * KSPLIT), 512, 0, stream>>>(Km, srcT16, uu, vvv, part0, part1, part2, part3);
  k_opconv<<<dim3(N_ / 64, C_ / 128, B_), 256, 0, stream>>>(opwB, op_b, part0, part1, part2, part3, img, outf, inTp);
  k_conv3m<<<dim3(66, 2, B_ * KSPLIT), 256, 0, stream>>>(inTp, Wt, biasF, part0, part1, part2, part3);
  k_bnstats2<<<256, 256, 0, stream>>>(part0, part1, part2, part3, stats);
  k_headF<<<B_ * N_ / 32, 256, 0, stream>>>(part0, part1, part2, part3, stats,
      hm_g, hm_b, hm2_w, hm2_b, hv_g, hv_b, hv2_w, hv2_b, outhm, outhv);
}